// Round 12
// baseline (4396.166 us; speedup 1.0000x reference)
//
#include <hip/hip_runtime.h>

#define B_ 64
#define P_ 196
#define ENC_ 2048
#define L_ 20
#define T_ 19
#define A_ 512
#define D_ 512
#define E_ 512
#define V_ 10000

// output offsets (float elements)
#define OFF_PREDS 0
#define OFF_CAPS  12160000
#define OFF_DLEN  12161280
#define OFF_ALPH  12161344
#define OFF_SIDX  12399680

// workspace offsets (bytes) — total ~104.5 MB
#define WS_SORT   0          /* 64 int */
#define WS_DLEN   1024
#define WS_CAPS   2048       /* 64*20 int -> 7168 */
#define WS_C0     8192       /* 64*512 f32 -> 139264 */
#define WS_C1     139264     /* -> 270336 */
#define WS_DAS    270336     /* 64*512 f32 -> 401408 */
#define WS_GATE   401408     /* 64*2048 f32 -> 925696 */
#define WS_HB0    925696     /* 64*512 bf16 -> 991232 */
#define WS_HB1    991232     /* -> 1056768 */
#define WS_CTXG   1056768    /* 64*2048 bf16 -> 1318912 */
#define WS_MEANB  1318912    /* 64*2048 bf16 -> 1581056 */
#define WS_HIST   1581056    /* 1280*512 bf16 -> 2891776 */
#define WS_EMB    2891776    /* 1216*512 bf16 -> 4136960 */
#define WS_GPART  4194304    /* 8*64*2048 f32 = 4 MB */
#define WS_EPT    8388608    /* 12544*512 bf16 = 12.85 MB */
#define WS_WEAT   21233664   /* 512*2048 bf16 */
#define WS_WHG    23330816   /* 2560*512 bf16 */
#define WS_W2I    25952256   /* 2048*3072 bf16 */
#define WS_WOB    38535168   /* 10112*512 bf16 */
#define WS_WINIT  48889856   /* 1024*2048 bf16 */
#define WS_ENCS   53084160   /* 12544*2048 bf16 = 51.38 MB -> end 104464384 */

typedef __attribute__((ext_vector_type(8))) short short8v;
typedef __attribute__((ext_vector_type(4))) float f32x4;
typedef unsigned int uint32;
typedef unsigned short ushort16;

__device__ __forceinline__ float ftanh(float x){ float e=__expf(2.f*x); return 1.f-2.f/(e+1.f); }
__device__ __forceinline__ float fsigm(float x){ return 1.f/(1.f+__expf(-x)); }
__device__ __forceinline__ ushort16 f2b(float f){
    uint32 u = __float_as_uint(f);
    uint32 r = (u + 0x7FFFu + ((u >> 16) & 1u)) >> 16;
    return (ushort16)r;
}
__device__ __forceinline__ uint32 pack_b2(float a, float b){
    return (uint32)f2b(a) | ((uint32)f2b(b) << 16);
}
__device__ __forceinline__ float b2f_lo(uint32 w){ return __uint_as_float(w << 16); }
__device__ __forceinline__ float b2f_hi(uint32 w){ return __uint_as_float(w & 0xFFFF0000u); }
__device__ __forceinline__ float b1f(ushort16 x){ return __uint_as_float((uint32)x << 16); }

// ---------------------------------------------------------------- parallel rank sort + meta
__global__ void k_sort(const int* __restrict__ cap_len, const int* __restrict__ captions,
                       float* __restrict__ out, int* __restrict__ wsi)
{
    __shared__ int len_s[B_];
    int tid = threadIdx.x;        // 64 threads
    int len = cap_len[tid];
    len_s[tid] = len;
    __syncthreads();
    int rank = 0;
#pragma unroll
    for (int j = 0; j < B_; ++j) {
        int lj = len_s[j];
        rank += (lj > len) || (lj == len && j < tid);
    }
    wsi[WS_SORT / 4 + rank] = tid;
    wsi[WS_DLEN / 4 + rank] = len - 1;
    out[OFF_SIDX + rank] = (float)tid;
    out[OFF_DLEN + rank] = (float)(len - 1);
#pragma unroll
    for (int l = 0; l < L_; ++l) {
        int cv = captions[tid * L_ + l];
        wsi[WS_CAPS / 4 + rank * L_ + l] = cv;
        out[OFF_CAPS + rank * L_ + l] = (float)cv;
    }
}

// ---------------------------------------------------------------- fused: sorted bf16 enc copy + mean
__global__ __launch_bounds__(256) void k_prep_enc(const float* __restrict__ enc,
                                                  const int* __restrict__ sortidx,
                                                  ushort16* __restrict__ encS,
                                                  ushort16* __restrict__ meanB)
{
    int b = blockIdx.x;
    int e = blockIdx.y * 256 + threadIdx.x;
    long sbase = (long)sortidx[b] * P_ * ENC_ + e;
    long dbase = (long)b * P_ * ENC_ + e;
    float s = 0.f;
    for (int p = 0; p < P_; ++p) {
        float v = enc[sbase + (long)p * ENC_];
        s += v;
        encS[dbase + (long)p * ENC_] = f2b(v);
    }
    meanB[b * ENC_ + e] = f2b(s * (1.f / (float)P_));
}

// ---------------------------------------------------------------- merged transpose+cast (5 weights)
__global__ __launch_bounds__(256) void k_transpose_all(
    const float* __restrict__ Wea, const float* __restrict__ Wda,
    const float* __restrict__ Wbe, const float* __restrict__ Wih,
    const float* __restrict__ Wic,
    ushort16* __restrict__ WeaT, ushort16* __restrict__ Whg,
    ushort16* __restrict__ WInit)
{
    __shared__ float tile[64][65];
    int id = blockIdx.x;
    const float* src; ushort16* dst; int R, C, bx, by;
    if (id < 256)      { src = Wea; dst = WeaT;                R = 2048; C = 512;  int i2 = id;        bx = i2 & 7;  by = i2 >> 3; }
    else if (id < 320) { src = Wda; dst = Whg;                 R = 512;  C = 512;  int i2 = id - 256;  bx = i2 & 7;  by = i2 >> 3; }
    else if (id < 576) { src = Wbe; dst = Whg + 512 * 512;     R = 512;  C = 2048; int i2 = id - 320;  bx = i2 & 31; by = i2 >> 5; }
    else if (id < 832) { src = Wih; dst = WInit;               R = 2048; C = 512;  int i2 = id - 576;  bx = i2 & 7;  by = i2 >> 3; }
    else               { src = Wic; dst = WInit + 512 * 2048;  R = 2048; C = 512;  int i2 = id - 832;  bx = i2 & 7;  by = i2 >> 3; }
    int c0 = bx * 64, r0 = by * 64;
    int lx = threadIdx.x & 63, ly = threadIdx.x >> 6;
#pragma unroll
    for (int i = 0; i < 16; ++i) {
        int r = ly * 16 + i;
        tile[lx][r] = src[(long)(r0 + r) * C + c0 + lx];
    }
    __syncthreads();
#pragma unroll
    for (int i = 0; i < 16; ++i) {
        int cr = ly * 16 + i;
        dst[(long)(c0 + cr) * R + r0 + lx] = f2b(tile[cr][lx]);
    }
}

// ---------------------------------------------------------------- merged small prep: wout | emb | w2i
__global__ __launch_bounds__(256) void k_prep_small(
    const float* __restrict__ Wout, const float* __restrict__ embedding,
    const int* __restrict__ caps, const float* __restrict__ WIH,
    const float* __restrict__ WHH,
    ushort16* __restrict__ WoB, ushort16* __restrict__ embB,
    ushort16* __restrict__ W2i)
{
    int id = blockIdx.x;
    if (id < 10112) {
        int r = id, k = threadIdx.x * 2;
        uint32 v = 0;
        if (r < V_) {
            float2 f = *(const float2*)(Wout + (long)r * 512 + k);
            v = pack_b2(f.x, f.y);
        }
        *(uint32*)(WoB + (long)r * 512 + k) = v;
    } else if (id < 11328) {
        int m = id - 10112;                    // m = t*64+b
        int tok = caps[(m & 63) * L_ + (m >> 6)];
        int k = threadIdx.x * 2;
        float2 v = *(const float2*)(embedding + (long)tok * E_ + k);
        *(uint32*)(embB + (long)m * E_ + k) = pack_b2(v.x, v.y);
    } else {
        int r = id - 11328;                    // 0..2047, r = 4d+q
        int d = r >> 2, q = r & 3;
        int n = q * 512 + d;
        for (int cch = threadIdx.x; cch < 384; cch += 256) {
            int kof = cch * 8;
            const float* s = (kof < 2560) ? (WIH + (long)n * 2560 + kof)
                                          : (WHH + (long)n * 512 + (kof - 2560));
            float4 f0 = *(const float4*)s;
            float4 f1 = *(const float4*)(s + 4);
            uint4 v; v.x = pack_b2(f0.x, f0.y); v.y = pack_b2(f0.z, f0.w);
            v.z = pack_b2(f1.x, f1.y); v.w = pack_b2(f1.z, f1.w);
            *(uint4*)(W2i + (long)r * 3072 + kof) = v;
        }
    }
}

// ---------------------------------------------------------------- bf16 MFMA GEMM
// EPI 1: bf16 C = v+bias
// EPI 6: gn<512 -> hb=f2b(v+bias); else c=v+bias2
// EPI 7: b=gm&63,tt=gm>>6; tt<T_ guard; preds=(tt<dlen)?v+bias:0
// SWZ 1: enc_proj 1D grid 1568=196x8 exact, XCD-chunked
// SWZ 2: pred 1D grid 800 -> (x<79, y<10), same-B blocks co-XCD
template<int BM, int BN, int WM, int WN, int EPI, int SWZ>
__global__ __launch_bounds__(256) void mgemm(
    const ushort16* __restrict__ Amat, int lda1,
    const ushort16* __restrict__ Bmat, int ldb,
    void* __restrict__ Cout, void* __restrict__ Cout2, int ldc, int N, int K,
    const float* __restrict__ bias, const float* __restrict__ bias2,
    const int* __restrict__ dlen)
{
    int bx, by;
    if (SWZ == 1) {
        int id = blockIdx.x;                 // 1568 = 196 per XCD x 8 XCDs (exact)
        int xcd = id & 7, idx = id >> 3;     // idx 0..195
        int j = xcd * 196 + idx;             // contiguous chunk per XCD
        by = j >> 3;                         // m-tile 0..195 (8 same-A blocks co-XCD)
        bx = j & 7;                          // n-tile 0..7
    } else if (SWZ == 2) {
        int id = blockIdx.x;                 // 800 launched, 790 logical
        bx = (id / 80) * 8 + (id & 7);
        by = (id >> 3) % 10;
        if (bx >= 79) return;
    } else { bx = blockIdx.x; by = blockIdx.y; }

    __shared__ __align__(16) ushort16 As[BM * 64];
    __shared__ __align__(16) ushort16 Bs[BN * 64];
    const int tid = threadIdx.x;
    const int m0 = by * BM, n0 = bx * BN;
    const int lane = tid & 63, wid = tid >> 6;
    constexpr int NWC = BN / WN;
    const int wr = wid / NWC, wc = wid % NWC;
    constexpr int FM = WM / 16, FN = WN / 16;
    f32x4 acc[FM][FN] = {};

    for (int k0 = 0; k0 < K; k0 += 64) {
        for (int i = tid; i < BM * 8; i += 256) {
            int r = i >> 3, ck = i & 7;
            uint4 val = *(const uint4*)(Amat + (long)(m0 + r) * lda1 + k0 + ck * 8);
            int bo = (r * 128 + ck * 16) ^ ((r & 7) << 4);
            *(uint4*)((char*)As + bo) = val;
        }
        for (int i = tid; i < BN * 8; i += 256) {
            int r = i >> 3, ck = i & 7;
            uint4 val = *(const uint4*)(Bmat + (long)(n0 + r) * ldb + k0 + ck * 8);
            int bo = (r * 128 + ck * 16) ^ ((r & 7) << 4);
            *(uint4*)((char*)Bs + bo) = val;
        }
        __syncthreads();
#pragma unroll
        for (int kk = 0; kk < 64; kk += 32) {
            short8v af[FM], bfr[FN];
#pragma unroll
            for (int f = 0; f < FM; ++f) {
                int r = wr * WM + f * 16 + (lane & 15);
                int bo = (r * 128 + (kk + ((lane >> 4) << 3)) * 2) ^ ((r & 7) << 4);
                af[f] = *(const short8v*)((const char*)As + bo);
            }
#pragma unroll
            for (int f = 0; f < FN; ++f) {
                int r = wc * WN + f * 16 + (lane & 15);
                int bo = (r * 128 + (kk + ((lane >> 4) << 3)) * 2) ^ ((r & 7) << 4);
                bfr[f] = *(const short8v*)((const char*)Bs + bo);
            }
#pragma unroll
            for (int fm = 0; fm < FM; ++fm)
#pragma unroll
                for (int fn = 0; fn < FN; ++fn)
                    acc[fm][fn] = __builtin_amdgcn_mfma_f32_16x16x32_bf16(
                        af[fm], bfr[fn], acc[fm][fn], 0, 0, 0);
        }
        __syncthreads();
    }

    int rr = lane >> 4, cc = lane & 15;
#pragma unroll
    for (int fm = 0; fm < FM; ++fm) {
#pragma unroll
        for (int fn = 0; fn < FN; ++fn) {
#pragma unroll
            for (int r = 0; r < 4; ++r) {
                int gm = m0 + wr * WM + fm * 16 + rr * 4 + r;
                int gn = n0 + wc * WN + fn * 16 + cc;
                float v = acc[fm][fn][r];
                if (EPI == 1) {
                    ((ushort16*)Cout)[(long)gm * ldc + gn] = f2b(v + bias[gn]);
                } else if (EPI == 6) {
                    if (gn < 512) ((ushort16*)Cout)[gm * 512 + gn] = f2b(v + bias[gn]);
                    else ((float*)Cout2)[gm * 512 + (gn - 512)] = v + bias2[gn - 512];
                } else if (EPI == 7) {
                    int bq = gm & 63, tt = gm >> 6;
                    if (gn < N && tt < T_)   // tt<T_: rows >=1216 are padding (R8 bug lesson)
                        ((float*)Cout)[((long)bq * T_ + tt) * V_ + gn] =
                            (tt < dlen[bq]) ? v + bias[gn] : 0.f;
                }
            }
        }
    }
}

// ---------------------------------------------------------------- fused LSTM(t-1) + das|gate GEMM
// 40 blocks x 256. Prologue: every block redundantly computes h_t from gpart+c_in
// (bit-identical across blocks) into swizzled LDS; block 0 also writes h/c/hist to
// global (no same-kernel consumer -> race-free). GEMM: A=h from LDS, B fully staged,
// single barrier, 64 MFMA. t==0: h loaded from h_in (h0c0 output).
__global__ __launch_bounds__(256) void k_dasgate(
    const float* __restrict__ gpart,
    const float* __restrict__ bIH, const float* __restrict__ bHH,
    const int* __restrict__ dlen,
    const float* __restrict__ c_in, float* __restrict__ c_out,
    const ushort16* __restrict__ h_in, ushort16* __restrict__ h_out,
    ushort16* __restrict__ histB,
    const ushort16* __restrict__ Whg,
    const float* __restrict__ bda, const float* __restrict__ bbe,
    float* __restrict__ das, float* __restrict__ gate, int t)
{
    __shared__ __align__(16) char hsm[65536];   // h 64x512 bf16, XOR-swizzled
    __shared__ __align__(16) char Bsm[65536];   // Whg tile 64x512 bf16, XOR-swizzled
    const int tid = threadIdx.x;
    const int n0 = blockIdx.x * 64;
    const bool w0 = (blockIdx.x == 0);

    if (t == 0) {
        for (int i = tid; i < 4096; i += 256) {
            int r = i >> 6, col8 = (i & 63) << 3;
            uint4 v = *(const uint4*)(h_in + r * 512 + col8);
            int bo = (r * 1024 + col8 * 2) ^ ((r & 7) << 4);
            *(uint4*)(hsm + bo) = v;
        }
    } else {
        for (int i = tid; i < 4096; i += 256) {
            int b = i >> 6, d0 = (i & 63) << 3;
            ushort16 harr[8];
            if ((t - 1) < dlen[b]) {
                float sums[32];
#pragma unroll
                for (int j = 0; j < 32; ++j) sums[j] = 0.f;
#pragma unroll
                for (int k2 = 0; k2 < 8; ++k2) {
                    const float* gp = gpart + ((long)(k2 * 64 + b)) * ENC_ + 4 * d0;
#pragma unroll
                    for (int j = 0; j < 8; ++j) {
                        float4 g4 = *(const float4*)(gp + j * 4);
                        sums[j * 4 + 0] += g4.x; sums[j * 4 + 1] += g4.y;
                        sums[j * 4 + 2] += g4.z; sums[j * 4 + 3] += g4.w;
                    }
                }
#pragma unroll
                for (int u = 0; u < 8; ++u) {
                    int d = d0 + u;
                    float g0 = sums[u * 4 + 0] + bIH[d] + bHH[d];
                    float g1 = sums[u * 4 + 1] + bIH[512 + d] + bHH[512 + d];
                    float g2 = sums[u * 4 + 2] + bIH[1024 + d] + bHH[1024 + d];
                    float g3 = sums[u * 4 + 3] + bIH[1536 + d] + bHH[1536 + d];
                    float i_ = fsigm(g0), f_ = fsigm(g1), gg = ftanh(g2), o_ = fsigm(g3);
                    long off = (long)b * 512 + d;
                    float cn = f_ * c_in[off] + i_ * gg;
                    float hn = o_ * ftanh(cn);
                    harr[u] = f2b(hn);
                    if (w0) {
                        c_out[off] = cn;
                        histB[((long)((t - 1) * 64 + b)) * 512 + d] = harr[u];
                    }
                }
            } else {
                *(uint4*)harr = *(const uint4*)(h_in + b * 512 + d0);
                if (w0) {
#pragma unroll
                    for (int u = 0; u < 8; ++u) {
                        long off = (long)b * 512 + d0 + u;
                        c_out[off] = c_in[off];
                    }
                }
            }
            if (w0) *(uint4*)(h_out + b * 512 + d0) = *(const uint4*)harr;
            int bo = (b * 1024 + d0 * 2) ^ ((b & 7) << 4);
            *(uint4*)(hsm + bo) = *(const uint4*)harr;
        }
    }
    // stage full B tile (Whg rows n0..n0+63, K=512)
    for (int i = tid; i < 4096; i += 256) {
        int r = i >> 6, col8 = (i & 63) << 3;
        uint4 v = *(const uint4*)(Whg + (long)(n0 + r) * 512 + col8);
        int bo = (r * 1024 + col8 * 2) ^ ((r & 7) << 4);
        *(uint4*)(Bsm + bo) = v;
    }
    __syncthreads();
    // GEMM 64x64xK512, 4 waves (2x2), barrier-free inner loop
    const int lane = tid & 63, wid = tid >> 6;
    const int wr = wid >> 1, wc = wid & 1;
    f32x4 acc[2][2] = {};
    for (int k0 = 0; k0 < 512; k0 += 32) {
        short8v af[2], bfv[2];
        int ko = (k0 + ((lane >> 4) << 3)) * 2;
#pragma unroll
        for (int f = 0; f < 2; ++f) {
            int r = wr * 32 + f * 16 + (lane & 15);
            af[f] = *(const short8v*)(hsm + ((r * 1024 + ko) ^ ((r & 7) << 4)));
        }
#pragma unroll
        for (int f = 0; f < 2; ++f) {
            int r = wc * 32 + f * 16 + (lane & 15);
            bfv[f] = *(const short8v*)(Bsm + ((r * 1024 + ko) ^ ((r & 7) << 4)));
        }
#pragma unroll
        for (int fm = 0; fm < 2; ++fm)
#pragma unroll
            for (int fn = 0; fn < 2; ++fn)
                acc[fm][fn] = __builtin_amdgcn_mfma_f32_16x16x32_bf16(
                    af[fm], bfv[fn], acc[fm][fn], 0, 0, 0);
    }
    int rr = lane >> 4, cc = lane & 15;
#pragma unroll
    for (int fm = 0; fm < 2; ++fm)
#pragma unroll
        for (int fn = 0; fn < 2; ++fn)
#pragma unroll
            for (int r = 0; r < 4; ++r) {
                int gm = wr * 32 + fm * 16 + rr * 4 + r;
                int gn = n0 + wc * 32 + fn * 16 + cc;
                float v = acc[fm][fn][r];
                if (gn < 512) das[gm * 512 + gn] = v + bda[gn];
                else gate[gm * ENC_ + (gn - 512)] = fsigm(v + bbe[gn - 512]);
            }
}

// ---------------------------------------------------------------- attention: scores+softmax+alpha+ctx
__global__ __launch_bounds__(512) void k_att(
    const float* __restrict__ das, const float* __restrict__ gate,
    const float* __restrict__ Wfa, const float* __restrict__ bfa,
    const ushort16* __restrict__ ept, const ushort16* __restrict__ encS,
    const int* __restrict__ dlen,
    ushort16* __restrict__ ctxg, float* __restrict__ out, int t)
{
    int b = blockIdx.x, eg = blockIdx.y;
    int tid = threadIdx.x;
    if (t >= dlen[b]) {
        if (eg == 0 && tid < P_) out[OFF_ALPH + ((long)b * T_ + t) * P_ + tid] = 0.f;
        return;
    }
    __shared__ float al[P_ + 4];
    __shared__ float red[512];
    int lane = tid & 63, wv = tid >> 6;
    float wf8[8], da8[8];
    {
        const float* wp = Wfa + lane * 8;
        const float* dp = das + b * 512 + lane * 8;
#pragma unroll
        for (int j = 0; j < 8; ++j) { wf8[j] = wp[j]; da8[j] = dp[j]; }
    }
    float b0 = bfa[0];
    for (int p = wv; p < P_; p += 8) {
        uint4 u = *(const uint4*)(ept + ((long)(b * P_ + p)) * 512 + lane * 8);
        float s = 0.f;
        s += wf8[0] * ftanh(b2f_lo(u.x) + da8[0]);
        s += wf8[1] * ftanh(b2f_hi(u.x) + da8[1]);
        s += wf8[2] * ftanh(b2f_lo(u.y) + da8[2]);
        s += wf8[3] * ftanh(b2f_hi(u.y) + da8[3]);
        s += wf8[4] * ftanh(b2f_lo(u.z) + da8[4]);
        s += wf8[5] * ftanh(b2f_hi(u.z) + da8[5]);
        s += wf8[6] * ftanh(b2f_lo(u.w) + da8[6]);
        s += wf8[7] * ftanh(b2f_hi(u.w) + da8[7]);
#pragma unroll
        for (int off = 32; off > 0; off >>= 1) s += __shfl_xor(s, off);
        if (lane == 0) al[p] = s + b0;
    }
    __syncthreads();
    float sc = (tid < P_) ? al[tid] : -1e30f;
    red[tid] = sc;
    __syncthreads();
    for (int s = 256; s > 0; s >>= 1) {
        if (tid < s) red[tid] = fmaxf(red[tid], red[tid + s]);
        __syncthreads();
    }
    float mx = red[0];
    __syncthreads();
    float e = (tid < P_) ? __expf(sc - mx) : 0.f;
    red[tid] = e;
    __syncthreads();
    for (int s = 256; s > 0; s >>= 1) {
        if (tid < s) red[tid] += red[tid + s];
        __syncthreads();
    }
    float inv = 1.f / red[0];
    __syncthreads();
    if (tid < P_) al[tid] = e * inv;
    __syncthreads();
    if (eg == 0 && tid < P_)
        out[OFF_ALPH + ((long)b * T_ + t) * P_ + tid] = al[tid];
    int e0 = eg * 1024 + tid * 2;
    long base = ((long)b * P_) * ENC_ + e0;
    float a0 = 0.f, a1 = 0.f;
#pragma unroll 4
    for (int p = 0; p < P_; ++p) {
        uint32 v = *(const uint32*)(encS + base + (long)p * ENC_);
        float alp = al[p];
        a0 += alp * b2f_lo(v); a1 += alp * b2f_hi(v);
    }
    float2 g2 = *(const float2*)(gate + b * ENC_ + e0);
    *(uint32*)(ctxg + b * ENC_ + e0) = pack_b2(g2.x * a0, g2.y * a1);
}

// ---------------------------------------------------------------- gates GEMM split-K (256 blocks)
__global__ __launch_bounds__(256) void k_gates(
    const ushort16* __restrict__ embB, const ushort16* __restrict__ ctxg,
    const ushort16* __restrict__ hin,  const ushort16* __restrict__ W2i,
    float* __restrict__ gpart, int t)
{
    __shared__ __align__(16) ushort16 As[64 * 64];
    __shared__ __align__(16) ushort16 Bs[64 * 64];
    const int tid = threadIdx.x;
    const int nt = blockIdx.x >> 3, ks = blockIdx.x & 7;
    const int n0 = nt * 64, kbeg = ks * 384;
    const int lane = tid & 63, wid = tid >> 6;
    const int wr = wid >> 1, wc = wid & 1;
    f32x4 acc[2][2] = {};

    for (int k0 = kbeg; k0 < kbeg + 384; k0 += 64) {
        for (int i = tid; i < 512; i += 256) {
            int r = i >> 3, ck = i & 7;
            int kk = k0 + ck * 8;
            const ushort16* src;
            if (kk < 512)       src = embB + ((long)(t * 64 + r)) * 512 + kk;
            else if (kk < 2560) src = ctxg + (long)r * ENC_ + (kk - 512);
            else                src = hin + (long)r * 512 + (kk - 2560);
            uint4 val = *(const uint4*)src;
            int bo = (r * 128 + ck * 16) ^ ((r & 7) << 4);
            *(uint4*)((char*)As + bo) = val;
        }
        for (int i = tid; i < 512; i += 256) {
            int r = i >> 3, ck = i & 7;
            uint4 val = *(const uint4*)(W2i + (long)(n0 + r) * 3072 + k0 + ck * 8);
            int bo = (r * 128 + ck * 16) ^ ((r & 7) << 4);
            *(uint4*)((char*)Bs + bo) = val;
        }
        __syncthreads();
#pragma unroll
        for (int kk = 0; kk < 64; kk += 32) {
            short8v af[2], bfr[2];
#pragma unroll
            for (int f = 0; f < 2; ++f) {
                int r = wr * 32 + f * 16 + (lane & 15);
                int bo = (r * 128 + (kk + ((lane >> 4) << 3)) * 2) ^ ((r & 7) << 4);
                af[f] = *(const short8v*)((const char*)As + bo);
            }
#pragma unroll
            for (int f = 0; f < 2; ++f) {
                int r = wc * 32 + f * 16 + (lane & 15);
                int bo = (r * 128 + (kk + ((lane >> 4) << 3)) * 2) ^ ((r & 7) << 4);
                bfr[f] = *(const short8v*)((const char*)Bs + bo);
            }
#pragma unroll
            for (int fm = 0; fm < 2; ++fm)
#pragma unroll
                for (int fn = 0; fn < 2; ++fn)
                    acc[fm][fn] = __builtin_amdgcn_mfma_f32_16x16x32_bf16(
                        af[fm], bfr[fn], acc[fm][fn], 0, 0, 0);
        }
        __syncthreads();
    }
    int rr = lane >> 4, cc = lane & 15;
#pragma unroll
    for (int fm = 0; fm < 2; ++fm)
#pragma unroll
        for (int fn = 0; fn < 2; ++fn)
#pragma unroll
            for (int r = 0; r < 4; ++r) {
                int gm = wr * 32 + fm * 16 + rr * 4 + r;
                int gn = n0 + wc * 32 + fn * 16 + cc;
                gpart[((long)(ks * 64 + gm)) * ENC_ + gn] = acc[fm][fn][r];
            }
}

// ---------------------------------------------------------------- LSTM pointwise (final hist(18) only)
__global__ __launch_bounds__(256) void k_lstm(
    const float* __restrict__ gpart,
    const float* __restrict__ bIH, const float* __restrict__ bHH,
    const int* __restrict__ dlen, float* __restrict__ c,
    const ushort16* __restrict__ hin, ushort16* __restrict__ hout,
    ushort16* __restrict__ histB, int t)
{
    int idx = blockIdx.x * 256 + threadIdx.x;
    int b = idx >> 9, d = idx & 511;
    long off = (long)b * 512 + d;
    if (t < dlen[b]) {
        float s0 = 0.f, s1 = 0.f, s2 = 0.f, s3 = 0.f;
#pragma unroll
        for (int ks = 0; ks < 8; ++ks) {
            float4 gp = *(const float4*)(gpart + ((long)(ks * 64 + b)) * ENC_ + 4 * d);
            s0 += gp.x; s1 += gp.y; s2 += gp.z; s3 += gp.w;
        }
        float g0 = s0 + bIH[d] + bHH[d];
        float g1 = s1 + bIH[512 + d] + bHH[512 + d];
        float g2v = s2 + bIH[1024 + d] + bHH[1024 + d];
        float g3 = s3 + bIH[1536 + d] + bHH[1536 + d];
        float i_ = fsigm(g0), f_ = fsigm(g1), gg = ftanh(g2v), o_ = fsigm(g3);
        float cn = f_ * c[off] + i_ * gg;
        float hn = o_ * ftanh(cn);
        c[off] = cn;
        ushort16 hv = f2b(hn);
        hout[off] = hv;
        histB[((long)(t * 64 + b)) * 512 + d] = hv;
    } else {
        hout[off] = hin[off];
    }
}

// ---------------------------------------------------------------- launch
extern "C" void kernel_launch(void* const* d_in, const int* in_sizes, int n_in,
                              void* d_out, int out_size, void* d_ws, size_t ws_size,
                              hipStream_t stream)
{
    (void)in_sizes; (void)n_in; (void)out_size; (void)ws_size;
    const float* enc      = (const float*)d_in[0];
    const int*   captions = (const int*)d_in[1];
    const int*   caplen   = (const int*)d_in[2];
    const float* Wemb     = (const float*)d_in[3];
    const float* Wea = (const float*)d_in[4];  const float* bea = (const float*)d_in[5];
    const float* Wda = (const float*)d_in[6];  const float* bda = (const float*)d_in[7];
    const float* Wfa = (const float*)d_in[8];  const float* bfa = (const float*)d_in[9];
    const float* Wih = (const float*)d_in[10]; const float* bih = (const float*)d_in[11];
    const float* Wic = (const float*)d_in[12]; const float* bic = (const float*)d_in[13];
    const float* Wbe = (const float*)d_in[14]; const float* bbe = (const float*)d_in[15];
    const float* WIH = (const float*)d_in[16]; const float* bIH = (const float*)d_in[17];
    const float* WHH = (const float*)d_in[18]; const float* bHH = (const float*)d_in[19];
    const float* Wout = (const float*)d_in[20]; const float* bout = (const float*)d_in[21];

    float* out = (float*)d_out;
    char*  ws  = (char*)d_ws;
    int*   wsi = (int*)ws;
    const int* dlen = wsi + WS_DLEN / 4;
    const int* sortidx = wsi + WS_SORT / 4;
    float* cb0     = (float*)(ws + WS_C0);
    float* cb1     = (float*)(ws + WS_C1);
    float* das     = (float*)(ws + WS_DAS);
    float* gate    = (float*)(ws + WS_GATE);
    ushort16* hb0  = (ushort16*)(ws + WS_HB0);
    ushort16* hb1  = (ushort16*)(ws + WS_HB1);
    ushort16* ctxg = (ushort16*)(ws + WS_CTXG);
    ushort16* meanB= (ushort16*)(ws + WS_MEANB);
    ushort16* histB= (ushort16*)(ws + WS_HIST);
    ushort16* embB = (ushort16*)(ws + WS_EMB);
    float* gpart   = (float*)(ws + WS_GPART);
    ushort16* ept  = (ushort16*)(ws + WS_EPT);
    ushort16* WeaT = (ushort16*)(ws + WS_WEAT);
    ushort16* Whg  = (ushort16*)(ws + WS_WHG);
    ushort16* W2i  = (ushort16*)(ws + WS_W2I);
    ushort16* WoB  = (ushort16*)(ws + WS_WOB);
    ushort16* WInit= (ushort16*)(ws + WS_WINIT);
    ushort16* encS = (ushort16*)(ws + WS_ENCS);

    k_sort<<<1, 64, 0, stream>>>(caplen, captions, out, wsi);
    k_prep_enc<<<dim3(64, 8), 256, 0, stream>>>(enc, sortidx, encS, meanB);
    k_transpose_all<<<1088, 256, 0, stream>>>(Wea, Wda, Wbe, Wih, Wic, WeaT, Whg, WInit);
    k_prep_small<<<13376, 256, 0, stream>>>(Wout, Wemb, wsi + WS_CAPS / 4, WIH, WHH,
                                            WoB, embB, W2i);

    // h0 | c0 = meanB @ WInit^T  -> hb0, cb0
    mgemm<64, 64, 32, 32, 6, 0><<<dim3(16, 1), 256, 0, stream>>>(
        meanB, ENC_, WInit, ENC_, hb0, cb0, 0, 1024, ENC_, bih, bic, nullptr);
    // enc_proj -> ept bf16: BM=BN=64, grid 1568 (6 blk/CU), XCD-chunked
    mgemm<64, 64, 32, 32, 1, 1><<<1568, 256, 0, stream>>>(
        encS, ENC_, WeaT, ENC_, ept, nullptr, A_, A_, ENC_, bea, nullptr, nullptr);

    for (int t = 0; t < T_; ++t) {
        int pp = (t > 0) ? ((t - 1) & 1) : 0;
        float* c_in  = pp ? cb1 : cb0;
        float* c_out = (t & 1) ? cb1 : cb0;
        ushort16* h_in  = pp ? hb1 : hb0;
        ushort16* h_out = (t & 1) ? hb1 : hb0;
        // fused LSTM(t-1) + das|gate GEMM (40 blocks)
        k_dasgate<<<40, 256, 0, stream>>>(gpart, bIH, bHH, dlen, c_in, c_out,
                                          h_in, h_out, histB, Whg, bda, bbe,
                                          das, gate, t);
        k_att<<<dim3(64, 2), 512, 0, stream>>>(das, gate, Wfa, bfa, ept, encS,
                                               dlen, ctxg, out, t);
        k_gates<<<256, 256, 0, stream>>>(embB, ctxg, h_out, W2i, gpart, t);
    }
    // finalize hist(18) = LSTM of gpart(18) with c_18 (in cb0, t=18 even)
    k_lstm<<<128, 256, 0, stream>>>(gpart, bIH, bHH, dlen, cb0, hb0, hb1, histB, 18);

    // all preds in one GEMM, XCD-swizzled
    mgemm<128, 128, 64, 64, 7, 2><<<800, 256, 0, stream>>>(
        histB, D_, WoB, D_, out + OFF_PREDS, nullptr, 0, V_, D_, bout, nullptr,
        dlen);
}

// Round 13
// 1634.054 us; speedup vs baseline: 2.6903x; 2.6903x over previous
//
#include <hip/hip_runtime.h>

#define B_ 64
#define P_ 196
#define ENC_ 2048
#define L_ 20
#define T_ 19
#define A_ 512
#define D_ 512
#define E_ 512
#define V_ 10000

// output offsets (float elements)
#define OFF_PREDS 0
#define OFF_CAPS  12160000
#define OFF_DLEN  12161280
#define OFF_ALPH  12161344
#define OFF_SIDX  12399680

// workspace offsets (bytes) — total ~104.5 MB
#define WS_SORT   0          /* 64 int */
#define WS_DLEN   1024
#define WS_CAPS   2048       /* 64*20 int */
#define WS_DAS    114688     /* 64*512 f32 */
#define WS_GATE   245760     /* 64*2048 f32 */
#define WS_HB0    770048     /* 64*512 bf16 */
#define WS_HB1    835584
#define WS_C      901120     /* 64*512 f32 */
#define WS_CTXG   1032192    /* 64*2048 bf16 */
#define WS_MEANB  1294336    /* 64*2048 bf16 */
#define WS_HIST   1556480    /* 1280*512 bf16 */
#define WS_EMB    2867200    /* 1216*512 bf16 */
#define WS_GPART  4194304    /* 8*64*2048 f32 = 4 MB */
#define WS_EPT    8388608    /* 12544*512 bf16 = 12.85 MB */
#define WS_WEAT   21233664   /* 512*2048 bf16 */
#define WS_WHG    23330816   /* 2560*512 bf16 */
#define WS_W2I    25952256   /* 2048*3072 bf16 */
#define WS_WOB    38535168   /* 10112*512 bf16 */
#define WS_WINIT  48889856   /* 1024*2048 bf16 */
#define WS_ENCS   53084160   /* 12544*2048 bf16 = 51.38 MB -> end 104464384 */

typedef __attribute__((ext_vector_type(8))) short short8v;
typedef __attribute__((ext_vector_type(4))) float f32x4;
typedef unsigned int uint32;
typedef unsigned short ushort16;

__device__ __forceinline__ float ftanh(float x){ float e=__expf(2.f*x); return 1.f-2.f/(e+1.f); }
__device__ __forceinline__ float fsigm(float x){ return 1.f/(1.f+__expf(-x)); }
__device__ __forceinline__ ushort16 f2b(float f){
    uint32 u = __float_as_uint(f);
    uint32 r = (u + 0x7FFFu + ((u >> 16) & 1u)) >> 16;
    return (ushort16)r;
}
__device__ __forceinline__ uint32 pack_b2(float a, float b){
    return (uint32)f2b(a) | ((uint32)f2b(b) << 16);
}
__device__ __forceinline__ float b2f_lo(uint32 w){ return __uint_as_float(w << 16); }
__device__ __forceinline__ float b2f_hi(uint32 w){ return __uint_as_float(w & 0xFFFF0000u); }
__device__ __forceinline__ float b1f(ushort16 x){ return __uint_as_float((uint32)x << 16); }

// ---------------------------------------------------------------- parallel rank sort + meta
__global__ void k_sort(const int* __restrict__ cap_len, const int* __restrict__ captions,
                       float* __restrict__ out, int* __restrict__ wsi)
{
    __shared__ int len_s[B_];
    int tid = threadIdx.x;        // 64 threads
    int len = cap_len[tid];
    len_s[tid] = len;
    __syncthreads();
    int rank = 0;
#pragma unroll
    for (int j = 0; j < B_; ++j) {
        int lj = len_s[j];
        rank += (lj > len) || (lj == len && j < tid);
    }
    wsi[WS_SORT / 4 + rank] = tid;
    wsi[WS_DLEN / 4 + rank] = len - 1;
    out[OFF_SIDX + rank] = (float)tid;
    out[OFF_DLEN + rank] = (float)(len - 1);
#pragma unroll
    for (int l = 0; l < L_; ++l) {
        int cv = captions[tid * L_ + l];
        wsi[WS_CAPS / 4 + rank * L_ + l] = cv;
        out[OFF_CAPS + rank * L_ + l] = (float)cv;
    }
}

// ---------------------------------------------------------------- fused: sorted bf16 enc copy + mean
// grid (64, 8): block (b, e-slice of 256). Reads enc f32 once; writes encS + meanB.
__global__ __launch_bounds__(256) void k_prep_enc(const float* __restrict__ enc,
                                                  const int* __restrict__ sortidx,
                                                  ushort16* __restrict__ encS,
                                                  ushort16* __restrict__ meanB)
{
    int b = blockIdx.x;
    int e = blockIdx.y * 256 + threadIdx.x;
    long sbase = (long)sortidx[b] * P_ * ENC_ + e;
    long dbase = (long)b * P_ * ENC_ + e;
    float s = 0.f;
    for (int p = 0; p < P_; ++p) {
        float v = enc[sbase + (long)p * ENC_];
        s += v;
        encS[dbase + (long)p * ENC_] = f2b(v);
    }
    meanB[b * ENC_ + e] = f2b(s * (1.f / (float)P_));
}

// ---------------------------------------------------------------- merged transpose+cast (5 weights, 1 launch)
// ranges: [0,256) Wea | [256,320) Wda | [320,576) Wbe | [576,832) Wih | [832,1088) Wic
__global__ __launch_bounds__(256) void k_transpose_all(
    const float* __restrict__ Wea, const float* __restrict__ Wda,
    const float* __restrict__ Wbe, const float* __restrict__ Wih,
    const float* __restrict__ Wic,
    ushort16* __restrict__ WeaT, ushort16* __restrict__ Whg,
    ushort16* __restrict__ WInit)
{
    __shared__ float tile[64][65];
    int id = blockIdx.x;
    const float* src; ushort16* dst; int R, C, bx, by;
    if (id < 256)      { src = Wea; dst = WeaT;                R = 2048; C = 512;  int i2 = id;        bx = i2 & 7;  by = i2 >> 3; }
    else if (id < 320) { src = Wda; dst = Whg;                 R = 512;  C = 512;  int i2 = id - 256;  bx = i2 & 7;  by = i2 >> 3; }
    else if (id < 576) { src = Wbe; dst = Whg + 512 * 512;     R = 512;  C = 2048; int i2 = id - 320;  bx = i2 & 31; by = i2 >> 5; }
    else if (id < 832) { src = Wih; dst = WInit;               R = 2048; C = 512;  int i2 = id - 576;  bx = i2 & 7;  by = i2 >> 3; }
    else               { src = Wic; dst = WInit + 512 * 2048;  R = 2048; C = 512;  int i2 = id - 832;  bx = i2 & 7;  by = i2 >> 3; }
    int c0 = bx * 64, r0 = by * 64;
    int lx = threadIdx.x & 63, ly = threadIdx.x >> 6;
#pragma unroll
    for (int i = 0; i < 16; ++i) {
        int r = ly * 16 + i;
        tile[lx][r] = src[(long)(r0 + r) * C + c0 + lx];
    }
    __syncthreads();
#pragma unroll
    for (int i = 0; i < 16; ++i) {
        int cr = ly * 16 + i;
        dst[(long)(c0 + cr) * R + r0 + lx] = f2b(tile[cr][lx]);
    }
}

// ---------------------------------------------------------------- merged small prep: wout | emb | w2i
// ranges: [0,10112) wout rows | [10112,11328) emb rows | [11328,13376) w2i rows
__global__ __launch_bounds__(256) void k_prep_small(
    const float* __restrict__ Wout, const float* __restrict__ embedding,
    const int* __restrict__ caps, const float* __restrict__ WIH,
    const float* __restrict__ WHH,
    ushort16* __restrict__ WoB, ushort16* __restrict__ embB,
    ushort16* __restrict__ W2i)
{
    int id = blockIdx.x;
    if (id < 10112) {
        int r = id, k = threadIdx.x * 2;
        uint32 v = 0;
        if (r < V_) {
            float2 f = *(const float2*)(Wout + (long)r * 512 + k);
            v = pack_b2(f.x, f.y);
        }
        *(uint32*)(WoB + (long)r * 512 + k) = v;
    } else if (id < 11328) {
        int m = id - 10112;                    // m = t*64+b
        int tok = caps[(m & 63) * L_ + (m >> 6)];
        int k = threadIdx.x * 2;
        float2 v = *(const float2*)(embedding + (long)tok * E_ + k);
        *(uint32*)(embB + (long)m * E_ + k) = pack_b2(v.x, v.y);
    } else {
        int r = id - 11328;                    // 0..2047, r = 4d+q
        int d = r >> 2, q = r & 3;
        int n = q * 512 + d;
        for (int cch = threadIdx.x; cch < 384; cch += 256) {
            int kof = cch * 8;
            const float* s = (kof < 2560) ? (WIH + (long)n * 2560 + kof)
                                          : (WHH + (long)n * 512 + (kof - 2560));
            float4 f0 = *(const float4*)s;
            float4 f1 = *(const float4*)(s + 4);
            uint4 v; v.x = pack_b2(f0.x, f0.y); v.y = pack_b2(f0.z, f0.w);
            v.z = pack_b2(f1.x, f1.y); v.w = pack_b2(f1.z, f1.w);
            *(uint4*)(W2i + (long)r * 3072 + kof) = v;
        }
    }
}

// ---------------------------------------------------------------- bf16 MFMA GEMM
// EPI 1: bf16 C = v+bias
// EPI 2: gn<512 -> das=v+bias; else gate=sigmoid(v+bias2)
// EPI 6: gn<512 -> hb=f2b(v+bias); else c=v+bias2
// EPI 7: b=gm&63,tt=gm>>6; tt<T_ guard; preds=(tt<dlen)?v+bias:0
// SWZ 1: enc_proj 1D grid 784=98x8 -> (m<196, n<4), 4 same-A blocks co-XCD
// SWZ 2: pred     1D grid 800 -> (x<79, y<10), same-B blocks co-XCD
template<int BM, int BN, int WM, int WN, int EPI, int SWZ>
__global__ __launch_bounds__(256) void mgemm(
    const ushort16* __restrict__ Amat, int lda1,
    const ushort16* __restrict__ Bmat, int ldb,
    void* __restrict__ Cout, void* __restrict__ Cout2, int ldc, int N, int K,
    const float* __restrict__ bias, const float* __restrict__ bias2,
    const int* __restrict__ dlen)
{
    int bx, by;
    if (SWZ == 1) {
        int id = blockIdx.x;                 // 784 = 98 per XCD x 8 XCDs (exact)
        int xcd = id & 7, idx = id >> 3;     // idx 0..97
        int j = xcd * 98 + idx;              // contiguous j-chunk per XCD
        by = j >> 2;                         // m-tile 0..195 (same-A quad co-XCD)
        bx = j & 3;                          // n-tile 0..3
    } else if (SWZ == 2) {
        int id = blockIdx.x;                 // 800 launched, 790 logical
        bx = (id / 80) * 8 + (id & 7);       // same-bx blocks differ by 8 -> same XCD
        by = (id >> 3) % 10;
        if (bx >= 79) return;
    } else { bx = blockIdx.x; by = blockIdx.y; }

    __shared__ __align__(16) ushort16 As[BM * 64];
    __shared__ __align__(16) ushort16 Bs[BN * 64];
    const int tid = threadIdx.x;
    const int m0 = by * BM, n0 = bx * BN;
    const int lane = tid & 63, wid = tid >> 6;
    constexpr int NWC = BN / WN;
    const int wr = wid / NWC, wc = wid % NWC;
    constexpr int FM = WM / 16, FN = WN / 16;
    f32x4 acc[FM][FN] = {};

    for (int k0 = 0; k0 < K; k0 += 64) {
        for (int i = tid; i < BM * 8; i += 256) {
            int r = i >> 3, ck = i & 7;
            uint4 val = *(const uint4*)(Amat + (long)(m0 + r) * lda1 + k0 + ck * 8);
            int bo = (r * 128 + ck * 16) ^ ((r & 7) << 4);
            *(uint4*)((char*)As + bo) = val;
        }
        for (int i = tid; i < BN * 8; i += 256) {
            int r = i >> 3, ck = i & 7;
            uint4 val = *(const uint4*)(Bmat + (long)(n0 + r) * ldb + k0 + ck * 8);
            int bo = (r * 128 + ck * 16) ^ ((r & 7) << 4);
            *(uint4*)((char*)Bs + bo) = val;
        }
        __syncthreads();
#pragma unroll
        for (int kk = 0; kk < 64; kk += 32) {
            short8v af[FM], bfr[FN];
#pragma unroll
            for (int f = 0; f < FM; ++f) {
                int r = wr * WM + f * 16 + (lane & 15);
                int bo = (r * 128 + (kk + ((lane >> 4) << 3)) * 2) ^ ((r & 7) << 4);
                af[f] = *(const short8v*)((const char*)As + bo);
            }
#pragma unroll
            for (int f = 0; f < FN; ++f) {
                int r = wc * WN + f * 16 + (lane & 15);
                int bo = (r * 128 + (kk + ((lane >> 4) << 3)) * 2) ^ ((r & 7) << 4);
                bfr[f] = *(const short8v*)((const char*)Bs + bo);
            }
#pragma unroll
            for (int fm = 0; fm < FM; ++fm)
#pragma unroll
                for (int fn = 0; fn < FN; ++fn)
                    acc[fm][fn] = __builtin_amdgcn_mfma_f32_16x16x32_bf16(
                        af[fm], bfr[fn], acc[fm][fn], 0, 0, 0);
        }
        __syncthreads();
    }

    int rr = lane >> 4, cc = lane & 15;
#pragma unroll
    for (int fm = 0; fm < FM; ++fm) {
#pragma unroll
        for (int fn = 0; fn < FN; ++fn) {
#pragma unroll
            for (int r = 0; r < 4; ++r) {
                int gm = m0 + wr * WM + fm * 16 + rr * 4 + r;
                int gn = n0 + wc * WN + fn * 16 + cc;
                float v = acc[fm][fn][r];
                if (EPI == 1) {
                    ((ushort16*)Cout)[(long)gm * ldc + gn] = f2b(v + bias[gn]);
                } else if (EPI == 2) {
                    if (gn < 512) ((float*)Cout)[gm * 512 + gn] = v + bias[gn];
                    else ((float*)Cout2)[gm * ENC_ + (gn - 512)] = fsigm(v + bias2[gn - 512]);
                } else if (EPI == 6) {
                    if (gn < 512) ((ushort16*)Cout)[gm * 512 + gn] = f2b(v + bias[gn]);
                    else ((float*)Cout2)[gm * 512 + (gn - 512)] = v + bias2[gn - 512];
                } else if (EPI == 7) {
                    int bq = gm & 63, tt = gm >> 6;
                    if (gn < N && tt < T_)   // tt<T_: rows >=1216 are padding (R8 bug lesson)
                        ((float*)Cout)[((long)bq * T_ + tt) * V_ + gn] =
                            (tt < dlen[bq]) ? v + bias[gn] : 0.f;
                }
            }
        }
    }
}

// ---------------------------------------------------------------- attention: scores+softmax+alpha+ctx
// grid (64, 2), 512 threads: scores+softmax redundant per eg; ctx split by eg (1024 cols each)
__global__ __launch_bounds__(512) void k_att(
    const float* __restrict__ das, const float* __restrict__ gate,
    const float* __restrict__ Wfa, const float* __restrict__ bfa,
    const ushort16* __restrict__ ept, const ushort16* __restrict__ encS,
    const int* __restrict__ dlen,
    ushort16* __restrict__ ctxg, float* __restrict__ out, int t)
{
    int b = blockIdx.x, eg = blockIdx.y;
    int tid = threadIdx.x;
    if (t >= dlen[b]) {
        if (eg == 0 && tid < P_) out[OFF_ALPH + ((long)b * T_ + t) * P_ + tid] = 0.f;
        return;
    }
    __shared__ float al[P_ + 4];
    __shared__ float red[512];
    int lane = tid & 63, wv = tid >> 6;
    // scores: waves split p, lanes split a
    float wf8[8], da8[8];
    {
        const float* wp = Wfa + lane * 8;
        const float* dp = das + b * 512 + lane * 8;
#pragma unroll
        for (int j = 0; j < 8; ++j) { wf8[j] = wp[j]; da8[j] = dp[j]; }
    }
    float b0 = bfa[0];
    for (int p = wv; p < P_; p += 8) {
        uint4 u = *(const uint4*)(ept + ((long)(b * P_ + p)) * 512 + lane * 8);
        float s = 0.f;
        s += wf8[0] * ftanh(b2f_lo(u.x) + da8[0]);
        s += wf8[1] * ftanh(b2f_hi(u.x) + da8[1]);
        s += wf8[2] * ftanh(b2f_lo(u.y) + da8[2]);
        s += wf8[3] * ftanh(b2f_hi(u.y) + da8[3]);
        s += wf8[4] * ftanh(b2f_lo(u.z) + da8[4]);
        s += wf8[5] * ftanh(b2f_hi(u.z) + da8[5]);
        s += wf8[6] * ftanh(b2f_lo(u.w) + da8[6]);
        s += wf8[7] * ftanh(b2f_hi(u.w) + da8[7]);
#pragma unroll
        for (int off = 32; off > 0; off >>= 1) s += __shfl_xor(s, off);
        if (lane == 0) al[p] = s + b0;
    }
    __syncthreads();
    // softmax over 196 (512-thread tree)
    float sc = (tid < P_) ? al[tid] : -1e30f;
    red[tid] = sc;
    __syncthreads();
    for (int s = 256; s > 0; s >>= 1) {
        if (tid < s) red[tid] = fmaxf(red[tid], red[tid + s]);
        __syncthreads();
    }
    float mx = red[0];
    __syncthreads();
    float e = (tid < P_) ? __expf(sc - mx) : 0.f;
    red[tid] = e;
    __syncthreads();
    for (int s = 256; s > 0; s >>= 1) {
        if (tid < s) red[tid] += red[tid + s];
        __syncthreads();
    }
    float inv = 1.f / red[0];
    __syncthreads();
    if (tid < P_) al[tid] = e * inv;
    __syncthreads();
    if (eg == 0 && tid < P_)
        out[OFF_ALPH + ((long)b * T_ + t) * P_ + tid] = al[tid];
    // ctx: 2 bf16 cols per thread from encS, this block's 1024-col slice
    int e0 = eg * 1024 + tid * 2;
    long base = ((long)b * P_) * ENC_ + e0;
    float a0 = 0.f, a1 = 0.f;
#pragma unroll 4
    for (int p = 0; p < P_; ++p) {
        uint32 v = *(const uint32*)(encS + base + (long)p * ENC_);
        float alp = al[p];
        a0 += alp * b2f_lo(v); a1 += alp * b2f_hi(v);
    }
    float2 g2 = *(const float2*)(gate + b * ENC_ + e0);
    *(uint32*)(ctxg + b * ENC_ + e0) = pack_b2(g2.x * a0, g2.y * a1);
}

// ---------------------------------------------------------------- gates GEMM split-K (256 blocks) — R7 proven
__global__ __launch_bounds__(256) void k_gates(
    const ushort16* __restrict__ embB, const ushort16* __restrict__ ctxg,
    const ushort16* __restrict__ hin,  const ushort16* __restrict__ W2i,
    float* __restrict__ gpart, int t)
{
    __shared__ __align__(16) ushort16 As[64 * 64];
    __shared__ __align__(16) ushort16 Bs[64 * 64];
    const int tid = threadIdx.x;
    const int nt = blockIdx.x >> 3, ks = blockIdx.x & 7;
    const int n0 = nt * 64, kbeg = ks * 384;
    const int lane = tid & 63, wid = tid >> 6;
    const int wr = wid >> 1, wc = wid & 1;
    f32x4 acc[2][2] = {};

    for (int k0 = kbeg; k0 < kbeg + 384; k0 += 64) {
        for (int i = tid; i < 512; i += 256) {
            int r = i >> 3, ck = i & 7;
            int kk = k0 + ck * 8;
            const ushort16* src;
            if (kk < 512)       src = embB + ((long)(t * 64 + r)) * 512 + kk;
            else if (kk < 2560) src = ctxg + (long)r * ENC_ + (kk - 512);
            else                src = hin + (long)r * 512 + (kk - 2560);
            uint4 val = *(const uint4*)src;
            int bo = (r * 128 + ck * 16) ^ ((r & 7) << 4);
            *(uint4*)((char*)As + bo) = val;
        }
        for (int i = tid; i < 512; i += 256) {
            int r = i >> 3, ck = i & 7;
            uint4 val = *(const uint4*)(W2i + (long)(n0 + r) * 3072 + k0 + ck * 8);
            int bo = (r * 128 + ck * 16) ^ ((r & 7) << 4);
            *(uint4*)((char*)Bs + bo) = val;
        }
        __syncthreads();
#pragma unroll
        for (int kk = 0; kk < 64; kk += 32) {
            short8v af[2], bfr[2];
#pragma unroll
            for (int f = 0; f < 2; ++f) {
                int r = wr * 32 + f * 16 + (lane & 15);
                int bo = (r * 128 + (kk + ((lane >> 4) << 3)) * 2) ^ ((r & 7) << 4);
                af[f] = *(const short8v*)((const char*)As + bo);
            }
#pragma unroll
            for (int f = 0; f < 2; ++f) {
                int r = wc * 32 + f * 16 + (lane & 15);
                int bo = (r * 128 + (kk + ((lane >> 4) << 3)) * 2) ^ ((r & 7) << 4);
                bfr[f] = *(const short8v*)((const char*)Bs + bo);
            }
#pragma unroll
            for (int fm = 0; fm < 2; ++fm)
#pragma unroll
                for (int fn = 0; fn < 2; ++fn)
                    acc[fm][fn] = __builtin_amdgcn_mfma_f32_16x16x32_bf16(
                        af[fm], bfr[fn], acc[fm][fn], 0, 0, 0);
        }
        __syncthreads();
    }
    int rr = lane >> 4, cc = lane & 15;
#pragma unroll
    for (int fm = 0; fm < 2; ++fm)
#pragma unroll
        for (int fn = 0; fn < 2; ++fn)
#pragma unroll
            for (int r = 0; r < 4; ++r) {
                int gm = wr * 32 + fm * 16 + rr * 4 + r;
                int gn = n0 + wc * 32 + fn * 16 + cc;
                gpart[((long)(ks * 64 + gm)) * ENC_ + gn] = acc[fm][fn][r];
            }
}

// ---------------------------------------------------------------- LSTM pointwise (reduce 8 partials) — R7 proven
__global__ __launch_bounds__(256) void k_lstm(
    const float* __restrict__ gpart,
    const float* __restrict__ bIH, const float* __restrict__ bHH,
    const int* __restrict__ dlen, float* __restrict__ c,
    const ushort16* __restrict__ hin, ushort16* __restrict__ hout,
    ushort16* __restrict__ histB, int t)
{
    int idx = blockIdx.x * 256 + threadIdx.x;   // 128 blocks -> 64 b x 512 d
    int b = idx >> 9, d = idx & 511;
    long off = (long)b * 512 + d;
    if (t < dlen[b]) {
        float s0 = 0.f, s1 = 0.f, s2 = 0.f, s3 = 0.f;
#pragma unroll
        for (int ks = 0; ks < 8; ++ks) {
            float4 gp = *(const float4*)(gpart + ((long)(ks * 64 + b)) * ENC_ + 4 * d);
            s0 += gp.x; s1 += gp.y; s2 += gp.z; s3 += gp.w;
        }
        float g0 = s0 + bIH[d] + bHH[d];
        float g1 = s1 + bIH[512 + d] + bHH[512 + d];
        float g2v = s2 + bIH[1024 + d] + bHH[1024 + d];
        float g3 = s3 + bIH[1536 + d] + bHH[1536 + d];
        float i_ = fsigm(g0), f_ = fsigm(g1), gg = ftanh(g2v), o_ = fsigm(g3);
        float cn = f_ * c[off] + i_ * gg;
        float hn = o_ * ftanh(cn);
        c[off] = cn;
        ushort16 hv = f2b(hn);
        hout[off] = hv;
        histB[((long)(t * 64 + b)) * 512 + d] = hv;
    } else {
        hout[off] = hin[off];
    }
}

// ---------------------------------------------------------------- launch
extern "C" void kernel_launch(void* const* d_in, const int* in_sizes, int n_in,
                              void* d_out, int out_size, void* d_ws, size_t ws_size,
                              hipStream_t stream)
{
    (void)in_sizes; (void)n_in; (void)out_size; (void)ws_size;
    const float* enc      = (const float*)d_in[0];
    const int*   captions = (const int*)d_in[1];
    const int*   caplen   = (const int*)d_in[2];
    const float* Wemb     = (const float*)d_in[3];
    const float* Wea = (const float*)d_in[4];  const float* bea = (const float*)d_in[5];
    const float* Wda = (const float*)d_in[6];  const float* bda = (const float*)d_in[7];
    const float* Wfa = (const float*)d_in[8];  const float* bfa = (const float*)d_in[9];
    const float* Wih = (const float*)d_in[10]; const float* bih = (const float*)d_in[11];
    const float* Wic = (const float*)d_in[12]; const float* bic = (const float*)d_in[13];
    const float* Wbe = (const float*)d_in[14]; const float* bbe = (const float*)d_in[15];
    const float* WIH = (const float*)d_in[16]; const float* bIH = (const float*)d_in[17];
    const float* WHH = (const float*)d_in[18]; const float* bHH = (const float*)d_in[19];
    const float* Wout = (const float*)d_in[20]; const float* bout = (const float*)d_in[21];

    float* out = (float*)d_out;
    char*  ws  = (char*)d_ws;
    int*   wsi = (int*)ws;
    const int* dlen = wsi + WS_DLEN / 4;
    const int* sortidx = wsi + WS_SORT / 4;
    float* das     = (float*)(ws + WS_DAS);
    float* gate    = (float*)(ws + WS_GATE);
    ushort16* hb0  = (ushort16*)(ws + WS_HB0);
    ushort16* hb1  = (ushort16*)(ws + WS_HB1);
    float* c       = (float*)(ws + WS_C);
    ushort16* ctxg = (ushort16*)(ws + WS_CTXG);
    ushort16* meanB= (ushort16*)(ws + WS_MEANB);
    ushort16* histB= (ushort16*)(ws + WS_HIST);
    ushort16* embB = (ushort16*)(ws + WS_EMB);
    float* gpart   = (float*)(ws + WS_GPART);
    ushort16* ept  = (ushort16*)(ws + WS_EPT);
    ushort16* WeaT = (ushort16*)(ws + WS_WEAT);
    ushort16* Whg  = (ushort16*)(ws + WS_WHG);
    ushort16* W2i  = (ushort16*)(ws + WS_W2I);
    ushort16* WoB  = (ushort16*)(ws + WS_WOB);
    ushort16* WInit= (ushort16*)(ws + WS_WINIT);
    ushort16* encS = (ushort16*)(ws + WS_ENCS);

    k_sort<<<1, 64, 0, stream>>>(caplen, captions, out, wsi);
    k_prep_enc<<<dim3(64, 8), 256, 0, stream>>>(enc, sortidx, encS, meanB);
    k_transpose_all<<<1088, 256, 0, stream>>>(Wea, Wda, Wbe, Wih, Wic, WeaT, Whg, WInit);
    k_prep_small<<<13376, 256, 0, stream>>>(Wout, Wemb, wsi + WS_CAPS / 4, WIH, WHH,
                                            WoB, embB, W2i);

    // h0 | c0 = meanB @ WInit^T
    mgemm<64, 64, 32, 32, 6, 0><<<dim3(16, 1), 256, 0, stream>>>(
        meanB, ENC_, WInit, ENC_, hb0, c, 0, 1024, ENC_, bih, bic, nullptr);
    // enc_proj -> ept bf16 [b*196+p][a]: BM=64 x BN=128, 784 blocks (3/CU), XCD-chunked
    mgemm<64, 128, 32, 64, 1, 1><<<784, 256, 0, stream>>>(
        encS, ENC_, WeaT, ENC_, ept, nullptr, A_, A_, ENC_, bea, nullptr, nullptr);

    for (int t = 0; t < T_; ++t) {
        ushort16* hcur = (t & 1) ? hb1 : hb0;
        ushort16* hnxt = (t & 1) ? hb0 : hb1;
        // das | beta-gate (MFMA, 40 blocks)
        mgemm<64, 64, 32, 32, 2, 0><<<dim3(40, 1), 256, 0, stream>>>(
            hcur, D_, Whg, D_, das, gate, 0, 2560, D_, bda, bbe, nullptr);
        k_att<<<dim3(64, 2), 512, 0, stream>>>(das, gate, Wfa, bfa, ept, encS,
                                               dlen, ctxg, out, t);
        k_gates<<<256, 256, 0, stream>>>(embB, ctxg, hcur, W2i, gpart, t);
        k_lstm<<<128, 256, 0, stream>>>(gpart, bIH, bHH, dlen, c, hcur, hnxt, histB, t);
    }
    // all preds in one GEMM, XCD-swizzled (B-tile shared blocks co-XCD)
    mgemm<128, 128, 64, 64, 7, 2><<<800, 256, 0, stream>>>(
        histB, D_, WoB, D_, out + OFF_PREDS, nullptr, 0, V_, D_, bout, nullptr,
        dlen);
}

// Round 14
// 1437.902 us; speedup vs baseline: 3.0573x; 1.1364x over previous
//
#include <hip/hip_runtime.h>

#define B_ 64
#define P_ 196
#define ENC_ 2048
#define L_ 20
#define T_ 19
#define A_ 512
#define D_ 512
#define E_ 512
#define V_ 10000

// output offsets (float elements)
#define OFF_PREDS 0
#define OFF_CAPS  12160000
#define OFF_DLEN  12161280
#define OFF_ALPH  12161344
#define OFF_SIDX  12399680

// workspace offsets (bytes) — total ~104.5 MB
#define WS_SORT   0          /* 64 int */
#define WS_DLEN   1024
#define WS_CAPS   2048       /* 64*20 int */
#define WS_DAS    114688     /* 64*512 f32 */
#define WS_GATE   245760     /* 64*2048 f32 */
#define WS_HB0    770048     /* 64*512 bf16 */
#define WS_HB1    835584
#define WS_C      901120     /* 64*512 f32 */
#define WS_CTXG   1032192    /* 64*2048 bf16 */
#define WS_MEANB  1294336    /* 64*2048 bf16 */
#define WS_HIST   1556480    /* 1280*512 bf16 */
#define WS_EMB    2867200    /* 1216*512 bf16 */
#define WS_GPART  4194304    /* 8*64*2048 f32 = 4 MB */
#define WS_EPT    8388608    /* 12544*512 bf16 = 12.85 MB */
#define WS_WEAT   21233664   /* 512*2048 bf16 */
#define WS_WHG    23330816   /* 2560*512 bf16 */
#define WS_W2I    25952256   /* 2048*3072 bf16 */
#define WS_WOB    38535168   /* 10112*512 bf16 */
#define WS_WINIT  48889856   /* 1024*2048 bf16 */
#define WS_ENCS   53084160   /* 12544*2048 bf16 = 51.38 MB -> end 104464384 */

typedef __attribute__((ext_vector_type(8))) short short8v;
typedef __attribute__((ext_vector_type(4))) float f32x4;
typedef unsigned int uint32;
typedef unsigned short ushort16;

__device__ __forceinline__ float ftanh(float x){ float e=__expf(2.f*x); return 1.f-2.f/(e+1.f); }
__device__ __forceinline__ float fsigm(float x){ return 1.f/(1.f+__expf(-x)); }
__device__ __forceinline__ ushort16 f2b(float f){
    uint32 u = __float_as_uint(f);
    uint32 r = (u + 0x7FFFu + ((u >> 16) & 1u)) >> 16;
    return (ushort16)r;
}
__device__ __forceinline__ uint32 pack_b2(float a, float b){
    return (uint32)f2b(a) | ((uint32)f2b(b) << 16);
}
__device__ __forceinline__ float b2f_lo(uint32 w){ return __uint_as_float(w << 16); }
__device__ __forceinline__ float b2f_hi(uint32 w){ return __uint_as_float(w & 0xFFFF0000u); }
__device__ __forceinline__ float b1f(ushort16 x){ return __uint_as_float((uint32)x << 16); }

// ---------------------------------------------------------------- parallel rank sort + meta
__global__ void k_sort(const int* __restrict__ cap_len, const int* __restrict__ captions,
                       float* __restrict__ out, int* __restrict__ wsi)
{
    __shared__ int len_s[B_];
    int tid = threadIdx.x;        // 64 threads
    int len = cap_len[tid];
    len_s[tid] = len;
    __syncthreads();
    int rank = 0;
#pragma unroll
    for (int j = 0; j < B_; ++j) {
        int lj = len_s[j];
        rank += (lj > len) || (lj == len && j < tid);
    }
    wsi[WS_SORT / 4 + rank] = tid;
    wsi[WS_DLEN / 4 + rank] = len - 1;
    out[OFF_SIDX + rank] = (float)tid;
    out[OFF_DLEN + rank] = (float)(len - 1);
#pragma unroll
    for (int l = 0; l < L_; ++l) {
        int cv = captions[tid * L_ + l];
        wsi[WS_CAPS / 4 + rank * L_ + l] = cv;
        out[OFF_CAPS + rank * L_ + l] = (float)cv;
    }
}

// ---------------------------------------------------------------- fused: sorted bf16 enc copy + mean
// grid (64, 4): block (b, 512-col slice). float2 loads (8B/lane, G13).
__global__ __launch_bounds__(256) void k_prep_enc(const float* __restrict__ enc,
                                                  const int* __restrict__ sortidx,
                                                  ushort16* __restrict__ encS,
                                                  ushort16* __restrict__ meanB)
{
    int b = blockIdx.x;
    int e = blockIdx.y * 512 + threadIdx.x * 2;
    long sbase = (long)sortidx[b] * P_ * ENC_ + e;
    long dbase = (long)b * P_ * ENC_ + e;
    float s0 = 0.f, s1 = 0.f;
#pragma unroll 4
    for (int p = 0; p < P_; ++p) {
        float2 v = *(const float2*)(enc + sbase + (long)p * ENC_);
        s0 += v.x; s1 += v.y;
        *(uint32*)(encS + dbase + (long)p * ENC_) = pack_b2(v.x, v.y);
    }
    *(uint32*)(meanB + b * ENC_ + e) = pack_b2(s0 * (1.f / (float)P_),
                                               s1 * (1.f / (float)P_));
}

// ---------------------------------------------------------------- merged transpose+cast (5 weights, 1 launch)
// ranges: [0,256) Wea | [256,320) Wda | [320,576) Wbe | [576,832) Wih | [832,1088) Wic
__global__ __launch_bounds__(256) void k_transpose_all(
    const float* __restrict__ Wea, const float* __restrict__ Wda,
    const float* __restrict__ Wbe, const float* __restrict__ Wih,
    const float* __restrict__ Wic,
    ushort16* __restrict__ WeaT, ushort16* __restrict__ Whg,
    ushort16* __restrict__ WInit)
{
    __shared__ float tile[64][65];
    int id = blockIdx.x;
    const float* src; ushort16* dst; int R, C, bx, by;
    if (id < 256)      { src = Wea; dst = WeaT;                R = 2048; C = 512;  int i2 = id;        bx = i2 & 7;  by = i2 >> 3; }
    else if (id < 320) { src = Wda; dst = Whg;                 R = 512;  C = 512;  int i2 = id - 256;  bx = i2 & 7;  by = i2 >> 3; }
    else if (id < 576) { src = Wbe; dst = Whg + 512 * 512;     R = 512;  C = 2048; int i2 = id - 320;  bx = i2 & 31; by = i2 >> 5; }
    else if (id < 832) { src = Wih; dst = WInit;               R = 2048; C = 512;  int i2 = id - 576;  bx = i2 & 7;  by = i2 >> 3; }
    else               { src = Wic; dst = WInit + 512 * 2048;  R = 2048; C = 512;  int i2 = id - 832;  bx = i2 & 7;  by = i2 >> 3; }
    int c0 = bx * 64, r0 = by * 64;
    int lx = threadIdx.x & 63, ly = threadIdx.x >> 6;
#pragma unroll
    for (int i = 0; i < 16; ++i) {
        int r = ly * 16 + i;
        tile[lx][r] = src[(long)(r0 + r) * C + c0 + lx];
    }
    __syncthreads();
#pragma unroll
    for (int i = 0; i < 16; ++i) {
        int cr = ly * 16 + i;
        dst[(long)(c0 + cr) * R + r0 + lx] = f2b(tile[cr][lx]);
    }
}

// ---------------------------------------------------------------- merged small prep: wout | emb | w2i
// ranges: [0,10112) wout rows | [10112,11328) emb rows | [11328,13376) w2i rows
__global__ __launch_bounds__(256) void k_prep_small(
    const float* __restrict__ Wout, const float* __restrict__ embedding,
    const int* __restrict__ caps, const float* __restrict__ WIH,
    const float* __restrict__ WHH,
    ushort16* __restrict__ WoB, ushort16* __restrict__ embB,
    ushort16* __restrict__ W2i)
{
    int id = blockIdx.x;
    if (id < 10112) {
        int r = id, k = threadIdx.x * 2;
        uint32 v = 0;
        if (r < V_) {
            float2 f = *(const float2*)(Wout + (long)r * 512 + k);
            v = pack_b2(f.x, f.y);
        }
        *(uint32*)(WoB + (long)r * 512 + k) = v;
    } else if (id < 11328) {
        int m = id - 10112;                    // m = t*64+b
        int tok = caps[(m & 63) * L_ + (m >> 6)];
        int k = threadIdx.x * 2;
        float2 v = *(const float2*)(embedding + (long)tok * E_ + k);
        *(uint32*)(embB + (long)m * E_ + k) = pack_b2(v.x, v.y);
    } else {
        int r = id - 11328;                    // 0..2047, r = 4d+q
        int d = r >> 2, q = r & 3;
        int n = q * 512 + d;
        for (int cch = threadIdx.x; cch < 384; cch += 256) {
            int kof = cch * 8;
            const float* s = (kof < 2560) ? (WIH + (long)n * 2560 + kof)
                                          : (WHH + (long)n * 512 + (kof - 2560));
            float4 f0 = *(const float4*)s;
            float4 f1 = *(const float4*)(s + 4);
            uint4 v; v.x = pack_b2(f0.x, f0.y); v.y = pack_b2(f0.z, f0.w);
            v.z = pack_b2(f1.x, f1.y); v.w = pack_b2(f1.z, f1.w);
            *(uint4*)(W2i + (long)r * 3072 + kof) = v;
        }
    }
}

// ---------------------------------------------------------------- bf16 MFMA GEMM
// EPI 1: bf16 C = v+bias
// EPI 2: gn<512 -> das=v+bias; else gate=sigmoid(v+bias2)
// EPI 6: gn<512 -> hb=f2b(v+bias); else c=v+bias2
// EPI 7: b=gm&63,tt=gm>>6; tt<T_ guard; preds=(tt<dlen)?v+bias:0
// SWZ 1: enc_proj 1D grid 784=98x8 -> (m<196, n<4), 4 same-A blocks co-XCD
// SWZ 2: pred     1D grid 800 -> (x<79, y<10), same-B blocks co-XCD
template<int BM, int BN, int WM, int WN, int EPI, int SWZ>
__global__ __launch_bounds__(256) void mgemm(
    const ushort16* __restrict__ Amat, int lda1,
    const ushort16* __restrict__ Bmat, int ldb,
    void* __restrict__ Cout, void* __restrict__ Cout2, int ldc, int N, int K,
    const float* __restrict__ bias, const float* __restrict__ bias2,
    const int* __restrict__ dlen)
{
    int bx, by;
    if (SWZ == 1) {
        int id = blockIdx.x;                 // 784 = 98 per XCD x 8 XCDs (exact)
        int xcd = id & 7, idx = id >> 3;     // idx 0..97
        int j = xcd * 98 + idx;              // contiguous j-chunk per XCD
        by = j >> 2;                         // m-tile 0..195 (same-A quad co-XCD)
        bx = j & 3;                          // n-tile 0..3
    } else if (SWZ == 2) {
        int id = blockIdx.x;                 // 800 launched, 790 logical
        bx = (id / 80) * 8 + (id & 7);       // same-bx blocks differ by 8 -> same XCD
        by = (id >> 3) % 10;
        if (bx >= 79) return;
    } else { bx = blockIdx.x; by = blockIdx.y; }

    __shared__ __align__(16) ushort16 As[BM * 64];
    __shared__ __align__(16) ushort16 Bs[BN * 64];
    const int tid = threadIdx.x;
    const int m0 = by * BM, n0 = bx * BN;
    const int lane = tid & 63, wid = tid >> 6;
    constexpr int NWC = BN / WN;
    const int wr = wid / NWC, wc = wid % NWC;
    constexpr int FM = WM / 16, FN = WN / 16;
    f32x4 acc[FM][FN] = {};

    for (int k0 = 0; k0 < K; k0 += 64) {
        for (int i = tid; i < BM * 8; i += 256) {
            int r = i >> 3, ck = i & 7;
            uint4 val = *(const uint4*)(Amat + (long)(m0 + r) * lda1 + k0 + ck * 8);
            int bo = (r * 128 + ck * 16) ^ ((r & 7) << 4);
            *(uint4*)((char*)As + bo) = val;
        }
        for (int i = tid; i < BN * 8; i += 256) {
            int r = i >> 3, ck = i & 7;
            uint4 val = *(const uint4*)(Bmat + (long)(n0 + r) * ldb + k0 + ck * 8);
            int bo = (r * 128 + ck * 16) ^ ((r & 7) << 4);
            *(uint4*)((char*)Bs + bo) = val;
        }
        __syncthreads();
#pragma unroll
        for (int kk = 0; kk < 64; kk += 32) {
            short8v af[FM], bfr[FN];
#pragma unroll
            for (int f = 0; f < FM; ++f) {
                int r = wr * WM + f * 16 + (lane & 15);
                int bo = (r * 128 + (kk + ((lane >> 4) << 3)) * 2) ^ ((r & 7) << 4);
                af[f] = *(const short8v*)((const char*)As + bo);
            }
#pragma unroll
            for (int f = 0; f < FN; ++f) {
                int r = wc * WN + f * 16 + (lane & 15);
                int bo = (r * 128 + (kk + ((lane >> 4) << 3)) * 2) ^ ((r & 7) << 4);
                bfr[f] = *(const short8v*)((const char*)Bs + bo);
            }
#pragma unroll
            for (int fm = 0; fm < FM; ++fm)
#pragma unroll
                for (int fn = 0; fn < FN; ++fn)
                    acc[fm][fn] = __builtin_amdgcn_mfma_f32_16x16x32_bf16(
                        af[fm], bfr[fn], acc[fm][fn], 0, 0, 0);
        }
        __syncthreads();
    }

    int rr = lane >> 4, cc = lane & 15;
#pragma unroll
    for (int fm = 0; fm < FM; ++fm) {
#pragma unroll
        for (int fn = 0; fn < FN; ++fn) {
#pragma unroll
            for (int r = 0; r < 4; ++r) {
                int gm = m0 + wr * WM + fm * 16 + rr * 4 + r;
                int gn = n0 + wc * WN + fn * 16 + cc;
                float v = acc[fm][fn][r];
                if (EPI == 1) {
                    ((ushort16*)Cout)[(long)gm * ldc + gn] = f2b(v + bias[gn]);
                } else if (EPI == 2) {
                    if (gn < 512) ((float*)Cout)[gm * 512 + gn] = v + bias[gn];
                    else ((float*)Cout2)[gm * ENC_ + (gn - 512)] = fsigm(v + bias2[gn - 512]);
                } else if (EPI == 6) {
                    if (gn < 512) ((ushort16*)Cout)[gm * 512 + gn] = f2b(v + bias[gn]);
                    else ((float*)Cout2)[gm * 512 + (gn - 512)] = v + bias2[gn - 512];
                } else if (EPI == 7) {
                    int bq = gm & 63, tt = gm >> 6;
                    if (gn < N && tt < T_)   // tt<T_: rows >=1216 are padding (R8 bug lesson)
                        ((float*)Cout)[((long)bq * T_ + tt) * V_ + gn] =
                            (tt < dlen[bq]) ? v + bias[gn] : 0.f;
                }
            }
        }
    }
}

// ---------------------------------------------------------------- attention: scores+softmax+alpha+ctx
// grid (64, 2), 512 threads: scores+softmax redundant per eg; ctx split by eg (1024 cols each)
__global__ __launch_bounds__(512) void k_att(
    const float* __restrict__ das, const float* __restrict__ gate,
    const float* __restrict__ Wfa, const float* __restrict__ bfa,
    const ushort16* __restrict__ ept, const ushort16* __restrict__ encS,
    const int* __restrict__ dlen,
    ushort16* __restrict__ ctxg, float* __restrict__ out, int t)
{
    int b = blockIdx.x, eg = blockIdx.y;
    int tid = threadIdx.x;
    if (t >= dlen[b]) {
        if (eg == 0 && tid < P_) out[OFF_ALPH + ((long)b * T_ + t) * P_ + tid] = 0.f;
        return;
    }
    __shared__ float al[P_ + 4];
    __shared__ float red[512];
    int lane = tid & 63, wv = tid >> 6;
    // scores: waves split p, lanes split a
    float wf8[8], da8[8];
    {
        const float* wp = Wfa + lane * 8;
        const float* dp = das + b * 512 + lane * 8;
#pragma unroll
        for (int j = 0; j < 8; ++j) { wf8[j] = wp[j]; da8[j] = dp[j]; }
    }
    float b0 = bfa[0];
    for (int p = wv; p < P_; p += 8) {
        uint4 u = *(const uint4*)(ept + ((long)(b * P_ + p)) * 512 + lane * 8);
        float s = 0.f;
        s += wf8[0] * ftanh(b2f_lo(u.x) + da8[0]);
        s += wf8[1] * ftanh(b2f_hi(u.x) + da8[1]);
        s += wf8[2] * ftanh(b2f_lo(u.y) + da8[2]);
        s += wf8[3] * ftanh(b2f_hi(u.y) + da8[3]);
        s += wf8[4] * ftanh(b2f_lo(u.z) + da8[4]);
        s += wf8[5] * ftanh(b2f_hi(u.z) + da8[5]);
        s += wf8[6] * ftanh(b2f_lo(u.w) + da8[6]);
        s += wf8[7] * ftanh(b2f_hi(u.w) + da8[7]);
#pragma unroll
        for (int off = 32; off > 0; off >>= 1) s += __shfl_xor(s, off);
        if (lane == 0) al[p] = s + b0;
    }
    __syncthreads();
    // softmax over 196 (512-thread tree)
    float sc = (tid < P_) ? al[tid] : -1e30f;
    red[tid] = sc;
    __syncthreads();
    for (int s = 256; s > 0; s >>= 1) {
        if (tid < s) red[tid] = fmaxf(red[tid], red[tid + s]);
        __syncthreads();
    }
    float mx = red[0];
    __syncthreads();
    float e = (tid < P_) ? __expf(sc - mx) : 0.f;
    red[tid] = e;
    __syncthreads();
    for (int s = 256; s > 0; s >>= 1) {
        if (tid < s) red[tid] += red[tid + s];
        __syncthreads();
    }
    float inv = 1.f / red[0];
    __syncthreads();
    if (tid < P_) al[tid] = e * inv;
    __syncthreads();
    if (eg == 0 && tid < P_)
        out[OFF_ALPH + ((long)b * T_ + t) * P_ + tid] = al[tid];
    // ctx: 2 bf16 cols per thread from encS, this block's 1024-col slice.
    // unroll 14 (196=14x14): 14 outstanding L3 loads to break the latency chain.
    int e0 = eg * 1024 + tid * 2;
    long base = ((long)b * P_) * ENC_ + e0;
    float a0 = 0.f, a1 = 0.f;
#pragma unroll 14
    for (int p = 0; p < P_; ++p) {
        uint32 v = *(const uint32*)(encS + base + (long)p * ENC_);
        float alp = al[p];
        a0 += alp * b2f_lo(v); a1 += alp * b2f_hi(v);
    }
    float2 g2 = *(const float2*)(gate + b * ENC_ + e0);
    *(uint32*)(ctxg + b * ENC_ + e0) = pack_b2(g2.x * a0, g2.y * a1);
}

// ---------------------------------------------------------------- gates GEMM split-K (256 blocks) — R7 proven
__global__ __launch_bounds__(256) void k_gates(
    const ushort16* __restrict__ embB, const ushort16* __restrict__ ctxg,
    const ushort16* __restrict__ hin,  const ushort16* __restrict__ W2i,
    float* __restrict__ gpart, int t)
{
    __shared__ __align__(16) ushort16 As[64 * 64];
    __shared__ __align__(16) ushort16 Bs[64 * 64];
    const int tid = threadIdx.x;
    const int nt = blockIdx.x >> 3, ks = blockIdx.x & 7;
    const int n0 = nt * 64, kbeg = ks * 384;
    const int lane = tid & 63, wid = tid >> 6;
    const int wr = wid >> 1, wc = wid & 1;
    f32x4 acc[2][2] = {};

    for (int k0 = kbeg; k0 < kbeg + 384; k0 += 64) {
        for (int i = tid; i < 512; i += 256) {
            int r = i >> 3, ck = i & 7;
            int kk = k0 + ck * 8;
            const ushort16* src;
            if (kk < 512)       src = embB + ((long)(t * 64 + r)) * 512 + kk;
            else if (kk < 2560) src = ctxg + (long)r * ENC_ + (kk - 512);
            else                src = hin + (long)r * 512 + (kk - 2560);
            uint4 val = *(const uint4*)src;
            int bo = (r * 128 + ck * 16) ^ ((r & 7) << 4);
            *(uint4*)((char*)As + bo) = val;
        }
        for (int i = tid; i < 512; i += 256) {
            int r = i >> 3, ck = i & 7;
            uint4 val = *(const uint4*)(W2i + (long)(n0 + r) * 3072 + k0 + ck * 8);
            int bo = (r * 128 + ck * 16) ^ ((r & 7) << 4);
            *(uint4*)((char*)Bs + bo) = val;
        }
        __syncthreads();
#pragma unroll
        for (int kk = 0; kk < 64; kk += 32) {
            short8v af[2], bfr[2];
#pragma unroll
            for (int f = 0; f < 2; ++f) {
                int r = wr * 32 + f * 16 + (lane & 15);
                int bo = (r * 128 + (kk + ((lane >> 4) << 3)) * 2) ^ ((r & 7) << 4);
                af[f] = *(const short8v*)((const char*)As + bo);
            }
#pragma unroll
            for (int f = 0; f < 2; ++f) {
                int r = wc * 32 + f * 16 + (lane & 15);
                int bo = (r * 128 + (kk + ((lane >> 4) << 3)) * 2) ^ ((r & 7) << 4);
                bfr[f] = *(const short8v*)((const char*)Bs + bo);
            }
#pragma unroll
            for (int fm = 0; fm < 2; ++fm)
#pragma unroll
                for (int fn = 0; fn < 2; ++fn)
                    acc[fm][fn] = __builtin_amdgcn_mfma_f32_16x16x32_bf16(
                        af[fm], bfr[fn], acc[fm][fn], 0, 0, 0);
        }
        __syncthreads();
    }
    int rr = lane >> 4, cc = lane & 15;
#pragma unroll
    for (int fm = 0; fm < 2; ++fm)
#pragma unroll
        for (int fn = 0; fn < 2; ++fn)
#pragma unroll
            for (int r = 0; r < 4; ++r) {
                int gm = wr * 32 + fm * 16 + rr * 4 + r;
                int gn = n0 + wc * 32 + fn * 16 + cc;
                gpart[((long)(ks * 64 + gm)) * ENC_ + gn] = acc[fm][fn][r];
            }
}

// ---------------------------------------------------------------- LSTM pointwise (reduce 8 partials) — R7 proven
__global__ __launch_bounds__(256) void k_lstm(
    const float* __restrict__ gpart,
    const float* __restrict__ bIH, const float* __restrict__ bHH,
    const int* __restrict__ dlen, float* __restrict__ c,
    const ushort16* __restrict__ hin, ushort16* __restrict__ hout,
    ushort16* __restrict__ histB, int t)
{
    int idx = blockIdx.x * 256 + threadIdx.x;   // 128 blocks -> 64 b x 512 d
    int b = idx >> 9, d = idx & 511;
    long off = (long)b * 512 + d;
    if (t < dlen[b]) {
        float s0 = 0.f, s1 = 0.f, s2 = 0.f, s3 = 0.f;
#pragma unroll
        for (int ks = 0; ks < 8; ++ks) {
            float4 gp = *(const float4*)(gpart + ((long)(ks * 64 + b)) * ENC_ + 4 * d);
            s0 += gp.x; s1 += gp.y; s2 += gp.z; s3 += gp.w;
        }
        float g0 = s0 + bIH[d] + bHH[d];
        float g1 = s1 + bIH[512 + d] + bHH[512 + d];
        float g2v = s2 + bIH[1024 + d] + bHH[1024 + d];
        float g3 = s3 + bIH[1536 + d] + bHH[1536 + d];
        float i_ = fsigm(g0), f_ = fsigm(g1), gg = ftanh(g2v), o_ = fsigm(g3);
        float cn = f_ * c[off] + i_ * gg;
        float hn = o_ * ftanh(cn);
        c[off] = cn;
        ushort16 hv = f2b(hn);
        hout[off] = hv;
        histB[((long)(t * 64 + b)) * 512 + d] = hv;
    } else {
        hout[off] = hin[off];
    }
}

// ---------------------------------------------------------------- launch
extern "C" void kernel_launch(void* const* d_in, const int* in_sizes, int n_in,
                              void* d_out, int out_size, void* d_ws, size_t ws_size,
                              hipStream_t stream)
{
    (void)in_sizes; (void)n_in; (void)out_size; (void)ws_size;
    const float* enc      = (const float*)d_in[0];
    const int*   captions = (const int*)d_in[1];
    const int*   caplen   = (const int*)d_in[2];
    const float* Wemb     = (const float*)d_in[3];
    const float* Wea = (const float*)d_in[4];  const float* bea = (const float*)d_in[5];
    const float* Wda = (const float*)d_in[6];  const float* bda = (const float*)d_in[7];
    const float* Wfa = (const float*)d_in[8];  const float* bfa = (const float*)d_in[9];
    const float* Wih = (const float*)d_in[10]; const float* bih = (const float*)d_in[11];
    const float* Wic = (const float*)d_in[12]; const float* bic = (const float*)d_in[13];
    const float* Wbe = (const float*)d_in[14]; const float* bbe = (const float*)d_in[15];
    const float* WIH = (const float*)d_in[16]; const float* bIH = (const float*)d_in[17];
    const float* WHH = (const float*)d_in[18]; const float* bHH = (const float*)d_in[19];
    const float* Wout = (const float*)d_in[20]; const float* bout = (const float*)d_in[21];

    float* out = (float*)d_out;
    char*  ws  = (char*)d_ws;
    int*   wsi = (int*)ws;
    const int* dlen = wsi + WS_DLEN / 4;
    const int* sortidx = wsi + WS_SORT / 4;
    float* das     = (float*)(ws + WS_DAS);
    float* gate    = (float*)(ws + WS_GATE);
    ushort16* hb0  = (ushort16*)(ws + WS_HB0);
    ushort16* hb1  = (ushort16*)(ws + WS_HB1);
    float* c       = (float*)(ws + WS_C);
    ushort16* ctxg = (ushort16*)(ws + WS_CTXG);
    ushort16* meanB= (ushort16*)(ws + WS_MEANB);
    ushort16* histB= (ushort16*)(ws + WS_HIST);
    ushort16* embB = (ushort16*)(ws + WS_EMB);
    float* gpart   = (float*)(ws + WS_GPART);
    ushort16* ept  = (ushort16*)(ws + WS_EPT);
    ushort16* WeaT = (ushort16*)(ws + WS_WEAT);
    ushort16* Whg  = (ushort16*)(ws + WS_WHG);
    ushort16* W2i  = (ushort16*)(ws + WS_W2I);
    ushort16* WoB  = (ushort16*)(ws + WS_WOB);
    ushort16* WInit= (ushort16*)(ws + WS_WINIT);
    ushort16* encS = (ushort16*)(ws + WS_ENCS);

    k_sort<<<1, 64, 0, stream>>>(caplen, captions, out, wsi);
    k_prep_enc<<<dim3(64, 4), 256, 0, stream>>>(enc, sortidx, encS, meanB);
    k_transpose_all<<<1088, 256, 0, stream>>>(Wea, Wda, Wbe, Wih, Wic, WeaT, Whg, WInit);
    k_prep_small<<<13376, 256, 0, stream>>>(Wout, Wemb, wsi + WS_CAPS / 4, WIH, WHH,
                                            WoB, embB, W2i);

    // h0 | c0 = meanB @ WInit^T
    mgemm<64, 64, 32, 32, 6, 0><<<dim3(16, 1), 256, 0, stream>>>(
        meanB, ENC_, WInit, ENC_, hb0, c, 0, 1024, ENC_, bih, bic, nullptr);
    // enc_proj -> ept bf16 [b*196+p][a]: BM=64 x BN=128, 784 blocks (3/CU), XCD-chunked
    mgemm<64, 128, 32, 64, 1, 1><<<784, 256, 0, stream>>>(
        encS, ENC_, WeaT, ENC_, ept, nullptr, A_, A_, ENC_, bea, nullptr, nullptr);

    for (int t = 0; t < T_; ++t) {
        ushort16* hcur = (t & 1) ? hb1 : hb0;
        ushort16* hnxt = (t & 1) ? hb0 : hb1;
        // das | beta-gate (MFMA, 40 blocks)
        mgemm<64, 64, 32, 32, 2, 0><<<dim3(40, 1), 256, 0, stream>>>(
            hcur, D_, Whg, D_, das, gate, 0, 2560, D_, bda, bbe, nullptr);
        k_att<<<dim3(64, 2), 512, 0, stream>>>(das, gate, Wfa, bfa, ept, encS,
                                               dlen, ctxg, out, t);
        k_gates<<<256, 256, 0, stream>>>(embB, ctxg, hcur, W2i, gpart, t);
        k_lstm<<<128, 256, 0, stream>>>(gpart, bIH, bHH, dlen, c, hcur, hnxt, histB, t);
    }
    // all preds in one GEMM, XCD-swizzled (B-tile shared blocks co-XCD)
    mgemm<128, 128, 64, 64, 7, 2><<<800, 256, 0, stream>>>(
        histB, D_, WoB, D_, out + OFF_PREDS, nullptr, 0, V_, D_, bout, nullptr,
        dlen);
}

// Round 15
// 1428.376 us; speedup vs baseline: 3.0777x; 1.0067x over previous
//
#include <hip/hip_runtime.h>

#define B_ 64
#define P_ 196
#define ENC_ 2048
#define L_ 20
#define T_ 19
#define A_ 512
#define D_ 512
#define E_ 512
#define V_ 10000

// output offsets (float elements)
#define OFF_PREDS 0
#define OFF_CAPS  12160000
#define OFF_DLEN  12161280
#define OFF_ALPH  12161344
#define OFF_SIDX  12399680

// workspace offsets (bytes) — total ~104.5 MB
#define WS_SORT   0          /* 64 int */
#define WS_DLEN   1024
#define WS_CAPS   2048       /* 64*20 int */
#define WS_DAS    114688     /* 64*512 f32 */
#define WS_GATE   245760     /* 64*2048 f32 */
#define WS_HB0    770048     /* 64*512 bf16 */
#define WS_HB1    835584
#define WS_C      901120     /* 64*512 f32 */
#define WS_CTXG   1032192    /* 64*2048 bf16 */
#define WS_MEANB  1294336    /* 64*2048 bf16 */
#define WS_HIST   1556480    /* 1280*512 bf16 */
#define WS_EMB    2867200    /* 1216*512 bf16 */
#define WS_GPART  4194304    /* 8*64*2048 f32 = 4 MB */
#define WS_EPT    8388608    /* 12544*512 bf16 = 12.85 MB */
#define WS_WEAT   21233664   /* 512*2048 bf16 */
#define WS_WHG    23330816   /* 2560*512 bf16 */
#define WS_W2I    25952256   /* 2048*3072 bf16 */
#define WS_WOB    38535168   /* 10112*512 bf16 */
#define WS_WINIT  48889856   /* 1024*2048 bf16 */
#define WS_ENCS   53084160   /* 12544*2048 bf16 = 51.38 MB -> end 104464384 */

typedef __attribute__((ext_vector_type(8))) short short8v;
typedef __attribute__((ext_vector_type(4))) float f32x4;
typedef unsigned int uint32;
typedef unsigned short ushort16;

__device__ __forceinline__ float ftanh(float x){ float e=__expf(2.f*x); return 1.f-2.f/(e+1.f); }
__device__ __forceinline__ float fsigm(float x){ return 1.f/(1.f+__expf(-x)); }
__device__ __forceinline__ ushort16 f2b(float f){
    uint32 u = __float_as_uint(f);
    uint32 r = (u + 0x7FFFu + ((u >> 16) & 1u)) >> 16;
    return (ushort16)r;
}
__device__ __forceinline__ uint32 pack_b2(float a, float b){
    return (uint32)f2b(a) | ((uint32)f2b(b) << 16);
}
__device__ __forceinline__ float b2f_lo(uint32 w){ return __uint_as_float(w << 16); }
__device__ __forceinline__ float b2f_hi(uint32 w){ return __uint_as_float(w & 0xFFFF0000u); }
__device__ __forceinline__ float b1f(ushort16 x){ return __uint_as_float((uint32)x << 16); }

// ---------------------------------------------------------------- parallel rank sort + meta
__global__ void k_sort(const int* __restrict__ cap_len, const int* __restrict__ captions,
                       float* __restrict__ out, int* __restrict__ wsi)
{
    __shared__ int len_s[B_];
    int tid = threadIdx.x;        // 64 threads
    int len = cap_len[tid];
    len_s[tid] = len;
    __syncthreads();
    int rank = 0;
#pragma unroll
    for (int j = 0; j < B_; ++j) {
        int lj = len_s[j];
        rank += (lj > len) || (lj == len && j < tid);
    }
    wsi[WS_SORT / 4 + rank] = tid;
    wsi[WS_DLEN / 4 + rank] = len - 1;
    out[OFF_SIDX + rank] = (float)tid;
    out[OFF_DLEN + rank] = (float)(len - 1);
#pragma unroll
    for (int l = 0; l < L_; ++l) {
        int cv = captions[tid * L_ + l];
        wsi[WS_CAPS / 4 + rank * L_ + l] = cv;
        out[OFF_CAPS + rank * L_ + l] = (float)cv;
    }
}

// ---------------------------------------------------------------- fused: sorted bf16 enc copy + mean
// grid (64, 4): block (b, 512-col slice). float2 loads (8B/lane, G13).
__global__ __launch_bounds__(256) void k_prep_enc(const float* __restrict__ enc,
                                                  const int* __restrict__ sortidx,
                                                  ushort16* __restrict__ encS,
                                                  ushort16* __restrict__ meanB)
{
    int b = blockIdx.x;
    int e = blockIdx.y * 512 + threadIdx.x * 2;
    long sbase = (long)sortidx[b] * P_ * ENC_ + e;
    long dbase = (long)b * P_ * ENC_ + e;
    float s0 = 0.f, s1 = 0.f;
#pragma unroll 4
    for (int p = 0; p < P_; ++p) {
        float2 v = *(const float2*)(enc + sbase + (long)p * ENC_);
        s0 += v.x; s1 += v.y;
        *(uint32*)(encS + dbase + (long)p * ENC_) = pack_b2(v.x, v.y);
    }
    *(uint32*)(meanB + b * ENC_ + e) = pack_b2(s0 * (1.f / (float)P_),
                                               s1 * (1.f / (float)P_));
}

// ---------------------------------------------------------------- merged transpose+cast (5 weights, 1 launch)
// ranges: [0,256) Wea | [256,320) Wda | [320,576) Wbe | [576,832) Wih | [832,1088) Wic
__global__ __launch_bounds__(256) void k_transpose_all(
    const float* __restrict__ Wea, const float* __restrict__ Wda,
    const float* __restrict__ Wbe, const float* __restrict__ Wih,
    const float* __restrict__ Wic,
    ushort16* __restrict__ WeaT, ushort16* __restrict__ Whg,
    ushort16* __restrict__ WInit)
{
    __shared__ float tile[64][65];
    int id = blockIdx.x;
    const float* src; ushort16* dst; int R, C, bx, by;
    if (id < 256)      { src = Wea; dst = WeaT;                R = 2048; C = 512;  int i2 = id;        bx = i2 & 7;  by = i2 >> 3; }
    else if (id < 320) { src = Wda; dst = Whg;                 R = 512;  C = 512;  int i2 = id - 256;  bx = i2 & 7;  by = i2 >> 3; }
    else if (id < 576) { src = Wbe; dst = Whg + 512 * 512;     R = 512;  C = 2048; int i2 = id - 320;  bx = i2 & 31; by = i2 >> 5; }
    else if (id < 832) { src = Wih; dst = WInit;               R = 2048; C = 512;  int i2 = id - 576;  bx = i2 & 7;  by = i2 >> 3; }
    else               { src = Wic; dst = WInit + 512 * 2048;  R = 2048; C = 512;  int i2 = id - 832;  bx = i2 & 7;  by = i2 >> 3; }
    int c0 = bx * 64, r0 = by * 64;
    int lx = threadIdx.x & 63, ly = threadIdx.x >> 6;
#pragma unroll
    for (int i = 0; i < 16; ++i) {
        int r = ly * 16 + i;
        tile[lx][r] = src[(long)(r0 + r) * C + c0 + lx];
    }
    __syncthreads();
#pragma unroll
    for (int i = 0; i < 16; ++i) {
        int cr = ly * 16 + i;
        dst[(long)(c0 + cr) * R + r0 + lx] = f2b(tile[cr][lx]);
    }
}

// ---------------------------------------------------------------- merged small prep: wout | emb | w2i
// ranges: [0,10112) wout rows | [10112,11328) emb rows | [11328,13376) w2i rows
__global__ __launch_bounds__(256) void k_prep_small(
    const float* __restrict__ Wout, const float* __restrict__ embedding,
    const int* __restrict__ caps, const float* __restrict__ WIH,
    const float* __restrict__ WHH,
    ushort16* __restrict__ WoB, ushort16* __restrict__ embB,
    ushort16* __restrict__ W2i)
{
    int id = blockIdx.x;
    if (id < 10112) {
        int r = id, k = threadIdx.x * 2;
        uint32 v = 0;
        if (r < V_) {
            float2 f = *(const float2*)(Wout + (long)r * 512 + k);
            v = pack_b2(f.x, f.y);
        }
        *(uint32*)(WoB + (long)r * 512 + k) = v;
    } else if (id < 11328) {
        int m = id - 10112;                    // m = t*64+b
        int tok = caps[(m & 63) * L_ + (m >> 6)];
        int k = threadIdx.x * 2;
        float2 v = *(const float2*)(embedding + (long)tok * E_ + k);
        *(uint32*)(embB + (long)m * E_ + k) = pack_b2(v.x, v.y);
    } else {
        int r = id - 11328;                    // 0..2047, r = 4d+q
        int d = r >> 2, q = r & 3;
        int n = q * 512 + d;
        for (int cch = threadIdx.x; cch < 384; cch += 256) {
            int kof = cch * 8;
            const float* s = (kof < 2560) ? (WIH + (long)n * 2560 + kof)
                                          : (WHH + (long)n * 512 + (kof - 2560));
            float4 f0 = *(const float4*)s;
            float4 f1 = *(const float4*)(s + 4);
            uint4 v; v.x = pack_b2(f0.x, f0.y); v.y = pack_b2(f0.z, f0.w);
            v.z = pack_b2(f1.x, f1.y); v.w = pack_b2(f1.z, f1.w);
            *(uint4*)(W2i + (long)r * 3072 + kof) = v;
        }
    }
}

// ---------------------------------------------------------------- bf16 MFMA GEMM
// EPI 1: bf16 C = v+bias
// EPI 2: gn<512 -> das=v+bias; else gate=sigmoid(v+bias2)
// EPI 6: gn<512 -> hb=f2b(v+bias); else c=v+bias2
// EPI 7: b=gm&63,tt=gm>>6; tt<T_ guard; preds=(tt<dlen)?v+bias:0
// SWZ 1: enc_proj 1D grid 784=98x8 -> (m<196, n<4), 4 same-A blocks co-XCD
// SWZ 2: pred     1D grid 800 -> (x<79, y<10), same-B blocks co-XCD
template<int BM, int BN, int WM, int WN, int EPI, int SWZ>
__global__ __launch_bounds__(256) void mgemm(
    const ushort16* __restrict__ Amat, int lda1,
    const ushort16* __restrict__ Bmat, int ldb,
    void* __restrict__ Cout, void* __restrict__ Cout2, int ldc, int N, int K,
    const float* __restrict__ bias, const float* __restrict__ bias2,
    const int* __restrict__ dlen)
{
    int bx, by;
    if (SWZ == 1) {
        int id = blockIdx.x;                 // 784 = 98 per XCD x 8 XCDs (exact)
        int xcd = id & 7, idx = id >> 3;     // idx 0..97
        int j = xcd * 98 + idx;              // contiguous j-chunk per XCD
        by = j >> 2;                         // m-tile 0..195 (same-A quad co-XCD)
        bx = j & 3;                          // n-tile 0..3
    } else if (SWZ == 2) {
        int id = blockIdx.x;                 // 800 launched, 790 logical
        bx = (id / 80) * 8 + (id & 7);       // same-bx blocks differ by 8 -> same XCD
        by = (id >> 3) % 10;
        if (bx >= 79) return;
    } else { bx = blockIdx.x; by = blockIdx.y; }

    __shared__ __align__(16) ushort16 As[BM * 64];
    __shared__ __align__(16) ushort16 Bs[BN * 64];
    const int tid = threadIdx.x;
    const int m0 = by * BM, n0 = bx * BN;
    const int lane = tid & 63, wid = tid >> 6;
    constexpr int NWC = BN / WN;
    const int wr = wid / NWC, wc = wid % NWC;
    constexpr int FM = WM / 16, FN = WN / 16;
    f32x4 acc[FM][FN] = {};

    for (int k0 = 0; k0 < K; k0 += 64) {
        for (int i = tid; i < BM * 8; i += 256) {
            int r = i >> 3, ck = i & 7;
            uint4 val = *(const uint4*)(Amat + (long)(m0 + r) * lda1 + k0 + ck * 8);
            int bo = (r * 128 + ck * 16) ^ ((r & 7) << 4);
            *(uint4*)((char*)As + bo) = val;
        }
        for (int i = tid; i < BN * 8; i += 256) {
            int r = i >> 3, ck = i & 7;
            uint4 val = *(const uint4*)(Bmat + (long)(n0 + r) * ldb + k0 + ck * 8);
            int bo = (r * 128 + ck * 16) ^ ((r & 7) << 4);
            *(uint4*)((char*)Bs + bo) = val;
        }
        __syncthreads();
#pragma unroll
        for (int kk = 0; kk < 64; kk += 32) {
            short8v af[FM], bfr[FN];
#pragma unroll
            for (int f = 0; f < FM; ++f) {
                int r = wr * WM + f * 16 + (lane & 15);
                int bo = (r * 128 + (kk + ((lane >> 4) << 3)) * 2) ^ ((r & 7) << 4);
                af[f] = *(const short8v*)((const char*)As + bo);
            }
#pragma unroll
            for (int f = 0; f < FN; ++f) {
                int r = wc * WN + f * 16 + (lane & 15);
                int bo = (r * 128 + (kk + ((lane >> 4) << 3)) * 2) ^ ((r & 7) << 4);
                bfr[f] = *(const short8v*)((const char*)Bs + bo);
            }
#pragma unroll
            for (int fm = 0; fm < FM; ++fm)
#pragma unroll
                for (int fn = 0; fn < FN; ++fn)
                    acc[fm][fn] = __builtin_amdgcn_mfma_f32_16x16x32_bf16(
                        af[fm], bfr[fn], acc[fm][fn], 0, 0, 0);
        }
        __syncthreads();
    }

    int rr = lane >> 4, cc = lane & 15;
#pragma unroll
    for (int fm = 0; fm < FM; ++fm) {
#pragma unroll
        for (int fn = 0; fn < FN; ++fn) {
#pragma unroll
            for (int r = 0; r < 4; ++r) {
                int gm = m0 + wr * WM + fm * 16 + rr * 4 + r;
                int gn = n0 + wc * WN + fn * 16 + cc;
                float v = acc[fm][fn][r];
                if (EPI == 1) {
                    ((ushort16*)Cout)[(long)gm * ldc + gn] = f2b(v + bias[gn]);
                } else if (EPI == 2) {
                    if (gn < 512) ((float*)Cout)[gm * 512 + gn] = v + bias[gn];
                    else ((float*)Cout2)[gm * ENC_ + (gn - 512)] = fsigm(v + bias2[gn - 512]);
                } else if (EPI == 6) {
                    if (gn < 512) ((ushort16*)Cout)[gm * 512 + gn] = f2b(v + bias[gn]);
                    else ((float*)Cout2)[gm * 512 + (gn - 512)] = v + bias2[gn - 512];
                } else if (EPI == 7) {
                    int bq = gm & 63, tt = gm >> 6;
                    if (gn < N && tt < T_)   // tt<T_: rows >=1216 are padding (R8 bug lesson)
                        ((float*)Cout)[((long)bq * T_ + tt) * V_ + gn] =
                            (tt < dlen[bq]) ? v + bias[gn] : 0.f;
                }
            }
        }
    }
}

// ---------------------------------------------------------------- attention: scores+softmax+alpha+ctx
// grid 64 (one block per b), 1024 threads (16 waves): scores once, ctx 2 cols/thread
__global__ __launch_bounds__(1024) void k_att(
    const float* __restrict__ das, const float* __restrict__ gate,
    const float* __restrict__ Wfa, const float* __restrict__ bfa,
    const ushort16* __restrict__ ept, const ushort16* __restrict__ encS,
    const int* __restrict__ dlen,
    ushort16* __restrict__ ctxg, float* __restrict__ out, int t)
{
    int b = blockIdx.x;
    int tid = threadIdx.x;
    if (t >= dlen[b]) {
        if (tid < P_) out[OFF_ALPH + ((long)b * T_ + t) * P_ + tid] = 0.f;
        return;
    }
    __shared__ float al[P_ + 4];
    __shared__ float red[1024];
    int lane = tid & 63, wv = tid >> 6;   // 16 waves
    // scores: waves split p (16-stride), lanes split a
    float wf8[8], da8[8];
    {
        const float* wp = Wfa + lane * 8;
        const float* dp = das + b * 512 + lane * 8;
#pragma unroll
        for (int j = 0; j < 8; ++j) { wf8[j] = wp[j]; da8[j] = dp[j]; }
    }
    float b0 = bfa[0];
    for (int p = wv; p < P_; p += 16) {
        uint4 u = *(const uint4*)(ept + ((long)(b * P_ + p)) * 512 + lane * 8);
        float s = 0.f;
        s += wf8[0] * ftanh(b2f_lo(u.x) + da8[0]);
        s += wf8[1] * ftanh(b2f_hi(u.x) + da8[1]);
        s += wf8[2] * ftanh(b2f_lo(u.y) + da8[2]);
        s += wf8[3] * ftanh(b2f_hi(u.y) + da8[3]);
        s += wf8[4] * ftanh(b2f_lo(u.z) + da8[4]);
        s += wf8[5] * ftanh(b2f_hi(u.z) + da8[5]);
        s += wf8[6] * ftanh(b2f_lo(u.w) + da8[6]);
        s += wf8[7] * ftanh(b2f_hi(u.w) + da8[7]);
#pragma unroll
        for (int off = 32; off > 0; off >>= 1) s += __shfl_xor(s, off);
        if (lane == 0) al[p] = s + b0;
    }
    __syncthreads();
    // softmax over 196 (1024-thread tree)
    float sc = (tid < P_) ? al[tid] : -1e30f;
    red[tid] = sc;
    __syncthreads();
    for (int s = 512; s > 0; s >>= 1) {
        if (tid < s) red[tid] = fmaxf(red[tid], red[tid + s]);
        __syncthreads();
    }
    float mx = red[0];
    __syncthreads();
    float e = (tid < P_) ? __expf(sc - mx) : 0.f;
    red[tid] = e;
    __syncthreads();
    for (int s = 512; s > 0; s >>= 1) {
        if (tid < s) red[tid] += red[tid + s];
        __syncthreads();
    }
    float inv = 1.f / red[0];
    __syncthreads();
    if (tid < P_) al[tid] = e * inv;
    __syncthreads();
    if (tid < P_)
        out[OFF_ALPH + ((long)b * T_ + t) * P_ + tid] = al[tid];
    // ctx: 2 bf16 cols per thread (2048 cols total), unroll 14 for MLP latency
    int e0 = tid * 2;
    long base = ((long)b * P_) * ENC_ + e0;
    float a0 = 0.f, a1 = 0.f;
#pragma unroll 14
    for (int p = 0; p < P_; ++p) {
        uint32 v = *(const uint32*)(encS + base + (long)p * ENC_);
        float alp = al[p];
        a0 += alp * b2f_lo(v); a1 += alp * b2f_hi(v);
    }
    float2 g2 = *(const float2*)(gate + b * ENC_ + e0);
    *(uint32*)(ctxg + b * ENC_ + e0) = pack_b2(g2.x * a0, g2.y * a1);
}

// ---------------------------------------------------------------- gates GEMM split-K (256 blocks) — R7 proven
__global__ __launch_bounds__(256) void k_gates(
    const ushort16* __restrict__ embB, const ushort16* __restrict__ ctxg,
    const ushort16* __restrict__ hin,  const ushort16* __restrict__ W2i,
    float* __restrict__ gpart, int t)
{
    __shared__ __align__(16) ushort16 As[64 * 64];
    __shared__ __align__(16) ushort16 Bs[64 * 64];
    const int tid = threadIdx.x;
    const int nt = blockIdx.x >> 3, ks = blockIdx.x & 7;
    const int n0 = nt * 64, kbeg = ks * 384;
    const int lane = tid & 63, wid = tid >> 6;
    const int wr = wid >> 1, wc = wid & 1;
    f32x4 acc[2][2] = {};

    for (int k0 = kbeg; k0 < kbeg + 384; k0 += 64) {
        for (int i = tid; i < 512; i += 256) {
            int r = i >> 3, ck = i & 7;
            int kk = k0 + ck * 8;
            const ushort16* src;
            if (kk < 512)       src = embB + ((long)(t * 64 + r)) * 512 + kk;
            else if (kk < 2560) src = ctxg + (long)r * ENC_ + (kk - 512);
            else                src = hin + (long)r * 512 + (kk - 2560);
            uint4 val = *(const uint4*)src;
            int bo = (r * 128 + ck * 16) ^ ((r & 7) << 4);
            *(uint4*)((char*)As + bo) = val;
        }
        for (int i = tid; i < 512; i += 256) {
            int r = i >> 3, ck = i & 7;
            uint4 val = *(const uint4*)(W2i + (long)(n0 + r) * 3072 + k0 + ck * 8);
            int bo = (r * 128 + ck * 16) ^ ((r & 7) << 4);
            *(uint4*)((char*)Bs + bo) = val;
        }
        __syncthreads();
#pragma unroll
        for (int kk = 0; kk < 64; kk += 32) {
            short8v af[2], bfr[2];
#pragma unroll
            for (int f = 0; f < 2; ++f) {
                int r = wr * 32 + f * 16 + (lane & 15);
                int bo = (r * 128 + (kk + ((lane >> 4) << 3)) * 2) ^ ((r & 7) << 4);
                af[f] = *(const short8v*)((const char*)As + bo);
            }
#pragma unroll
            for (int f = 0; f < 2; ++f) {
                int r = wc * 32 + f * 16 + (lane & 15);
                int bo = (r * 128 + (kk + ((lane >> 4) << 3)) * 2) ^ ((r & 7) << 4);
                bfr[f] = *(const short8v*)((const char*)Bs + bo);
            }
#pragma unroll
            for (int fm = 0; fm < 2; ++fm)
#pragma unroll
                for (int fn = 0; fn < 2; ++fn)
                    acc[fm][fn] = __builtin_amdgcn_mfma_f32_16x16x32_bf16(
                        af[fm], bfr[fn], acc[fm][fn], 0, 0, 0);
        }
        __syncthreads();
    }
    int rr = lane >> 4, cc = lane & 15;
#pragma unroll
    for (int fm = 0; fm < 2; ++fm)
#pragma unroll
        for (int fn = 0; fn < 2; ++fn)
#pragma unroll
            for (int r = 0; r < 4; ++r) {
                int gm = wr * 32 + fm * 16 + rr * 4 + r;
                int gn = n0 + wc * 32 + fn * 16 + cc;
                gpart[((long)(ks * 64 + gm)) * ENC_ + gn] = acc[fm][fn][r];
            }
}

// ---------------------------------------------------------------- LSTM pointwise (reduce 8 partials) — R7 proven
__global__ __launch_bounds__(256) void k_lstm(
    const float* __restrict__ gpart,
    const float* __restrict__ bIH, const float* __restrict__ bHH,
    const int* __restrict__ dlen, float* __restrict__ c,
    const ushort16* __restrict__ hin, ushort16* __restrict__ hout,
    ushort16* __restrict__ histB, int t)
{
    int idx = blockIdx.x * 256 + threadIdx.x;   // 128 blocks -> 64 b x 512 d
    int b = idx >> 9, d = idx & 511;
    long off = (long)b * 512 + d;
    if (t < dlen[b]) {
        float s0 = 0.f, s1 = 0.f, s2 = 0.f, s3 = 0.f;
#pragma unroll
        for (int ks = 0; ks < 8; ++ks) {
            float4 gp = *(const float4*)(gpart + ((long)(ks * 64 + b)) * ENC_ + 4 * d);
            s0 += gp.x; s1 += gp.y; s2 += gp.z; s3 += gp.w;
        }
        float g0 = s0 + bIH[d] + bHH[d];
        float g1 = s1 + bIH[512 + d] + bHH[512 + d];
        float g2v = s2 + bIH[1024 + d] + bHH[1024 + d];
        float g3 = s3 + bIH[1536 + d] + bHH[1536 + d];
        float i_ = fsigm(g0), f_ = fsigm(g1), gg = ftanh(g2v), o_ = fsigm(g3);
        float cn = f_ * c[off] + i_ * gg;
        float hn = o_ * ftanh(cn);
        c[off] = cn;
        ushort16 hv = f2b(hn);
        hout[off] = hv;
        histB[((long)(t * 64 + b)) * 512 + d] = hv;
    } else {
        hout[off] = hin[off];
    }
}

// ---------------------------------------------------------------- launch
extern "C" void kernel_launch(void* const* d_in, const int* in_sizes, int n_in,
                              void* d_out, int out_size, void* d_ws, size_t ws_size,
                              hipStream_t stream)
{
    (void)in_sizes; (void)n_in; (void)out_size; (void)ws_size;
    const float* enc      = (const float*)d_in[0];
    const int*   captions = (const int*)d_in[1];
    const int*   caplen   = (const int*)d_in[2];
    const float* Wemb     = (const float*)d_in[3];
    const float* Wea = (const float*)d_in[4];  const float* bea = (const float*)d_in[5];
    const float* Wda = (const float*)d_in[6];  const float* bda = (const float*)d_in[7];
    const float* Wfa = (const float*)d_in[8];  const float* bfa = (const float*)d_in[9];
    const float* Wih = (const float*)d_in[10]; const float* bih = (const float*)d_in[11];
    const float* Wic = (const float*)d_in[12]; const float* bic = (const float*)d_in[13];
    const float* Wbe = (const float*)d_in[14]; const float* bbe = (const float*)d_in[15];
    const float* WIH = (const float*)d_in[16]; const float* bIH = (const float*)d_in[17];
    const float* WHH = (const float*)d_in[18]; const float* bHH = (const float*)d_in[19];
    const float* Wout = (const float*)d_in[20]; const float* bout = (const float*)d_in[21];

    float* out = (float*)d_out;
    char*  ws  = (char*)d_ws;
    int*   wsi = (int*)ws;
    const int* dlen = wsi + WS_DLEN / 4;
    const int* sortidx = wsi + WS_SORT / 4;
    float* das     = (float*)(ws + WS_DAS);
    float* gate    = (float*)(ws + WS_GATE);
    ushort16* hb0  = (ushort16*)(ws + WS_HB0);
    ushort16* hb1  = (ushort16*)(ws + WS_HB1);
    float* c       = (float*)(ws + WS_C);
    ushort16* ctxg = (ushort16*)(ws + WS_CTXG);
    ushort16* meanB= (ushort16*)(ws + WS_MEANB);
    ushort16* histB= (ushort16*)(ws + WS_HIST);
    ushort16* embB = (ushort16*)(ws + WS_EMB);
    float* gpart   = (float*)(ws + WS_GPART);
    ushort16* ept  = (ushort16*)(ws + WS_EPT);
    ushort16* WeaT = (ushort16*)(ws + WS_WEAT);
    ushort16* Whg  = (ushort16*)(ws + WS_WHG);
    ushort16* W2i  = (ushort16*)(ws + WS_W2I);
    ushort16* WoB  = (ushort16*)(ws + WS_WOB);
    ushort16* WInit= (ushort16*)(ws + WS_WINIT);
    ushort16* encS = (ushort16*)(ws + WS_ENCS);

    k_sort<<<1, 64, 0, stream>>>(caplen, captions, out, wsi);
    k_prep_enc<<<dim3(64, 4), 256, 0, stream>>>(enc, sortidx, encS, meanB);
    k_transpose_all<<<1088, 256, 0, stream>>>(Wea, Wda, Wbe, Wih, Wic, WeaT, Whg, WInit);
    k_prep_small<<<13376, 256, 0, stream>>>(Wout, Wemb, wsi + WS_CAPS / 4, WIH, WHH,
                                            WoB, embB, W2i);

    // h0 | c0 = meanB @ WInit^T
    mgemm<64, 64, 32, 32, 6, 0><<<dim3(16, 1), 256, 0, stream>>>(
        meanB, ENC_, WInit, ENC_, hb0, c, 0, 1024, ENC_, bih, bic, nullptr);
    // enc_proj -> ept bf16 [b*196+p][a]: BM=64 x BN=128, 784 blocks (3/CU), XCD-chunked
    mgemm<64, 128, 32, 64, 1, 1><<<784, 256, 0, stream>>>(
        encS, ENC_, WeaT, ENC_, ept, nullptr, A_, A_, ENC_, bea, nullptr, nullptr);

    for (int t = 0; t < T_; ++t) {
        ushort16* hcur = (t & 1) ? hb1 : hb0;
        ushort16* hnxt = (t & 1) ? hb0 : hb1;
        // das | beta-gate (MFMA, 40 blocks)
        mgemm<64, 64, 32, 32, 2, 0><<<dim3(40, 1), 256, 0, stream>>>(
            hcur, D_, Whg, D_, das, gate, 0, 2560, D_, bda, bbe, nullptr);
        k_att<<<64, 1024, 0, stream>>>(das, gate, Wfa, bfa, ept, encS,
                                       dlen, ctxg, out, t);
        k_gates<<<256, 256, 0, stream>>>(embB, ctxg, hcur, W2i, gpart, t);
        k_lstm<<<128, 256, 0, stream>>>(gpart, bIH, bHH, dlen, c, hcur, hnxt, histB, t);
    }
    // all preds in one GEMM, XCD-swizzled (B-tile shared blocks co-XCD)
    mgemm<128, 128, 64, 64, 7, 2><<<800, 256, 0, stream>>>(
        histB, D_, WoB, D_, out + OFF_PREDS, nullptr, 0, V_, D_, bout, nullptr,
        dlen);
}

// Round 16
// 1401.692 us; speedup vs baseline: 3.1363x; 1.0190x over previous
//
#include <hip/hip_runtime.h>

#define B_ 64
#define P_ 196
#define ENC_ 2048
#define L_ 20
#define T_ 19
#define A_ 512
#define D_ 512
#define E_ 512
#define V_ 10000

// output offsets (float elements)
#define OFF_PREDS 0
#define OFF_CAPS  12160000
#define OFF_DLEN  12161280
#define OFF_ALPH  12161344
#define OFF_SIDX  12399680

// workspace offsets (bytes) — total ~104.5 MB
#define WS_SORT   0          /* 64 int */
#define WS_DLEN   1024
#define WS_CAPS   2048       /* 64*20 int */
#define WS_DAS    114688     /* 64*512 f32 */
#define WS_GATE   245760     /* 64*2048 f32 */
#define WS_HB0    770048     /* 64*512 bf16 */
#define WS_HB1    835584
#define WS_C      901120     /* 64*512 f32 */
#define WS_CTXG   1032192    /* 64*2048 bf16 */
#define WS_MEANB  1294336    /* 64*2048 bf16 */
#define WS_HIST   1556480    /* 1280*512 bf16 */
#define WS_EMB    2867200    /* 1216*512 bf16 */
#define WS_GPART  4194304    /* 8*64*2048 f32 = 4 MB */
#define WS_EPT    8388608    /* 12544*512 bf16 = 12.85 MB */
#define WS_WEAT   21233664   /* 512*2048 bf16 */
#define WS_WHG    23330816   /* 2560*512 bf16 */
#define WS_W2I    25952256   /* 2048*3072 bf16 */
#define WS_WOB    38535168   /* 10112*512 bf16 */
#define WS_WINIT  48889856   /* 1024*2048 bf16 */
#define WS_ENCS   53084160   /* 12544*2048 bf16 = 51.38 MB -> end 104464384 */

typedef __attribute__((ext_vector_type(8))) short short8v;
typedef __attribute__((ext_vector_type(4))) float f32x4;
typedef unsigned int uint32;
typedef unsigned short ushort16;

__device__ __forceinline__ float ftanh(float x){ float e=__expf(2.f*x); return 1.f-2.f/(e+1.f); }
__device__ __forceinline__ float fsigm(float x){ return 1.f/(1.f+__expf(-x)); }
__device__ __forceinline__ ushort16 f2b(float f){
    uint32 u = __float_as_uint(f);
    uint32 r = (u + 0x7FFFu + ((u >> 16) & 1u)) >> 16;
    return (ushort16)r;
}
__device__ __forceinline__ uint32 pack_b2(float a, float b){
    return (uint32)f2b(a) | ((uint32)f2b(b) << 16);
}
__device__ __forceinline__ float b2f_lo(uint32 w){ return __uint_as_float(w << 16); }
__device__ __forceinline__ float b2f_hi(uint32 w){ return __uint_as_float(w & 0xFFFF0000u); }
__device__ __forceinline__ float b1f(ushort16 x){ return __uint_as_float((uint32)x << 16); }

// ---------------------------------------------------------------- parallel rank sort + meta
__global__ void k_sort(const int* __restrict__ cap_len, const int* __restrict__ captions,
                       float* __restrict__ out, int* __restrict__ wsi)
{
    __shared__ int len_s[B_];
    int tid = threadIdx.x;        // 64 threads
    int len = cap_len[tid];
    len_s[tid] = len;
    __syncthreads();
    int rank = 0;
#pragma unroll
    for (int j = 0; j < B_; ++j) {
        int lj = len_s[j];
        rank += (lj > len) || (lj == len && j < tid);
    }
    wsi[WS_SORT / 4 + rank] = tid;
    wsi[WS_DLEN / 4 + rank] = len - 1;
    out[OFF_SIDX + rank] = (float)tid;
    out[OFF_DLEN + rank] = (float)(len - 1);
#pragma unroll
    for (int l = 0; l < L_; ++l) {
        int cv = captions[tid * L_ + l];
        wsi[WS_CAPS / 4 + rank * L_ + l] = cv;
        out[OFF_CAPS + rank * L_ + l] = (float)cv;
    }
}

// ---------------------------------------------------------------- fused: sorted bf16 enc copy + mean
// grid (64, 2): block (b, 1024-col slice). float4 loads (16B/lane, G13).
__global__ __launch_bounds__(256) void k_prep_enc(const float* __restrict__ enc,
                                                  const int* __restrict__ sortidx,
                                                  ushort16* __restrict__ encS,
                                                  ushort16* __restrict__ meanB)
{
    int b = blockIdx.x;
    int e = blockIdx.y * 1024 + threadIdx.x * 4;
    long sbase = (long)sortidx[b] * P_ * ENC_ + e;
    long dbase = (long)b * P_ * ENC_ + e;
    float s0 = 0.f, s1 = 0.f, s2 = 0.f, s3 = 0.f;
#pragma unroll 4
    for (int p = 0; p < P_; ++p) {
        float4 v = *(const float4*)(enc + sbase + (long)p * ENC_);
        s0 += v.x; s1 += v.y; s2 += v.z; s3 += v.w;
        uint2 o; o.x = pack_b2(v.x, v.y); o.y = pack_b2(v.z, v.w);
        *(uint2*)(encS + dbase + (long)p * ENC_) = o;
    }
    const float inv = 1.f / (float)P_;
    uint2 m; m.x = pack_b2(s0 * inv, s1 * inv); m.y = pack_b2(s2 * inv, s3 * inv);
    *(uint2*)(meanB + b * ENC_ + e) = m;
}

// ---------------------------------------------------------------- merged transpose+cast (5 weights, 1 launch)
// ranges: [0,256) Wea | [256,320) Wda | [320,576) Wbe | [576,832) Wih | [832,1088) Wic
__global__ __launch_bounds__(256) void k_transpose_all(
    const float* __restrict__ Wea, const float* __restrict__ Wda,
    const float* __restrict__ Wbe, const float* __restrict__ Wih,
    const float* __restrict__ Wic,
    ushort16* __restrict__ WeaT, ushort16* __restrict__ Whg,
    ushort16* __restrict__ WInit)
{
    __shared__ float tile[64][65];
    int id = blockIdx.x;
    const float* src; ushort16* dst; int R, C, bx, by;
    if (id < 256)      { src = Wea; dst = WeaT;                R = 2048; C = 512;  int i2 = id;        bx = i2 & 7;  by = i2 >> 3; }
    else if (id < 320) { src = Wda; dst = Whg;                 R = 512;  C = 512;  int i2 = id - 256;  bx = i2 & 7;  by = i2 >> 3; }
    else if (id < 576) { src = Wbe; dst = Whg + 512 * 512;     R = 512;  C = 2048; int i2 = id - 320;  bx = i2 & 31; by = i2 >> 5; }
    else if (id < 832) { src = Wih; dst = WInit;               R = 2048; C = 512;  int i2 = id - 576;  bx = i2 & 7;  by = i2 >> 3; }
    else               { src = Wic; dst = WInit + 512 * 2048;  R = 2048; C = 512;  int i2 = id - 832;  bx = i2 & 7;  by = i2 >> 3; }
    int c0 = bx * 64, r0 = by * 64;
    int lx = threadIdx.x & 63, ly = threadIdx.x >> 6;
#pragma unroll
    for (int i = 0; i < 16; ++i) {
        int r = ly * 16 + i;
        tile[lx][r] = src[(long)(r0 + r) * C + c0 + lx];
    }
    __syncthreads();
#pragma unroll
    for (int i = 0; i < 16; ++i) {
        int cr = ly * 16 + i;
        dst[(long)(c0 + cr) * R + r0 + lx] = f2b(tile[cr][lx]);
    }
}

// ---------------------------------------------------------------- merged small prep: wout | emb | w2i
// ranges: [0,10112) wout rows | [10112,11328) emb rows | [11328,13376) w2i rows
__global__ __launch_bounds__(256) void k_prep_small(
    const float* __restrict__ Wout, const float* __restrict__ embedding,
    const int* __restrict__ caps, const float* __restrict__ WIH,
    const float* __restrict__ WHH,
    ushort16* __restrict__ WoB, ushort16* __restrict__ embB,
    ushort16* __restrict__ W2i)
{
    int id = blockIdx.x;
    if (id < 10112) {
        int r = id, k = threadIdx.x * 2;
        uint32 v = 0;
        if (r < V_) {
            float2 f = *(const float2*)(Wout + (long)r * 512 + k);
            v = pack_b2(f.x, f.y);
        }
        *(uint32*)(WoB + (long)r * 512 + k) = v;
    } else if (id < 11328) {
        int m = id - 10112;                    // m = t*64+b
        int tok = caps[(m & 63) * L_ + (m >> 6)];
        int k = threadIdx.x * 2;
        float2 v = *(const float2*)(embedding + (long)tok * E_ + k);
        *(uint32*)(embB + (long)m * E_ + k) = pack_b2(v.x, v.y);
    } else {
        int r = id - 11328;                    // 0..2047, r = 4d+q
        int d = r >> 2, q = r & 3;
        int n = q * 512 + d;
        for (int cch = threadIdx.x; cch < 384; cch += 256) {
            int kof = cch * 8;
            const float* s = (kof < 2560) ? (WIH + (long)n * 2560 + kof)
                                          : (WHH + (long)n * 512 + (kof - 2560));
            float4 f0 = *(const float4*)s;
            float4 f1 = *(const float4*)(s + 4);
            uint4 v; v.x = pack_b2(f0.x, f0.y); v.y = pack_b2(f0.z, f0.w);
            v.z = pack_b2(f1.x, f1.y); v.w = pack_b2(f1.z, f1.w);
            *(uint4*)(W2i + (long)r * 3072 + kof) = v;
        }
    }
}

// ---------------------------------------------------------------- bf16 MFMA GEMM
// EPI 1: bf16 C = v+bias
// EPI 2: gn<512 -> das=v+bias; else gate=sigmoid(v+bias2)
// EPI 6: gn<512 -> hb=f2b(v+bias); else c=v+bias2
// EPI 7: b=gm&63,tt=gm>>6; tt<T_ guard; preds=(tt<dlen)?v+bias:0
// SWZ 1: enc_proj 1D grid 784=98x8 -> (m<196, n<4), 4 same-A blocks co-XCD
// SWZ 2: pred     1D grid 800 -> (x<79, y<10), same-B blocks co-XCD
// KS: K-step per LDS stage (64 default; 128 for enc_proj halves barrier count)
template<int BM, int BN, int WM, int WN, int EPI, int SWZ, int KS = 64>
__global__ __launch_bounds__(256) void mgemm(
    const ushort16* __restrict__ Amat, int lda1,
    const ushort16* __restrict__ Bmat, int ldb,
    void* __restrict__ Cout, void* __restrict__ Cout2, int ldc, int N, int K,
    const float* __restrict__ bias, const float* __restrict__ bias2,
    const int* __restrict__ dlen)
{
    int bx, by;
    if (SWZ == 1) {
        int id = blockIdx.x;                 // 784 = 98 per XCD x 8 XCDs (exact)
        int xcd = id & 7, idx = id >> 3;     // idx 0..97
        int j = xcd * 98 + idx;              // contiguous j-chunk per XCD
        by = j >> 2;                         // m-tile 0..195 (same-A quad co-XCD)
        bx = j & 3;                          // n-tile 0..3
    } else if (SWZ == 2) {
        int id = blockIdx.x;                 // 800 launched, 790 logical
        bx = (id / 80) * 8 + (id & 7);       // same-bx blocks differ by 8 -> same XCD
        by = (id >> 3) % 10;
        if (bx >= 79) return;
    } else { bx = blockIdx.x; by = blockIdx.y; }

    constexpr int KS8 = KS / 8;              // 8-elt chunks per row
    __shared__ __align__(16) ushort16 As[BM * KS];
    __shared__ __align__(16) ushort16 Bs[BN * KS];
    const int tid = threadIdx.x;
    const int m0 = by * BM, n0 = bx * BN;
    const int lane = tid & 63, wid = tid >> 6;
    constexpr int NWC = BN / WN;
    const int wr = wid / NWC, wc = wid % NWC;
    constexpr int FM = WM / 16, FN = WN / 16;
    f32x4 acc[FM][FN] = {};

    for (int k0 = 0; k0 < K; k0 += KS) {
        for (int i = tid; i < BM * KS8; i += 256) {
            int r = i / KS8, ck = i % KS8;
            uint4 val = *(const uint4*)(Amat + (long)(m0 + r) * lda1 + k0 + ck * 8);
            int bo = (r * (KS * 2) + ck * 16) ^ ((r & 7) << 4);
            *(uint4*)((char*)As + bo) = val;
        }
        for (int i = tid; i < BN * KS8; i += 256) {
            int r = i / KS8, ck = i % KS8;
            uint4 val = *(const uint4*)(Bmat + (long)(n0 + r) * ldb + k0 + ck * 8);
            int bo = (r * (KS * 2) + ck * 16) ^ ((r & 7) << 4);
            *(uint4*)((char*)Bs + bo) = val;
        }
        __syncthreads();
#pragma unroll
        for (int kk = 0; kk < KS; kk += 32) {
            short8v af[FM], bfr[FN];
#pragma unroll
            for (int f = 0; f < FM; ++f) {
                int r = wr * WM + f * 16 + (lane & 15);
                int bo = (r * (KS * 2) + (kk + ((lane >> 4) << 3)) * 2) ^ ((r & 7) << 4);
                af[f] = *(const short8v*)((const char*)As + bo);
            }
#pragma unroll
            for (int f = 0; f < FN; ++f) {
                int r = wc * WN + f * 16 + (lane & 15);
                int bo = (r * (KS * 2) + (kk + ((lane >> 4) << 3)) * 2) ^ ((r & 7) << 4);
                bfr[f] = *(const short8v*)((const char*)Bs + bo);
            }
#pragma unroll
            for (int fm = 0; fm < FM; ++fm)
#pragma unroll
                for (int fn = 0; fn < FN; ++fn)
                    acc[fm][fn] = __builtin_amdgcn_mfma_f32_16x16x32_bf16(
                        af[fm], bfr[fn], acc[fm][fn], 0, 0, 0);
        }
        __syncthreads();
    }

    int rr = lane >> 4, cc = lane & 15;
#pragma unroll
    for (int fm = 0; fm < FM; ++fm) {
#pragma unroll
        for (int fn = 0; fn < FN; ++fn) {
#pragma unroll
            for (int r = 0; r < 4; ++r) {
                int gm = m0 + wr * WM + fm * 16 + rr * 4 + r;
                int gn = n0 + wc * WN + fn * 16 + cc;
                float v = acc[fm][fn][r];
                if (EPI == 1) {
                    ((ushort16*)Cout)[(long)gm * ldc + gn] = f2b(v + bias[gn]);
                } else if (EPI == 2) {
                    if (gn < 512) ((float*)Cout)[gm * 512 + gn] = v + bias[gn];
                    else ((float*)Cout2)[gm * ENC_ + (gn - 512)] = fsigm(v + bias2[gn - 512]);
                } else if (EPI == 6) {
                    if (gn < 512) ((ushort16*)Cout)[gm * 512 + gn] = f2b(v + bias[gn]);
                    else ((float*)Cout2)[gm * 512 + (gn - 512)] = v + bias2[gn - 512];
                } else if (EPI == 7) {
                    int bq = gm & 63, tt = gm >> 6;
                    if (gn < N && tt < T_)   // tt<T_: rows >=1216 are padding (R8 bug lesson)
                        ((float*)Cout)[((long)bq * T_ + tt) * V_ + gn] =
                            (tt < dlen[bq]) ? v + bias[gn] : 0.f;
                }
            }
        }
    }
}

// ---------------------------------------------------------------- attention: scores+softmax+alpha+ctx
// grid 64 (one block per b), 1024 threads (16 waves): scores once, ctx 2 cols/thread
__global__ __launch_bounds__(1024) void k_att(
    const float* __restrict__ das, const float* __restrict__ gate,
    const float* __restrict__ Wfa, const float* __restrict__ bfa,
    const ushort16* __restrict__ ept, const ushort16* __restrict__ encS,
    const int* __restrict__ dlen,
    ushort16* __restrict__ ctxg, float* __restrict__ out, int t)
{
    int b = blockIdx.x;
    int tid = threadIdx.x;
    if (t >= dlen[b]) {
        if (tid < P_) out[OFF_ALPH + ((long)b * T_ + t) * P_ + tid] = 0.f;
        return;
    }
    __shared__ float al[P_ + 4];
    __shared__ float red[1024];
    int lane = tid & 63, wv = tid >> 6;   // 16 waves
    // scores: waves split p (16-stride), lanes split a
    float wf8[8], da8[8];
    {
        const float* wp = Wfa + lane * 8;
        const float* dp = das + b * 512 + lane * 8;
#pragma unroll
        for (int j = 0; j < 8; ++j) { wf8[j] = wp[j]; da8[j] = dp[j]; }
    }
    float b0 = bfa[0];
    for (int p = wv; p < P_; p += 16) {
        uint4 u = *(const uint4*)(ept + ((long)(b * P_ + p)) * 512 + lane * 8);
        float s = 0.f;
        s += wf8[0] * ftanh(b2f_lo(u.x) + da8[0]);
        s += wf8[1] * ftanh(b2f_hi(u.x) + da8[1]);
        s += wf8[2] * ftanh(b2f_lo(u.y) + da8[2]);
        s += wf8[3] * ftanh(b2f_hi(u.y) + da8[3]);
        s += wf8[4] * ftanh(b2f_lo(u.z) + da8[4]);
        s += wf8[5] * ftanh(b2f_hi(u.z) + da8[5]);
        s += wf8[6] * ftanh(b2f_lo(u.w) + da8[6]);
        s += wf8[7] * ftanh(b2f_hi(u.w) + da8[7]);
#pragma unroll
        for (int off = 32; off > 0; off >>= 1) s += __shfl_xor(s, off);
        if (lane == 0) al[p] = s + b0;
    }
    __syncthreads();
    // softmax over 196 (1024-thread tree)
    float sc = (tid < P_) ? al[tid] : -1e30f;
    red[tid] = sc;
    __syncthreads();
    for (int s = 512; s > 0; s >>= 1) {
        if (tid < s) red[tid] = fmaxf(red[tid], red[tid + s]);
        __syncthreads();
    }
    float mx = red[0];
    __syncthreads();
    float e = (tid < P_) ? __expf(sc - mx) : 0.f;
    red[tid] = e;
    __syncthreads();
    for (int s = 512; s > 0; s >>= 1) {
        if (tid < s) red[tid] += red[tid + s];
        __syncthreads();
    }
    float inv = 1.f / red[0];
    __syncthreads();
    if (tid < P_) al[tid] = e * inv;
    __syncthreads();
    if (tid < P_)
        out[OFF_ALPH + ((long)b * T_ + t) * P_ + tid] = al[tid];
    // ctx: 2 bf16 cols per thread (2048 cols total), unroll 14 for MLP latency
    int e0 = tid * 2;
    long base = ((long)b * P_) * ENC_ + e0;
    float a0 = 0.f, a1 = 0.f;
#pragma unroll 14
    for (int p = 0; p < P_; ++p) {
        uint32 v = *(const uint32*)(encS + base + (long)p * ENC_);
        float alp = al[p];
        a0 += alp * b2f_lo(v); a1 += alp * b2f_hi(v);
    }
    float2 g2 = *(const float2*)(gate + b * ENC_ + e0);
    *(uint32*)(ctxg + b * ENC_ + e0) = pack_b2(g2.x * a0, g2.y * a1);
}

// ---------------------------------------------------------------- gates GEMM split-K (256 blocks) — R7 proven
__global__ __launch_bounds__(256) void k_gates(
    const ushort16* __restrict__ embB, const ushort16* __restrict__ ctxg,
    const ushort16* __restrict__ hin,  const ushort16* __restrict__ W2i,
    float* __restrict__ gpart, int t)
{
    __shared__ __align__(16) ushort16 As[64 * 64];
    __shared__ __align__(16) ushort16 Bs[64 * 64];
    const int tid = threadIdx.x;
    const int nt = blockIdx.x >> 3, ks = blockIdx.x & 7;
    const int n0 = nt * 64, kbeg = ks * 384;
    const int lane = tid & 63, wid = tid >> 6;
    const int wr = wid >> 1, wc = wid & 1;
    f32x4 acc[2][2] = {};

    for (int k0 = kbeg; k0 < kbeg + 384; k0 += 64) {
        for (int i = tid; i < 512; i += 256) {
            int r = i >> 3, ck = i & 7;
            int kk = k0 + ck * 8;
            const ushort16* src;
            if (kk < 512)       src = embB + ((long)(t * 64 + r)) * 512 + kk;
            else if (kk < 2560) src = ctxg + (long)r * ENC_ + (kk - 512);
            else                src = hin + (long)r * 512 + (kk - 2560);
            uint4 val = *(const uint4*)src;
            int bo = (r * 128 + ck * 16) ^ ((r & 7) << 4);
            *(uint4*)((char*)As + bo) = val;
        }
        for (int i = tid; i < 512; i += 256) {
            int r = i >> 3, ck = i & 7;
            uint4 val = *(const uint4*)(W2i + (long)(n0 + r) * 3072 + k0 + ck * 8);
            int bo = (r * 128 + ck * 16) ^ ((r & 7) << 4);
            *(uint4*)((char*)Bs + bo) = val;
        }
        __syncthreads();
#pragma unroll
        for (int kk = 0; kk < 64; kk += 32) {
            short8v af[2], bfr[2];
#pragma unroll
            for (int f = 0; f < 2; ++f) {
                int r = wr * 32 + f * 16 + (lane & 15);
                int bo = (r * 128 + (kk + ((lane >> 4) << 3)) * 2) ^ ((r & 7) << 4);
                af[f] = *(const short8v*)((const char*)As + bo);
            }
#pragma unroll
            for (int f = 0; f < 2; ++f) {
                int r = wc * 32 + f * 16 + (lane & 15);
                int bo = (r * 128 + (kk + ((lane >> 4) << 3)) * 2) ^ ((r & 7) << 4);
                bfr[f] = *(const short8v*)((const char*)Bs + bo);
            }
#pragma unroll
            for (int fm = 0; fm < 2; ++fm)
#pragma unroll
                for (int fn = 0; fn < 2; ++fn)
                    acc[fm][fn] = __builtin_amdgcn_mfma_f32_16x16x32_bf16(
                        af[fm], bfr[fn], acc[fm][fn], 0, 0, 0);
        }
        __syncthreads();
    }
    int rr = lane >> 4, cc = lane & 15;
#pragma unroll
    for (int fm = 0; fm < 2; ++fm)
#pragma unroll
        for (int fn = 0; fn < 2; ++fn)
#pragma unroll
            for (int r = 0; r < 4; ++r) {
                int gm = wr * 32 + fm * 16 + rr * 4 + r;
                int gn = n0 + wc * 32 + fn * 16 + cc;
                gpart[((long)(ks * 64 + gm)) * ENC_ + gn] = acc[fm][fn][r];
            }
}

// ---------------------------------------------------------------- LSTM pointwise (reduce 8 partials) — R7 proven
__global__ __launch_bounds__(256) void k_lstm(
    const float* __restrict__ gpart,
    const float* __restrict__ bIH, const float* __restrict__ bHH,
    const int* __restrict__ dlen, float* __restrict__ c,
    const ushort16* __restrict__ hin, ushort16* __restrict__ hout,
    ushort16* __restrict__ histB, int t)
{
    int idx = blockIdx.x * 256 + threadIdx.x;   // 128 blocks -> 64 b x 512 d
    int b = idx >> 9, d = idx & 511;
    long off = (long)b * 512 + d;
    if (t < dlen[b]) {
        float s0 = 0.f, s1 = 0.f, s2 = 0.f, s3 = 0.f;
#pragma unroll
        for (int ks = 0; ks < 8; ++ks) {
            float4 gp = *(const float4*)(gpart + ((long)(ks * 64 + b)) * ENC_ + 4 * d);
            s0 += gp.x; s1 += gp.y; s2 += gp.z; s3 += gp.w;
        }
        float g0 = s0 + bIH[d] + bHH[d];
        float g1 = s1 + bIH[512 + d] + bHH[512 + d];
        float g2v = s2 + bIH[1024 + d] + bHH[1024 + d];
        float g3 = s3 + bIH[1536 + d] + bHH[1536 + d];
        float i_ = fsigm(g0), f_ = fsigm(g1), gg = ftanh(g2v), o_ = fsigm(g3);
        float cn = f_ * c[off] + i_ * gg;
        float hn = o_ * ftanh(cn);
        c[off] = cn;
        ushort16 hv = f2b(hn);
        hout[off] = hv;
        histB[((long)(t * 64 + b)) * 512 + d] = hv;
    } else {
        hout[off] = hin[off];
    }
}

// ---------------------------------------------------------------- launch
extern "C" void kernel_launch(void* const* d_in, const int* in_sizes, int n_in,
                              void* d_out, int out_size, void* d_ws, size_t ws_size,
                              hipStream_t stream)
{
    (void)in_sizes; (void)n_in; (void)out_size; (void)ws_size;
    const float* enc      = (const float*)d_in[0];
    const int*   captions = (const int*)d_in[1];
    const int*   caplen   = (const int*)d_in[2];
    const float* Wemb     = (const float*)d_in[3];
    const float* Wea = (const float*)d_in[4];  const float* bea = (const float*)d_in[5];
    const float* Wda = (const float*)d_in[6];  const float* bda = (const float*)d_in[7];
    const float* Wfa = (const float*)d_in[8];  const float* bfa = (const float*)d_in[9];
    const float* Wih = (const float*)d_in[10]; const float* bih = (const float*)d_in[11];
    const float* Wic = (const float*)d_in[12]; const float* bic = (const float*)d_in[13];
    const float* Wbe = (const float*)d_in[14]; const float* bbe = (const float*)d_in[15];
    const float* WIH = (const float*)d_in[16]; const float* bIH = (const float*)d_in[17];
    const float* WHH = (const float*)d_in[18]; const float* bHH = (const float*)d_in[19];
    const float* Wout = (const float*)d_in[20]; const float* bout = (const float*)d_in[21];

    float* out = (float*)d_out;
    char*  ws  = (char*)d_ws;
    int*   wsi = (int*)ws;
    const int* dlen = wsi + WS_DLEN / 4;
    const int* sortidx = wsi + WS_SORT / 4;
    float* das     = (float*)(ws + WS_DAS);
    float* gate    = (float*)(ws + WS_GATE);
    ushort16* hb0  = (ushort16*)(ws + WS_HB0);
    ushort16* hb1  = (ushort16*)(ws + WS_HB1);
    float* c       = (float*)(ws + WS_C);
    ushort16* ctxg = (ushort16*)(ws + WS_CTXG);
    ushort16* meanB= (ushort16*)(ws + WS_MEANB);
    ushort16* histB= (ushort16*)(ws + WS_HIST);
    ushort16* embB = (ushort16*)(ws + WS_EMB);
    float* gpart   = (float*)(ws + WS_GPART);
    ushort16* ept  = (ushort16*)(ws + WS_EPT);
    ushort16* WeaT = (ushort16*)(ws + WS_WEAT);
    ushort16* Whg  = (ushort16*)(ws + WS_WHG);
    ushort16* W2i  = (ushort16*)(ws + WS_W2I);
    ushort16* WoB  = (ushort16*)(ws + WS_WOB);
    ushort16* WInit= (ushort16*)(ws + WS_WINIT);
    ushort16* encS = (ushort16*)(ws + WS_ENCS);

    k_sort<<<1, 64, 0, stream>>>(caplen, captions, out, wsi);
    k_prep_enc<<<dim3(64, 2), 256, 0, stream>>>(enc, sortidx, encS, meanB);
    k_transpose_all<<<1088, 256, 0, stream>>>(Wea, Wda, Wbe, Wih, Wic, WeaT, Whg, WInit);
    k_prep_small<<<13376, 256, 0, stream>>>(Wout, Wemb, wsi + WS_CAPS / 4, WIH, WHH,
                                            WoB, embB, W2i);

    // h0 | c0 = meanB @ WInit^T
    mgemm<64, 64, 32, 32, 6, 0><<<dim3(16, 1), 256, 0, stream>>>(
        meanB, ENC_, WInit, ENC_, hb0, c, 0, 1024, ENC_, bih, bic, nullptr);
    // enc_proj -> ept bf16: BM=64 x BN=128, KS=128 (half the barriers), XCD-chunked
    mgemm<64, 128, 32, 64, 1, 1, 128><<<784, 256, 0, stream>>>(
        encS, ENC_, WeaT, ENC_, ept, nullptr, A_, A_, ENC_, bea, nullptr, nullptr);

    for (int t = 0; t < T_; ++t) {
        ushort16* hcur = (t & 1) ? hb1 : hb0;
        ushort16* hnxt = (t & 1) ? hb0 : hb1;
        // das | beta-gate (MFMA, 80 blocks of BN=32 for 2x CU coverage)
        mgemm<64, 32, 16, 32, 2, 0><<<dim3(80, 1), 256, 0, stream>>>(
            hcur, D_, Whg, D_, das, gate, 0, 2560, D_, bda, bbe, nullptr);
        k_att<<<64, 1024, 0, stream>>>(das, gate, Wfa, bfa, ept, encS,
                                       dlen, ctxg, out, t);
        k_gates<<<256, 256, 0, stream>>>(embB, ctxg, hcur, W2i, gpart, t);
        k_lstm<<<128, 256, 0, stream>>>(gpart, bIH, bHH, dlen, c, hcur, hnxt, histB, t);
    }
    // all preds in one GEMM, XCD-swizzled (B-tile shared blocks co-XCD)
    mgemm<128, 128, 64, 64, 7, 2><<<800, 256, 0, stream>>>(
        histB, D_, WoB, D_, out + OFF_PREDS, nullptr, 0, V_, D_, bout, nullptr,
        dlen);
}

// Round 17
// 1336.835 us; speedup vs baseline: 3.2885x; 1.0485x over previous
//
#include <hip/hip_runtime.h>

#define B_ 64
#define P_ 196
#define ENC_ 2048
#define L_ 20
#define T_ 19
#define A_ 512
#define D_ 512
#define E_ 512
#define V_ 10000

// output offsets (float elements)
#define OFF_PREDS 0
#define OFF_CAPS  12160000
#define OFF_DLEN  12161280
#define OFF_ALPH  12161344
#define OFF_SIDX  12399680

// workspace offsets (bytes) — total ~104.5 MB
#define WS_SORT   0          /* 64 int */
#define WS_DLEN   1024
#define WS_CAPS   2048       /* 64*20 int */
#define WS_DAS    114688     /* 64*512 f32 */
#define WS_GATE   245760     /* 64*2048 f32 */
#define WS_HB0    770048     /* 64*512 bf16 */
#define WS_HB1    835584
#define WS_C      901120     /* 64*512 f32 */
#define WS_CTXG   1032192    /* 64*2048 bf16 */
#define WS_MEANB  1294336    /* 64*2048 bf16 */
#define WS_HIST   1556480    /* 1280*512 bf16 */
#define WS_EMB    2867200    /* 1216*512 bf16 */
#define WS_GPART  4194304    /* 8*64*2048 f32 = 4 MB */
#define WS_EPT    8388608    /* 12544*512 bf16 = 12.85 MB */
#define WS_WEAT   21233664   /* 512*2048 bf16 */
#define WS_WHG    23330816   /* 2560*512 bf16 */
#define WS_W2I    25952256   /* 2048*3072 bf16 */
#define WS_WOB    38535168   /* 10112*512 bf16 */
#define WS_WINIT  48889856   /* 1024*2048 bf16 */
#define WS_ENCS   53084160   /* 12544*2048 bf16 = 51.38 MB -> end 104464384 */

typedef __attribute__((ext_vector_type(8))) short short8v;
typedef __attribute__((ext_vector_type(4))) float f32x4;
typedef unsigned int uint32;
typedef unsigned short ushort16;

__device__ __forceinline__ float ftanh(float x){ float e=__expf(2.f*x); return 1.f-2.f/(e+1.f); }
__device__ __forceinline__ float fsigm(float x){ return 1.f/(1.f+__expf(-x)); }
__device__ __forceinline__ ushort16 f2b(float f){
    uint32 u = __float_as_uint(f);
    uint32 r = (u + 0x7FFFu + ((u >> 16) & 1u)) >> 16;
    return (ushort16)r;
}
__device__ __forceinline__ uint32 pack_b2(float a, float b){
    return (uint32)f2b(a) | ((uint32)f2b(b) << 16);
}
__device__ __forceinline__ float b2f_lo(uint32 w){ return __uint_as_float(w << 16); }
__device__ __forceinline__ float b2f_hi(uint32 w){ return __uint_as_float(w & 0xFFFF0000u); }
__device__ __forceinline__ float b1f(ushort16 x){ return __uint_as_float((uint32)x << 16); }

// ---------------------------------------------------------------- parallel rank sort + meta
__global__ void k_sort(const int* __restrict__ cap_len, const int* __restrict__ captions,
                       float* __restrict__ out, int* __restrict__ wsi)
{
    __shared__ int len_s[B_];
    int tid = threadIdx.x;        // 64 threads
    int len = cap_len[tid];
    len_s[tid] = len;
    __syncthreads();
    int rank = 0;
#pragma unroll
    for (int j = 0; j < B_; ++j) {
        int lj = len_s[j];
        rank += (lj > len) || (lj == len && j < tid);
    }
    wsi[WS_SORT / 4 + rank] = tid;
    wsi[WS_DLEN / 4 + rank] = len - 1;
    out[OFF_SIDX + rank] = (float)tid;
    out[OFF_DLEN + rank] = (float)(len - 1);
#pragma unroll
    for (int l = 0; l < L_; ++l) {
        int cv = captions[tid * L_ + l];
        wsi[WS_CAPS / 4 + rank * L_ + l] = cv;
        out[OFF_CAPS + rank * L_ + l] = (float)cv;
    }
}

// ---------------------------------------------------------------- fused: sorted bf16 enc copy + mean
// grid (64, 2): block (b, 1024-col slice). float4 loads (16B/lane, G13).
__global__ __launch_bounds__(256) void k_prep_enc(const float* __restrict__ enc,
                                                  const int* __restrict__ sortidx,
                                                  ushort16* __restrict__ encS,
                                                  ushort16* __restrict__ meanB)
{
    int b = blockIdx.x;
    int e = blockIdx.y * 1024 + threadIdx.x * 4;
    long sbase = (long)sortidx[b] * P_ * ENC_ + e;
    long dbase = (long)b * P_ * ENC_ + e;
    float s0 = 0.f, s1 = 0.f, s2 = 0.f, s3 = 0.f;
#pragma unroll 4
    for (int p = 0; p < P_; ++p) {
        float4 v = *(const float4*)(enc + sbase + (long)p * ENC_);
        s0 += v.x; s1 += v.y; s2 += v.z; s3 += v.w;
        uint2 o; o.x = pack_b2(v.x, v.y); o.y = pack_b2(v.z, v.w);
        *(uint2*)(encS + dbase + (long)p * ENC_) = o;
    }
    const float inv = 1.f / (float)P_;
    uint2 m; m.x = pack_b2(s0 * inv, s1 * inv); m.y = pack_b2(s2 * inv, s3 * inv);
    *(uint2*)(meanB + b * ENC_ + e) = m;
}

// ---------------------------------------------------------------- merged transpose+cast (5 weights, 1 launch)
// ranges: [0,256) Wea | [256,320) Wda | [320,576) Wbe | [576,832) Wih | [832,1088) Wic
__global__ __launch_bounds__(256) void k_transpose_all(
    const float* __restrict__ Wea, const float* __restrict__ Wda,
    const float* __restrict__ Wbe, const float* __restrict__ Wih,
    const float* __restrict__ Wic,
    ushort16* __restrict__ WeaT, ushort16* __restrict__ Whg,
    ushort16* __restrict__ WInit)
{
    __shared__ float tile[64][65];
    int id = blockIdx.x;
    const float* src; ushort16* dst; int R, C, bx, by;
    if (id < 256)      { src = Wea; dst = WeaT;                R = 2048; C = 512;  int i2 = id;        bx = i2 & 7;  by = i2 >> 3; }
    else if (id < 320) { src = Wda; dst = Whg;                 R = 512;  C = 512;  int i2 = id - 256;  bx = i2 & 7;  by = i2 >> 3; }
    else if (id < 576) { src = Wbe; dst = Whg + 512 * 512;     R = 512;  C = 2048; int i2 = id - 320;  bx = i2 & 31; by = i2 >> 5; }
    else if (id < 832) { src = Wih; dst = WInit;               R = 2048; C = 512;  int i2 = id - 576;  bx = i2 & 7;  by = i2 >> 3; }
    else               { src = Wic; dst = WInit + 512 * 2048;  R = 2048; C = 512;  int i2 = id - 832;  bx = i2 & 7;  by = i2 >> 3; }
    int c0 = bx * 64, r0 = by * 64;
    int lx = threadIdx.x & 63, ly = threadIdx.x >> 6;
#pragma unroll
    for (int i = 0; i < 16; ++i) {
        int r = ly * 16 + i;
        tile[lx][r] = src[(long)(r0 + r) * C + c0 + lx];
    }
    __syncthreads();
#pragma unroll
    for (int i = 0; i < 16; ++i) {
        int cr = ly * 16 + i;
        dst[(long)(c0 + cr) * R + r0 + lx] = f2b(tile[cr][lx]);
    }
}

// ---------------------------------------------------------------- merged small prep: wout | emb | w2i
// ranges: [0,10112) wout rows | [10112,11328) emb rows | [11328,13376) w2i rows
__global__ __launch_bounds__(256) void k_prep_small(
    const float* __restrict__ Wout, const float* __restrict__ embedding,
    const int* __restrict__ caps, const float* __restrict__ WIH,
    const float* __restrict__ WHH,
    ushort16* __restrict__ WoB, ushort16* __restrict__ embB,
    ushort16* __restrict__ W2i)
{
    int id = blockIdx.x;
    if (id < 10112) {
        int r = id, k = threadIdx.x * 2;
        uint32 v = 0;
        if (r < V_) {
            float2 f = *(const float2*)(Wout + (long)r * 512 + k);
            v = pack_b2(f.x, f.y);
        }
        *(uint32*)(WoB + (long)r * 512 + k) = v;
    } else if (id < 11328) {
        int m = id - 10112;                    // m = t*64+b
        int tok = caps[(m & 63) * L_ + (m >> 6)];
        int k = threadIdx.x * 2;
        float2 v = *(const float2*)(embedding + (long)tok * E_ + k);
        *(uint32*)(embB + (long)m * E_ + k) = pack_b2(v.x, v.y);
    } else {
        int r = id - 11328;                    // 0..2047, r = 4d+q
        int d = r >> 2, q = r & 3;
        int n = q * 512 + d;
        for (int cch = threadIdx.x; cch < 384; cch += 256) {
            int kof = cch * 8;
            const float* s = (kof < 2560) ? (WIH + (long)n * 2560 + kof)
                                          : (WHH + (long)n * 512 + (kof - 2560));
            float4 f0 = *(const float4*)s;
            float4 f1 = *(const float4*)(s + 4);
            uint4 v; v.x = pack_b2(f0.x, f0.y); v.y = pack_b2(f0.z, f0.w);
            v.z = pack_b2(f1.x, f1.y); v.w = pack_b2(f1.z, f1.w);
            *(uint4*)(W2i + (long)r * 3072 + kof) = v;
        }
    }
}

// ---------------------------------------------------------------- bf16 MFMA GEMM
// EPI 1: bf16 C = v+bias
// EPI 2: gn<512 -> das=v+bias; else gate=sigmoid(v+bias2)
// EPI 6: gn<512 -> hb=f2b(v+bias); else c=v+bias2
// EPI 7: b=gm&63,tt=gm>>6; tt<T_ guard; preds=(tt<dlen)?v+bias:0
// SWZ 1: enc_proj 1D grid 784=98x8 -> (m<196, n<4), 4 same-A blocks co-XCD
// SWZ 2: pred     1D grid 800 -> (x<79, y<10), same-B blocks co-XCD
// KS fixed at 64: KS=128 broke the XOR swizzle (R16: 4.8M bank conflicts, +59us)
template<int BM, int BN, int WM, int WN, int EPI, int SWZ>
__global__ __launch_bounds__(256) void mgemm(
    const ushort16* __restrict__ Amat, int lda1,
    const ushort16* __restrict__ Bmat, int ldb,
    void* __restrict__ Cout, void* __restrict__ Cout2, int ldc, int N, int K,
    const float* __restrict__ bias, const float* __restrict__ bias2,
    const int* __restrict__ dlen)
{
    int bx, by;
    if (SWZ == 1) {
        int id = blockIdx.x;                 // 784 = 98 per XCD x 8 XCDs (exact)
        int xcd = id & 7, idx = id >> 3;     // idx 0..97
        int j = xcd * 98 + idx;              // contiguous j-chunk per XCD
        by = j >> 2;                         // m-tile 0..195 (same-A quad co-XCD)
        bx = j & 3;                          // n-tile 0..3
    } else if (SWZ == 2) {
        int id = blockIdx.x;                 // 800 launched, 790 logical
        bx = (id / 80) * 8 + (id & 7);       // same-bx blocks differ by 8 -> same XCD
        by = (id >> 3) % 10;
        if (bx >= 79) return;
    } else { bx = blockIdx.x; by = blockIdx.y; }

    __shared__ __align__(16) ushort16 As[BM * 64];
    __shared__ __align__(16) ushort16 Bs[BN * 64];
    const int tid = threadIdx.x;
    const int m0 = by * BM, n0 = bx * BN;
    const int lane = tid & 63, wid = tid >> 6;
    constexpr int NWC = BN / WN;
    const int wr = wid / NWC, wc = wid % NWC;
    constexpr int FM = WM / 16, FN = WN / 16;
    f32x4 acc[FM][FN] = {};

    for (int k0 = 0; k0 < K; k0 += 64) {
        for (int i = tid; i < BM * 8; i += 256) {
            int r = i >> 3, ck = i & 7;
            uint4 val = *(const uint4*)(Amat + (long)(m0 + r) * lda1 + k0 + ck * 8);
            int bo = (r * 128 + ck * 16) ^ ((r & 7) << 4);
            *(uint4*)((char*)As + bo) = val;
        }
        for (int i = tid; i < BN * 8; i += 256) {
            int r = i >> 3, ck = i & 7;
            uint4 val = *(const uint4*)(Bmat + (long)(n0 + r) * ldb + k0 + ck * 8);
            int bo = (r * 128 + ck * 16) ^ ((r & 7) << 4);
            *(uint4*)((char*)Bs + bo) = val;
        }
        __syncthreads();
#pragma unroll
        for (int kk = 0; kk < 64; kk += 32) {
            short8v af[FM], bfr[FN];
#pragma unroll
            for (int f = 0; f < FM; ++f) {
                int r = wr * WM + f * 16 + (lane & 15);
                int bo = (r * 128 + (kk + ((lane >> 4) << 3)) * 2) ^ ((r & 7) << 4);
                af[f] = *(const short8v*)((const char*)As + bo);
            }
#pragma unroll
            for (int f = 0; f < FN; ++f) {
                int r = wc * WN + f * 16 + (lane & 15);
                int bo = (r * 128 + (kk + ((lane >> 4) << 3)) * 2) ^ ((r & 7) << 4);
                bfr[f] = *(const short8v*)((const char*)Bs + bo);
            }
#pragma unroll
            for (int fm = 0; fm < FM; ++fm)
#pragma unroll
                for (int fn = 0; fn < FN; ++fn)
                    acc[fm][fn] = __builtin_amdgcn_mfma_f32_16x16x32_bf16(
                        af[fm], bfr[fn], acc[fm][fn], 0, 0, 0);
        }
        __syncthreads();
    }

    int rr = lane >> 4, cc = lane & 15;
#pragma unroll
    for (int fm = 0; fm < FM; ++fm) {
#pragma unroll
        for (int fn = 0; fn < FN; ++fn) {
#pragma unroll
            for (int r = 0; r < 4; ++r) {
                int gm = m0 + wr * WM + fm * 16 + rr * 4 + r;
                int gn = n0 + wc * WN + fn * 16 + cc;
                float v = acc[fm][fn][r];
                if (EPI == 1) {
                    ((ushort16*)Cout)[(long)gm * ldc + gn] = f2b(v + bias[gn]);
                } else if (EPI == 2) {
                    if (gn < 512) ((float*)Cout)[gm * 512 + gn] = v + bias[gn];
                    else ((float*)Cout2)[gm * ENC_ + (gn - 512)] = fsigm(v + bias2[gn - 512]);
                } else if (EPI == 6) {
                    if (gn < 512) ((ushort16*)Cout)[gm * 512 + gn] = f2b(v + bias[gn]);
                    else ((float*)Cout2)[gm * 512 + (gn - 512)] = v + bias2[gn - 512];
                } else if (EPI == 7) {
                    int bq = gm & 63, tt = gm >> 6;
                    if (gn < N && tt < T_)   // tt<T_: rows >=1216 are padding (R8 bug lesson)
                        ((float*)Cout)[((long)bq * T_ + tt) * V_ + gn] =
                            (tt < dlen[bq]) ? v + bias[gn] : 0.f;
                }
            }
        }
    }
}

// ---------------------------------------------------------------- attention: scores+softmax+alpha+ctx
// grid 64 (one block per b), 1024 threads (16 waves): scores once, ctx 2 cols/thread
__global__ __launch_bounds__(1024) void k_att(
    const float* __restrict__ das, const float* __restrict__ gate,
    const float* __restrict__ Wfa, const float* __restrict__ bfa,
    const ushort16* __restrict__ ept, const ushort16* __restrict__ encS,
    const int* __restrict__ dlen,
    ushort16* __restrict__ ctxg, float* __restrict__ out, int t)
{
    int b = blockIdx.x;
    int tid = threadIdx.x;
    if (t >= dlen[b]) {
        if (tid < P_) out[OFF_ALPH + ((long)b * T_ + t) * P_ + tid] = 0.f;
        return;
    }
    __shared__ float al[P_ + 4];
    __shared__ float red[1024];
    int lane = tid & 63, wv = tid >> 6;   // 16 waves
    // scores: waves split p (16-stride), lanes split a
    float wf8[8], da8[8];
    {
        const float* wp = Wfa + lane * 8;
        const float* dp = das + b * 512 + lane * 8;
#pragma unroll
        for (int j = 0; j < 8; ++j) { wf8[j] = wp[j]; da8[j] = dp[j]; }
    }
    float b0 = bfa[0];
    for (int p = wv; p < P_; p += 16) {
        uint4 u = *(const uint4*)(ept + ((long)(b * P_ + p)) * 512 + lane * 8);
        float s = 0.f;
        s += wf8[0] * ftanh(b2f_lo(u.x) + da8[0]);
        s += wf8[1] * ftanh(b2f_hi(u.x) + da8[1]);
        s += wf8[2] * ftanh(b2f_lo(u.y) + da8[2]);
        s += wf8[3] * ftanh(b2f_hi(u.y) + da8[3]);
        s += wf8[4] * ftanh(b2f_lo(u.z) + da8[4]);
        s += wf8[5] * ftanh(b2f_hi(u.z) + da8[5]);
        s += wf8[6] * ftanh(b2f_lo(u.w) + da8[6]);
        s += wf8[7] * ftanh(b2f_hi(u.w) + da8[7]);
#pragma unroll
        for (int off = 32; off > 0; off >>= 1) s += __shfl_xor(s, off);
        if (lane == 0) al[p] = s + b0;
    }
    __syncthreads();
    // softmax over 196 (1024-thread tree)
    float sc = (tid < P_) ? al[tid] : -1e30f;
    red[tid] = sc;
    __syncthreads();
    for (int s = 512; s > 0; s >>= 1) {
        if (tid < s) red[tid] = fmaxf(red[tid], red[tid + s]);
        __syncthreads();
    }
    float mx = red[0];
    __syncthreads();
    float e = (tid < P_) ? __expf(sc - mx) : 0.f;
    red[tid] = e;
    __syncthreads();
    for (int s = 512; s > 0; s >>= 1) {
        if (tid < s) red[tid] += red[tid + s];
        __syncthreads();
    }
    float inv = 1.f / red[0];
    __syncthreads();
    if (tid < P_) al[tid] = e * inv;
    __syncthreads();
    if (tid < P_)
        out[OFF_ALPH + ((long)b * T_ + t) * P_ + tid] = al[tid];
    // ctx: 2 bf16 cols per thread (2048 cols total), unroll 14 for MLP latency
    int e0 = tid * 2;
    long base = ((long)b * P_) * ENC_ + e0;
    float a0 = 0.f, a1 = 0.f;
#pragma unroll 14
    for (int p = 0; p < P_; ++p) {
        uint32 v = *(const uint32*)(encS + base + (long)p * ENC_);
        float alp = al[p];
        a0 += alp * b2f_lo(v); a1 += alp * b2f_hi(v);
    }
    float2 g2 = *(const float2*)(gate + b * ENC_ + e0);
    *(uint32*)(ctxg + b * ENC_ + e0) = pack_b2(g2.x * a0, g2.y * a1);
}

// ---------------------------------------------------------------- gates GEMM split-K (256 blocks) — R7 proven
__global__ __launch_bounds__(256) void k_gates(
    const ushort16* __restrict__ embB, const ushort16* __restrict__ ctxg,
    const ushort16* __restrict__ hin,  const ushort16* __restrict__ W2i,
    float* __restrict__ gpart, int t)
{
    __shared__ __align__(16) ushort16 As[64 * 64];
    __shared__ __align__(16) ushort16 Bs[64 * 64];
    const int tid = threadIdx.x;
    const int nt = blockIdx.x >> 3, ks = blockIdx.x & 7;
    const int n0 = nt * 64, kbeg = ks * 384;
    const int lane = tid & 63, wid = tid >> 6;
    const int wr = wid >> 1, wc = wid & 1;
    f32x4 acc[2][2] = {};

    for (int k0 = kbeg; k0 < kbeg + 384; k0 += 64) {
        for (int i = tid; i < 512; i += 256) {
            int r = i >> 3, ck = i & 7;
            int kk = k0 + ck * 8;
            const ushort16* src;
            if (kk < 512)       src = embB + ((long)(t * 64 + r)) * 512 + kk;
            else if (kk < 2560) src = ctxg + (long)r * ENC_ + (kk - 512);
            else                src = hin + (long)r * 512 + (kk - 2560);
            uint4 val = *(const uint4*)src;
            int bo = (r * 128 + ck * 16) ^ ((r & 7) << 4);
            *(uint4*)((char*)As + bo) = val;
        }
        for (int i = tid; i < 512; i += 256) {
            int r = i >> 3, ck = i & 7;
            uint4 val = *(const uint4*)(W2i + (long)(n0 + r) * 3072 + k0 + ck * 8);
            int bo = (r * 128 + ck * 16) ^ ((r & 7) << 4);
            *(uint4*)((char*)Bs + bo) = val;
        }
        __syncthreads();
#pragma unroll
        for (int kk = 0; kk < 64; kk += 32) {
            short8v af[2], bfr[2];
#pragma unroll
            for (int f = 0; f < 2; ++f) {
                int r = wr * 32 + f * 16 + (lane & 15);
                int bo = (r * 128 + (kk + ((lane >> 4) << 3)) * 2) ^ ((r & 7) << 4);
                af[f] = *(const short8v*)((const char*)As + bo);
            }
#pragma unroll
            for (int f = 0; f < 2; ++f) {
                int r = wc * 32 + f * 16 + (lane & 15);
                int bo = (r * 128 + (kk + ((lane >> 4) << 3)) * 2) ^ ((r & 7) << 4);
                bfr[f] = *(const short8v*)((const char*)Bs + bo);
            }
#pragma unroll
            for (int fm = 0; fm < 2; ++fm)
#pragma unroll
                for (int fn = 0; fn < 2; ++fn)
                    acc[fm][fn] = __builtin_amdgcn_mfma_f32_16x16x32_bf16(
                        af[fm], bfr[fn], acc[fm][fn], 0, 0, 0);
        }
        __syncthreads();
    }
    int rr = lane >> 4, cc = lane & 15;
#pragma unroll
    for (int fm = 0; fm < 2; ++fm)
#pragma unroll
        for (int fn = 0; fn < 2; ++fn)
#pragma unroll
            for (int r = 0; r < 4; ++r) {
                int gm = wr * 32 + fm * 16 + rr * 4 + r;
                int gn = n0 + wc * 32 + fn * 16 + cc;
                gpart[((long)(ks * 64 + gm)) * ENC_ + gn] = acc[fm][fn][r];
            }
}

// ---------------------------------------------------------------- LSTM pointwise (reduce 8 partials) — R7 proven
__global__ __launch_bounds__(256) void k_lstm(
    const float* __restrict__ gpart,
    const float* __restrict__ bIH, const float* __restrict__ bHH,
    const int* __restrict__ dlen, float* __restrict__ c,
    const ushort16* __restrict__ hin, ushort16* __restrict__ hout,
    ushort16* __restrict__ histB, int t)
{
    int idx = blockIdx.x * 256 + threadIdx.x;   // 128 blocks -> 64 b x 512 d
    int b = idx >> 9, d = idx & 511;
    long off = (long)b * 512 + d;
    if (t < dlen[b]) {
        float s0 = 0.f, s1 = 0.f, s2 = 0.f, s3 = 0.f;
#pragma unroll
        for (int ks = 0; ks < 8; ++ks) {
            float4 gp = *(const float4*)(gpart + ((long)(ks * 64 + b)) * ENC_ + 4 * d);
            s0 += gp.x; s1 += gp.y; s2 += gp.z; s3 += gp.w;
        }
        float g0 = s0 + bIH[d] + bHH[d];
        float g1 = s1 + bIH[512 + d] + bHH[512 + d];
        float g2v = s2 + bIH[1024 + d] + bHH[1024 + d];
        float g3 = s3 + bIH[1536 + d] + bHH[1536 + d];
        float i_ = fsigm(g0), f_ = fsigm(g1), gg = ftanh(g2v), o_ = fsigm(g3);
        float cn = f_ * c[off] + i_ * gg;
        float hn = o_ * ftanh(cn);
        c[off] = cn;
        ushort16 hv = f2b(hn);
        hout[off] = hv;
        histB[((long)(t * 64 + b)) * 512 + d] = hv;
    } else {
        hout[off] = hin[off];
    }
}

// ---------------------------------------------------------------- launch
extern "C" void kernel_launch(void* const* d_in, const int* in_sizes, int n_in,
                              void* d_out, int out_size, void* d_ws, size_t ws_size,
                              hipStream_t stream)
{
    (void)in_sizes; (void)n_in; (void)out_size; (void)ws_size;
    const float* enc      = (const float*)d_in[0];
    const int*   captions = (const int*)d_in[1];
    const int*   caplen   = (const int*)d_in[2];
    const float* Wemb     = (const float*)d_in[3];
    const float* Wea = (const float*)d_in[4];  const float* bea = (const float*)d_in[5];
    const float* Wda = (const float*)d_in[6];  const float* bda = (const float*)d_in[7];
    const float* Wfa = (const float*)d_in[8];  const float* bfa = (const float*)d_in[9];
    const float* Wih = (const float*)d_in[10]; const float* bih = (const float*)d_in[11];
    const float* Wic = (const float*)d_in[12]; const float* bic = (const float*)d_in[13];
    const float* Wbe = (const float*)d_in[14]; const float* bbe = (const float*)d_in[15];
    const float* WIH = (const float*)d_in[16]; const float* bIH = (const float*)d_in[17];
    const float* WHH = (const float*)d_in[18]; const float* bHH = (const float*)d_in[19];
    const float* Wout = (const float*)d_in[20]; const float* bout = (const float*)d_in[21];

    float* out = (float*)d_out;
    char*  ws  = (char*)d_ws;
    int*   wsi = (int*)ws;
    const int* dlen = wsi + WS_DLEN / 4;
    const int* sortidx = wsi + WS_SORT / 4;
    float* das     = (float*)(ws + WS_DAS);
    float* gate    = (float*)(ws + WS_GATE);
    ushort16* hb0  = (ushort16*)(ws + WS_HB0);
    ushort16* hb1  = (ushort16*)(ws + WS_HB1);
    float* c       = (float*)(ws + WS_C);
    ushort16* ctxg = (ushort16*)(ws + WS_CTXG);
    ushort16* meanB= (ushort16*)(ws + WS_MEANB);
    ushort16* histB= (ushort16*)(ws + WS_HIST);
    ushort16* embB = (ushort16*)(ws + WS_EMB);
    float* gpart   = (float*)(ws + WS_GPART);
    ushort16* ept  = (ushort16*)(ws + WS_EPT);
    ushort16* WeaT = (ushort16*)(ws + WS_WEAT);
    ushort16* Whg  = (ushort16*)(ws + WS_WHG);
    ushort16* W2i  = (ushort16*)(ws + WS_W2I);
    ushort16* WoB  = (ushort16*)(ws + WS_WOB);
    ushort16* WInit= (ushort16*)(ws + WS_WINIT);
    ushort16* encS = (ushort16*)(ws + WS_ENCS);

    k_sort<<<1, 64, 0, stream>>>(caplen, captions, out, wsi);
    k_prep_enc<<<dim3(64, 2), 256, 0, stream>>>(enc, sortidx, encS, meanB);
    k_transpose_all<<<1088, 256, 0, stream>>>(Wea, Wda, Wbe, Wih, Wic, WeaT, Whg, WInit);
    k_prep_small<<<13376, 256, 0, stream>>>(Wout, Wemb, wsi + WS_CAPS / 4, WIH, WHH,
                                            WoB, embB, W2i);

    // h0 | c0 = meanB @ WInit^T
    mgemm<64, 64, 32, 32, 6, 0><<<dim3(16, 1), 256, 0, stream>>>(
        meanB, ENC_, WInit, ENC_, hb0, c, 0, 1024, ENC_, bih, bic, nullptr);
    // enc_proj -> ept bf16: BM=64 x BN=128, KS=64 (R13-proven, 0 bank conflicts)
    mgemm<64, 128, 32, 64, 1, 1><<<784, 256, 0, stream>>>(
        encS, ENC_, WeaT, ENC_, ept, nullptr, A_, A_, ENC_, bea, nullptr, nullptr);

    for (int t = 0; t < T_; ++t) {
        ushort16* hcur = (t & 1) ? hb1 : hb0;
        ushort16* hnxt = (t & 1) ? hb0 : hb1;
        // das | beta-gate (MFMA, 80 blocks of BN=32 for 2x CU coverage)
        mgemm<64, 32, 16, 32, 2, 0><<<dim3(80, 1), 256, 0, stream>>>(
            hcur, D_, Whg, D_, das, gate, 0, 2560, D_, bda, bbe, nullptr);
        k_att<<<64, 1024, 0, stream>>>(das, gate, Wfa, bfa, ept, encS,
                                       dlen, ctxg, out, t);
        k_gates<<<256, 256, 0, stream>>>(embB, ctxg, hcur, W2i, gpart, t);
        k_lstm<<<128, 256, 0, stream>>>(gpart, bIH, bHH, dlen, c, hcur, hnxt, histB, t);
    }
    // all preds in one GEMM, XCD-swizzled (B-tile shared blocks co-XCD)
    mgemm<128, 128, 64, 64, 7, 2><<<800, 256, 0, stream>>>(
        histB, D_, WoB, D_, out + OFF_PREDS, nullptr, 0, V_, D_, bout, nullptr,
        dlen);
}

// Round 18
// 1295.934 us; speedup vs baseline: 3.3923x; 1.0316x over previous
//
#include <hip/hip_runtime.h>

#define B_ 64
#define P_ 196
#define ENC_ 2048
#define L_ 20
#define T_ 19
#define A_ 512
#define D_ 512
#define E_ 512
#define V_ 10000

// output offsets (float elements)
#define OFF_PREDS 0
#define OFF_CAPS  12160000
#define OFF_DLEN  12161280
#define OFF_ALPH  12161344
#define OFF_SIDX  12399680

// workspace offsets (bytes) — total ~104.5 MB
#define WS_SORT   0          /* 64 int */
#define WS_DLEN   1024
#define WS_CAPS   2048       /* 64*20 int */
#define WS_DAS    114688     /* 64*512 f32 */
#define WS_GATE   245760     /* 64*2048 f32 */
#define WS_HB0    770048     /* 64*512 bf16 */
#define WS_HB1    835584
#define WS_C      901120     /* 64*512 f32 */
#define WS_CTXG   1032192    /* 64*2048 bf16 */
#define WS_MEANB  1294336    /* 64*2048 bf16 */
#define WS_HIST   1556480    /* 1280*512 bf16 */
#define WS_EMB    2867200    /* 1216*512 bf16 */
#define WS_GPART  4194304    /* 8*64*2048 f32 = 4 MB */
#define WS_EPT    8388608    /* 12544*512 bf16 = 12.85 MB */
#define WS_WEAT   21233664   /* 512*2048 bf16 */
#define WS_WHG    23330816   /* 2560*512 bf16 */
#define WS_W2I    25952256   /* 2048*3072 bf16 */
#define WS_WOB    38535168   /* 10112*512 bf16 */
#define WS_WINIT  48889856   /* 1024*2048 bf16 */
#define WS_ENCS   53084160   /* 12544*2048 bf16 = 51.38 MB -> end 104464384 */

typedef __attribute__((ext_vector_type(8))) short short8v;
typedef __attribute__((ext_vector_type(4))) float f32x4;
typedef unsigned int uint32;
typedef unsigned short ushort16;

__device__ __forceinline__ float ftanh(float x){ float e=__expf(2.f*x); return 1.f-2.f/(e+1.f); }
__device__ __forceinline__ float fsigm(float x){ return 1.f/(1.f+__expf(-x)); }
__device__ __forceinline__ ushort16 f2b(float f){
    uint32 u = __float_as_uint(f);
    uint32 r = (u + 0x7FFFu + ((u >> 16) & 1u)) >> 16;
    return (ushort16)r;
}
__device__ __forceinline__ uint32 pack_b2(float a, float b){
    return (uint32)f2b(a) | ((uint32)f2b(b) << 16);
}
__device__ __forceinline__ float b2f_lo(uint32 w){ return __uint_as_float(w << 16); }
__device__ __forceinline__ float b2f_hi(uint32 w){ return __uint_as_float(w & 0xFFFF0000u); }
__device__ __forceinline__ float b1f(ushort16 x){ return __uint_as_float((uint32)x << 16); }

// ---------------------------------------------------------------- parallel rank sort + meta
__global__ void k_sort(const int* __restrict__ cap_len, const int* __restrict__ captions,
                       float* __restrict__ out, int* __restrict__ wsi)
{
    __shared__ int len_s[B_];
    int tid = threadIdx.x;        // 64 threads
    int len = cap_len[tid];
    len_s[tid] = len;
    __syncthreads();
    int rank = 0;
#pragma unroll
    for (int j = 0; j < B_; ++j) {
        int lj = len_s[j];
        rank += (lj > len) || (lj == len && j < tid);
    }
    wsi[WS_SORT / 4 + rank] = tid;
    wsi[WS_DLEN / 4 + rank] = len - 1;
    out[OFF_SIDX + rank] = (float)tid;
    out[OFF_DLEN + rank] = (float)(len - 1);
#pragma unroll
    for (int l = 0; l < L_; ++l) {
        int cv = captions[tid * L_ + l];
        wsi[WS_CAPS / 4 + rank * L_ + l] = cv;
        out[OFF_CAPS + rank * L_ + l] = (float)cv;
    }
}

// ---------------------------------------------------------------- merged one-time prep (1 launch)
// [0,128): prep_enc (b = id>>1, 1024-col slice id&1)     — enc->encS bf16 + mean
// [128,1216): transpose+cast 5 weights (1088 tiles)
// [1216,14592): wout cast | emb gather | w2i pack (13376)
__global__ __launch_bounds__(256) void k_prep_all(
    const float* __restrict__ enc, const int* __restrict__ sortidx,
    ushort16* __restrict__ encS, ushort16* __restrict__ meanB,
    const float* __restrict__ Wea, const float* __restrict__ Wda,
    const float* __restrict__ Wbe, const float* __restrict__ Wih,
    const float* __restrict__ Wic,
    ushort16* __restrict__ WeaT, ushort16* __restrict__ Whg,
    ushort16* __restrict__ WInit,
    const float* __restrict__ Wout, const float* __restrict__ embedding,
    const int* __restrict__ caps, const float* __restrict__ WIH,
    const float* __restrict__ WHH,
    ushort16* __restrict__ WoB, ushort16* __restrict__ embB,
    ushort16* __restrict__ W2i)
{
    int bid = blockIdx.x;
    if (bid < 128) {
        int b = bid >> 1;
        int e = (bid & 1) * 1024 + threadIdx.x * 4;
        long sbase = (long)sortidx[b] * P_ * ENC_ + e;
        long dbase = (long)b * P_ * ENC_ + e;
        float s0 = 0.f, s1 = 0.f, s2 = 0.f, s3 = 0.f;
#pragma unroll 4
        for (int p = 0; p < P_; ++p) {
            float4 v = *(const float4*)(enc + sbase + (long)p * ENC_);
            s0 += v.x; s1 += v.y; s2 += v.z; s3 += v.w;
            uint2 o; o.x = pack_b2(v.x, v.y); o.y = pack_b2(v.z, v.w);
            *(uint2*)(encS + dbase + (long)p * ENC_) = o;
        }
        const float inv = 1.f / (float)P_;
        uint2 m; m.x = pack_b2(s0 * inv, s1 * inv); m.y = pack_b2(s2 * inv, s3 * inv);
        *(uint2*)(meanB + b * ENC_ + e) = m;
        return;
    }
    if (bid < 1216) {
        __shared__ float tile[64][65];
        int id = bid - 128;
        const float* src; ushort16* dst; int R, C, bx, by;
        if (id < 256)      { src = Wea; dst = WeaT;                R = 2048; C = 512;  int i2 = id;        bx = i2 & 7;  by = i2 >> 3; }
        else if (id < 320) { src = Wda; dst = Whg;                 R = 512;  C = 512;  int i2 = id - 256;  bx = i2 & 7;  by = i2 >> 3; }
        else if (id < 576) { src = Wbe; dst = Whg + 512 * 512;     R = 512;  C = 2048; int i2 = id - 320;  bx = i2 & 31; by = i2 >> 5; }
        else if (id < 832) { src = Wih; dst = WInit;               R = 2048; C = 512;  int i2 = id - 576;  bx = i2 & 7;  by = i2 >> 3; }
        else               { src = Wic; dst = WInit + 512 * 2048;  R = 2048; C = 512;  int i2 = id - 832;  bx = i2 & 7;  by = i2 >> 3; }
        int c0 = bx * 64, r0 = by * 64;
        int lx = threadIdx.x & 63, ly = threadIdx.x >> 6;
#pragma unroll
        for (int i = 0; i < 16; ++i) {
            int r = ly * 16 + i;
            tile[lx][r] = src[(long)(r0 + r) * C + c0 + lx];
        }
        __syncthreads();
#pragma unroll
        for (int i = 0; i < 16; ++i) {
            int cr = ly * 16 + i;
            dst[(long)(c0 + cr) * R + r0 + lx] = f2b(tile[cr][lx]);
        }
        return;
    }
    int id = bid - 1216;
    if (id < 10112) {
        int r = id, k = threadIdx.x * 2;
        uint32 v = 0;
        if (r < V_) {
            float2 f = *(const float2*)(Wout + (long)r * 512 + k);
            v = pack_b2(f.x, f.y);
        }
        *(uint32*)(WoB + (long)r * 512 + k) = v;
    } else if (id < 11328) {
        int m = id - 10112;                    // m = t*64+b
        int tok = caps[(m & 63) * L_ + (m >> 6)];
        int k = threadIdx.x * 2;
        float2 v = *(const float2*)(embedding + (long)tok * E_ + k);
        *(uint32*)(embB + (long)m * E_ + k) = pack_b2(v.x, v.y);
    } else {
        int r = id - 11328;                    // 0..2047, r = 4d+q
        int d = r >> 2, q = r & 3;
        int n = q * 512 + d;
        for (int cch = threadIdx.x; cch < 384; cch += 256) {
            int kof = cch * 8;
            const float* s = (kof < 2560) ? (WIH + (long)n * 2560 + kof)
                                          : (WHH + (long)n * 512 + (kof - 2560));
            float4 f0 = *(const float4*)s;
            float4 f1 = *(const float4*)(s + 4);
            uint4 v; v.x = pack_b2(f0.x, f0.y); v.y = pack_b2(f0.z, f0.w);
            v.z = pack_b2(f1.x, f1.y); v.w = pack_b2(f1.z, f1.w);
            *(uint4*)(W2i + (long)r * 3072 + kof) = v;
        }
    }
}

// ---------------------------------------------------------------- bf16 MFMA GEMM
// EPI 1: bf16 C = v+bias
// EPI 2: gn<512 -> das=v+bias; else gate=sigmoid(v+bias2)
// EPI 6: gn<512 -> hb=f2b(v+bias); else c=v+bias2
// EPI 7: b=gm&63,tt=gm>>6; tt<T_ guard; preds=(tt<dlen)?v+bias:0
// SWZ 1: enc_proj 1D grid 784=98x8 -> (m<196, n<4), 4 same-A blocks co-XCD
// SWZ 2: pred     1D grid 800 -> (x<79, y<10), same-B blocks co-XCD
// KS fixed at 64 (KS=128 broke the XOR swizzle: R16, 4.8M bank conflicts)
template<int BM, int BN, int WM, int WN, int EPI, int SWZ>
__global__ __launch_bounds__(256) void mgemm(
    const ushort16* __restrict__ Amat, int lda1,
    const ushort16* __restrict__ Bmat, int ldb,
    void* __restrict__ Cout, void* __restrict__ Cout2, int ldc, int N, int K,
    const float* __restrict__ bias, const float* __restrict__ bias2,
    const int* __restrict__ dlen)
{
    int bx, by;
    if (SWZ == 1) {
        int id = blockIdx.x;                 // 784 = 98 per XCD x 8 XCDs (exact)
        int xcd = id & 7, idx = id >> 3;     // idx 0..97
        int j = xcd * 98 + idx;              // contiguous j-chunk per XCD
        by = j >> 2;                         // m-tile 0..195 (same-A quad co-XCD)
        bx = j & 3;                          // n-tile 0..3
    } else if (SWZ == 2) {
        int id = blockIdx.x;                 // 800 launched, 790 logical
        bx = (id / 80) * 8 + (id & 7);       // same-bx blocks differ by 8 -> same XCD
        by = (id >> 3) % 10;
        if (bx >= 79) return;
    } else { bx = blockIdx.x; by = blockIdx.y; }

    __shared__ __align__(16) ushort16 As[BM * 64];
    __shared__ __align__(16) ushort16 Bs[BN * 64];
    const int tid = threadIdx.x;
    const int m0 = by * BM, n0 = bx * BN;
    const int lane = tid & 63, wid = tid >> 6;
    constexpr int NWC = BN / WN;
    const int wr = wid / NWC, wc = wid % NWC;
    constexpr int FM = WM / 16, FN = WN / 16;
    f32x4 acc[FM][FN] = {};

    for (int k0 = 0; k0 < K; k0 += 64) {
        for (int i = tid; i < BM * 8; i += 256) {
            int r = i >> 3, ck = i & 7;
            uint4 val = *(const uint4*)(Amat + (long)(m0 + r) * lda1 + k0 + ck * 8);
            int bo = (r * 128 + ck * 16) ^ ((r & 7) << 4);
            *(uint4*)((char*)As + bo) = val;
        }
        for (int i = tid; i < BN * 8; i += 256) {
            int r = i >> 3, ck = i & 7;
            uint4 val = *(const uint4*)(Bmat + (long)(n0 + r) * ldb + k0 + ck * 8);
            int bo = (r * 128 + ck * 16) ^ ((r & 7) << 4);
            *(uint4*)((char*)Bs + bo) = val;
        }
        __syncthreads();
#pragma unroll
        for (int kk = 0; kk < 64; kk += 32) {
            short8v af[FM], bfr[FN];
#pragma unroll
            for (int f = 0; f < FM; ++f) {
                int r = wr * WM + f * 16 + (lane & 15);
                int bo = (r * 128 + (kk + ((lane >> 4) << 3)) * 2) ^ ((r & 7) << 4);
                af[f] = *(const short8v*)((const char*)As + bo);
            }
#pragma unroll
            for (int f = 0; f < FN; ++f) {
                int r = wc * WN + f * 16 + (lane & 15);
                int bo = (r * 128 + (kk + ((lane >> 4) << 3)) * 2) ^ ((r & 7) << 4);
                bfr[f] = *(const short8v*)((const char*)Bs + bo);
            }
#pragma unroll
            for (int fm = 0; fm < FM; ++fm)
#pragma unroll
                for (int fn = 0; fn < FN; ++fn)
                    acc[fm][fn] = __builtin_amdgcn_mfma_f32_16x16x32_bf16(
                        af[fm], bfr[fn], acc[fm][fn], 0, 0, 0);
        }
        __syncthreads();
    }

    int rr = lane >> 4, cc = lane & 15;
#pragma unroll
    for (int fm = 0; fm < FM; ++fm) {
#pragma unroll
        for (int fn = 0; fn < FN; ++fn) {
#pragma unroll
            for (int r = 0; r < 4; ++r) {
                int gm = m0 + wr * WM + fm * 16 + rr * 4 + r;
                int gn = n0 + wc * WN + fn * 16 + cc;
                float v = acc[fm][fn][r];
                if (EPI == 1) {
                    ((ushort16*)Cout)[(long)gm * ldc + gn] = f2b(v + bias[gn]);
                } else if (EPI == 2) {
                    if (gn < 512) ((float*)Cout)[gm * 512 + gn] = v + bias[gn];
                    else ((float*)Cout2)[gm * ENC_ + (gn - 512)] = fsigm(v + bias2[gn - 512]);
                } else if (EPI == 6) {
                    if (gn < 512) ((ushort16*)Cout)[gm * 512 + gn] = f2b(v + bias[gn]);
                    else ((float*)Cout2)[gm * 512 + (gn - 512)] = v + bias2[gn - 512];
                } else if (EPI == 7) {
                    int bq = gm & 63, tt = gm >> 6;
                    if (gn < N && tt < T_)   // tt<T_: rows >=1216 are padding (R8 bug lesson)
                        ((float*)Cout)[((long)bq * T_ + tt) * V_ + gn] =
                            (tt < dlen[bq]) ? v + bias[gn] : 0.f;
                }
            }
        }
    }
}

// ---------------------------------------------------------------- attention: scores+softmax+alpha+ctx
// grid 64 (one block per b), 1024 threads (16 waves): scores once, ctx 2 cols/thread
__global__ __launch_bounds__(1024) void k_att(
    const float* __restrict__ das, const float* __restrict__ gate,
    const float* __restrict__ Wfa, const float* __restrict__ bfa,
    const ushort16* __restrict__ ept, const ushort16* __restrict__ encS,
    const int* __restrict__ dlen,
    ushort16* __restrict__ ctxg, float* __restrict__ out, int t)
{
    int b = blockIdx.x;
    int tid = threadIdx.x;
    if (t >= dlen[b]) {
        if (tid < P_) out[OFF_ALPH + ((long)b * T_ + t) * P_ + tid] = 0.f;
        return;
    }
    __shared__ float al[P_ + 4];
    __shared__ float red[1024];
    int lane = tid & 63, wv = tid >> 6;   // 16 waves
    // scores: waves split p (16-stride), lanes split a
    float wf8[8], da8[8];
    {
        const float* wp = Wfa + lane * 8;
        const float* dp = das + b * 512 + lane * 8;
#pragma unroll
        for (int j = 0; j < 8; ++j) { wf8[j] = wp[j]; da8[j] = dp[j]; }
    }
    float b0 = bfa[0];
    for (int p = wv; p < P_; p += 16) {
        uint4 u = *(const uint4*)(ept + ((long)(b * P_ + p)) * 512 + lane * 8);
        float s = 0.f;
        s += wf8[0] * ftanh(b2f_lo(u.x) + da8[0]);
        s += wf8[1] * ftanh(b2f_hi(u.x) + da8[1]);
        s += wf8[2] * ftanh(b2f_lo(u.y) + da8[2]);
        s += wf8[3] * ftanh(b2f_hi(u.y) + da8[3]);
        s += wf8[4] * ftanh(b2f_lo(u.z) + da8[4]);
        s += wf8[5] * ftanh(b2f_hi(u.z) + da8[5]);
        s += wf8[6] * ftanh(b2f_lo(u.w) + da8[6]);
        s += wf8[7] * ftanh(b2f_hi(u.w) + da8[7]);
#pragma unroll
        for (int off = 32; off > 0; off >>= 1) s += __shfl_xor(s, off);
        if (lane == 0) al[p] = s + b0;
    }
    __syncthreads();
    // softmax over 196 (1024-thread tree)
    float sc = (tid < P_) ? al[tid] : -1e30f;
    red[tid] = sc;
    __syncthreads();
    for (int s = 512; s > 0; s >>= 1) {
        if (tid < s) red[tid] = fmaxf(red[tid], red[tid + s]);
        __syncthreads();
    }
    float mx = red[0];
    __syncthreads();
    float e = (tid < P_) ? __expf(sc - mx) : 0.f;
    red[tid] = e;
    __syncthreads();
    for (int s = 512; s > 0; s >>= 1) {
        if (tid < s) red[tid] += red[tid + s];
        __syncthreads();
    }
    float inv = 1.f / red[0];
    __syncthreads();
    if (tid < P_) al[tid] = e * inv;
    __syncthreads();
    if (tid < P_)
        out[OFF_ALPH + ((long)b * T_ + t) * P_ + tid] = al[tid];
    // ctx: 2 bf16 cols per thread (2048 cols total), unroll 14 for MLP latency
    int e0 = tid * 2;
    long base = ((long)b * P_) * ENC_ + e0;
    float a0 = 0.f, a1 = 0.f;
#pragma unroll 14
    for (int p = 0; p < P_; ++p) {
        uint32 v = *(const uint32*)(encS + base + (long)p * ENC_);
        float alp = al[p];
        a0 += alp * b2f_lo(v); a1 += alp * b2f_hi(v);
    }
    float2 g2 = *(const float2*)(gate + b * ENC_ + e0);
    *(uint32*)(ctxg + b * ENC_ + e0) = pack_b2(g2.x * a0, g2.y * a1);
}

// ---------------------------------------------------------------- gates GEMM split-K (512 blocks, BN=32)
// bid = nt*8 + ks: nt 0..63 (32-col tiles), ks 0..7 (384 K each). 2 blocks/CU.
__global__ __launch_bounds__(256) void k_gates(
    const ushort16* __restrict__ embB, const ushort16* __restrict__ ctxg,
    const ushort16* __restrict__ hin,  const ushort16* __restrict__ W2i,
    float* __restrict__ gpart, int t)
{
    __shared__ __align__(16) ushort16 As[64 * 64];
    __shared__ __align__(16) ushort16 Bs[32 * 64];
    const int tid = threadIdx.x;
    const int nt = blockIdx.x >> 3, ks = blockIdx.x & 7;
    const int n0 = nt * 32, kbeg = ks * 384;
    const int lane = tid & 63, wid = tid >> 6;
    const int wr = wid >> 1, wc = wid & 1;       // 2x2 waves: M 2x32, N 2x16
    f32x4 acc[2] = {};                            // FM=2 (WM=32), FN=1 (WN=16)

    for (int k0 = kbeg; k0 < kbeg + 384; k0 += 64) {
        for (int i = tid; i < 512; i += 256) {
            int r = i >> 3, ck = i & 7;
            int kk = k0 + ck * 8;
            const ushort16* src;
            if (kk < 512)       src = embB + ((long)(t * 64 + r)) * 512 + kk;
            else if (kk < 2560) src = ctxg + (long)r * ENC_ + (kk - 512);
            else                src = hin + (long)r * 512 + (kk - 2560);
            uint4 val = *(const uint4*)src;
            int bo = (r * 128 + ck * 16) ^ ((r & 7) << 4);
            *(uint4*)((char*)As + bo) = val;
        }
        {
            int r = tid >> 3, ck = tid & 7;      // 256 threads cover 32 rows x 8 chunks
            uint4 val = *(const uint4*)(W2i + (long)(n0 + r) * 3072 + k0 + ck * 8);
            int bo = (r * 128 + ck * 16) ^ ((r & 7) << 4);
            *(uint4*)((char*)Bs + bo) = val;
        }
        __syncthreads();
#pragma unroll
        for (int kk = 0; kk < 64; kk += 32) {
            short8v af[2], bfr;
#pragma unroll
            for (int f = 0; f < 2; ++f) {
                int r = wr * 32 + f * 16 + (lane & 15);
                int bo = (r * 128 + (kk + ((lane >> 4) << 3)) * 2) ^ ((r & 7) << 4);
                af[f] = *(const short8v*)((const char*)As + bo);
            }
            {
                int r = wc * 16 + (lane & 15);
                int bo = (r * 128 + (kk + ((lane >> 4) << 3)) * 2) ^ ((r & 7) << 4);
                bfr = *(const short8v*)((const char*)Bs + bo);
            }
#pragma unroll
            for (int f = 0; f < 2; ++f)
                acc[f] = __builtin_amdgcn_mfma_f32_16x16x32_bf16(af[f], bfr, acc[f], 0, 0, 0);
        }
        __syncthreads();
    }
    int rr = lane >> 4, cc = lane & 15;
#pragma unroll
    for (int f = 0; f < 2; ++f)
#pragma unroll
        for (int r = 0; r < 4; ++r) {
            int gm = wr * 32 + f * 16 + rr * 4 + r;
            int gn = n0 + wc * 16 + cc;
            gpart[((long)(ks * 64 + gm)) * ENC_ + gn] = acc[f][r];
        }
}

// ---------------------------------------------------------------- LSTM pointwise (reduce 8 partials) — R7 proven
__global__ __launch_bounds__(256) void k_lstm(
    const float* __restrict__ gpart,
    const float* __restrict__ bIH, const float* __restrict__ bHH,
    const int* __restrict__ dlen, float* __restrict__ c,
    const ushort16* __restrict__ hin, ushort16* __restrict__ hout,
    ushort16* __restrict__ histB, int t)
{
    int idx = blockIdx.x * 256 + threadIdx.x;   // 128 blocks -> 64 b x 512 d
    int b = idx >> 9, d = idx & 511;
    long off = (long)b * 512 + d;
    if (t < dlen[b]) {
        float s0 = 0.f, s1 = 0.f, s2 = 0.f, s3 = 0.f;
#pragma unroll
        for (int ks = 0; ks < 8; ++ks) {
            float4 gp = *(const float4*)(gpart + ((long)(ks * 64 + b)) * ENC_ + 4 * d);
            s0 += gp.x; s1 += gp.y; s2 += gp.z; s3 += gp.w;
        }
        float g0 = s0 + bIH[d] + bHH[d];
        float g1 = s1 + bIH[512 + d] + bHH[512 + d];
        float g2v = s2 + bIH[1024 + d] + bHH[1024 + d];
        float g3 = s3 + bIH[1536 + d] + bHH[1536 + d];
        float i_ = fsigm(g0), f_ = fsigm(g1), gg = ftanh(g2v), o_ = fsigm(g3);
        float cn = f_ * c[off] + i_ * gg;
        float hn = o_ * ftanh(cn);
        c[off] = cn;
        ushort16 hv = f2b(hn);
        hout[off] = hv;
        histB[((long)(t * 64 + b)) * 512 + d] = hv;
    } else {
        hout[off] = hin[off];
    }
}

// ---------------------------------------------------------------- launch
extern "C" void kernel_launch(void* const* d_in, const int* in_sizes, int n_in,
                              void* d_out, int out_size, void* d_ws, size_t ws_size,
                              hipStream_t stream)
{
    (void)in_sizes; (void)n_in; (void)out_size; (void)ws_size;
    const float* enc      = (const float*)d_in[0];
    const int*   captions = (const int*)d_in[1];
    const int*   caplen   = (const int*)d_in[2];
    const float* Wemb     = (const float*)d_in[3];
    const float* Wea = (const float*)d_in[4];  const float* bea = (const float*)d_in[5];
    const float* Wda = (const float*)d_in[6];  const float* bda = (const float*)d_in[7];
    const float* Wfa = (const float*)d_in[8];  const float* bfa = (const float*)d_in[9];
    const float* Wih = (const float*)d_in[10]; const float* bih = (const float*)d_in[11];
    const float* Wic = (const float*)d_in[12]; const float* bic = (const float*)d_in[13];
    const float* Wbe = (const float*)d_in[14]; const float* bbe = (const float*)d_in[15];
    const float* WIH = (const float*)d_in[16]; const float* bIH = (const float*)d_in[17];
    const float* WHH = (const float*)d_in[18]; const float* bHH = (const float*)d_in[19];
    const float* Wout = (const float*)d_in[20]; const float* bout = (const float*)d_in[21];

    float* out = (float*)d_out;
    char*  ws  = (char*)d_ws;
    int*   wsi = (int*)ws;
    const int* dlen = wsi + WS_DLEN / 4;
    const int* sortidx = wsi + WS_SORT / 4;
    float* das     = (float*)(ws + WS_DAS);
    float* gate    = (float*)(ws + WS_GATE);
    ushort16* hb0  = (ushort16*)(ws + WS_HB0);
    ushort16* hb1  = (ushort16*)(ws + WS_HB1);
    float* c       = (float*)(ws + WS_C);
    ushort16* ctxg = (ushort16*)(ws + WS_CTXG);
    ushort16* meanB= (ushort16*)(ws + WS_MEANB);
    ushort16* histB= (ushort16*)(ws + WS_HIST);
    ushort16* embB = (ushort16*)(ws + WS_EMB);
    float* gpart   = (float*)(ws + WS_GPART);
    ushort16* ept  = (ushort16*)(ws + WS_EPT);
    ushort16* WeaT = (ushort16*)(ws + WS_WEAT);
    ushort16* Whg  = (ushort16*)(ws + WS_WHG);
    ushort16* W2i  = (ushort16*)(ws + WS_W2I);
    ushort16* WoB  = (ushort16*)(ws + WS_WOB);
    ushort16* WInit= (ushort16*)(ws + WS_WINIT);
    ushort16* encS = (ushort16*)(ws + WS_ENCS);

    k_sort<<<1, 64, 0, stream>>>(caplen, captions, out, wsi);
    k_prep_all<<<14592, 256, 0, stream>>>(enc, sortidx, encS, meanB,
                                          Wea, Wda, Wbe, Wih, Wic, WeaT, Whg, WInit,
                                          Wout, Wemb, wsi + WS_CAPS / 4, WIH, WHH,
                                          WoB, embB, W2i);

    // h0 | c0 = meanB @ WInit^T
    mgemm<64, 64, 32, 32, 6, 0><<<dim3(16, 1), 256, 0, stream>>>(
        meanB, ENC_, WInit, ENC_, hb0, c, 0, 1024, ENC_, bih, bic, nullptr);
    // enc_proj -> ept bf16: BM=64 x BN=128, KS=64 (R13-proven, 0 bank conflicts)
    mgemm<64, 128, 32, 64, 1, 1><<<784, 256, 0, stream>>>(
        encS, ENC_, WeaT, ENC_, ept, nullptr, A_, A_, ENC_, bea, nullptr, nullptr);

    for (int t = 0; t < T_; ++t) {
        ushort16* hcur = (t & 1) ? hb1 : hb0;
        ushort16* hnxt = (t & 1) ? hb0 : hb1;
        // das | beta-gate (MFMA, 80 blocks of BN=32 for 2x CU coverage)
        mgemm<64, 32, 16, 32, 2, 0><<<dim3(80, 1), 256, 0, stream>>>(
            hcur, D_, Whg, D_, das, gate, 0, 2560, D_, bda, bbe, nullptr);
        k_att<<<64, 1024, 0, stream>>>(das, gate, Wfa, bfa, ept, encS,
                                       dlen, ctxg, out, t);
        k_gates<<<512, 256, 0, stream>>>(embB, ctxg, hcur, W2i, gpart, t);
        k_lstm<<<128, 256, 0, stream>>>(gpart, bIH, bHH, dlen, c, hcur, hnxt, histB, t);
    }
    // all preds in one GEMM, XCD-swizzled (B-tile shared blocks co-XCD)
    mgemm<128, 128, 64, 64, 7, 2><<<800, 256, 0, stream>>>(
        histB, D_, WoB, D_, out + OFF_PREDS, nullptr, 0, V_, D_, bout, nullptr,
        dlen);
}

// Round 19
// 1277.771 us; speedup vs baseline: 3.4405x; 1.0142x over previous
//
#include <hip/hip_runtime.h>

#define B_ 64
#define P_ 196
#define ENC_ 2048
#define L_ 20
#define T_ 19
#define A_ 512
#define D_ 512
#define E_ 512
#define V_ 10000

// output offsets (float elements)
#define OFF_PREDS 0
#define OFF_CAPS  12160000
#define OFF_DLEN  12161280
#define OFF_ALPH  12161344
#define OFF_SIDX  12399680

// workspace offsets (bytes) — total ~104.5 MB
#define WS_SORT   0          /* 64 int */
#define WS_DLEN   1024
#define WS_CAPS   2048       /* 64*20 int */
#define WS_DAS    114688     /* 64*512 f32 */
#define WS_GATE   245760     /* 64*2048 f32 */
#define WS_HB0    770048     /* 64*512 bf16 */
#define WS_HB1    835584
#define WS_C      901120     /* 64*512 f32 */
#define WS_CTXG   1032192    /* 64*2048 bf16 */
#define WS_MEANB  1294336    /* 64*2048 bf16 */
#define WS_HIST   1556480    /* 1280*512 bf16 */
#define WS_EMB    2867200    /* 1216*512 bf16 */
#define WS_GPART  4194304    /* 8*64*2048 f32 = 4 MB */
#define WS_EPT    8388608    /* 12544*512 bf16 = 12.85 MB */
#define WS_WEAT   21233664   /* 512*2048 bf16 */
#define WS_WHG    23330816   /* 2560*512 bf16 */
#define WS_W2I    25952256   /* 2048*3072 bf16 */
#define WS_WOB    38535168   /* 10112*512 bf16 */
#define WS_WINIT  48889856   /* 1024*2048 bf16 */
#define WS_ENCS   53084160   /* 12544*2048 bf16 = 51.38 MB -> end 104464384 */

typedef __attribute__((ext_vector_type(8))) short short8v;
typedef __attribute__((ext_vector_type(4))) float f32x4;
typedef unsigned int uint32;
typedef unsigned short ushort16;

__device__ __forceinline__ float ftanh(float x){ float e=__expf(2.f*x); return 1.f-2.f/(e+1.f); }
__device__ __forceinline__ float fsigm(float x){ return 1.f/(1.f+__expf(-x)); }
__device__ __forceinline__ ushort16 f2b(float f){
    uint32 u = __float_as_uint(f);
    uint32 r = (u + 0x7FFFu + ((u >> 16) & 1u)) >> 16;
    return (ushort16)r;
}
__device__ __forceinline__ uint32 pack_b2(float a, float b){
    return (uint32)f2b(a) | ((uint32)f2b(b) << 16);
}
__device__ __forceinline__ float b2f_lo(uint32 w){ return __uint_as_float(w << 16); }
__device__ __forceinline__ float b2f_hi(uint32 w){ return __uint_as_float(w & 0xFFFF0000u); }
__device__ __forceinline__ float b1f(ushort16 x){ return __uint_as_float((uint32)x << 16); }

// ---------------------------------------------------------------- parallel rank sort + meta
__global__ void k_sort(const int* __restrict__ cap_len, const int* __restrict__ captions,
                       float* __restrict__ out, int* __restrict__ wsi)
{
    __shared__ int len_s[B_];
    int tid = threadIdx.x;        // 64 threads
    int len = cap_len[tid];
    len_s[tid] = len;
    __syncthreads();
    int rank = 0;
#pragma unroll
    for (int j = 0; j < B_; ++j) {
        int lj = len_s[j];
        rank += (lj > len) || (lj == len && j < tid);
    }
    wsi[WS_SORT / 4 + rank] = tid;
    wsi[WS_DLEN / 4 + rank] = len - 1;
    out[OFF_SIDX + rank] = (float)tid;
    out[OFF_DLEN + rank] = (float)(len - 1);
#pragma unroll
    for (int l = 0; l < L_; ++l) {
        int cv = captions[tid * L_ + l];
        wsi[WS_CAPS / 4 + rank * L_ + l] = cv;
        out[OFF_CAPS + rank * L_ + l] = (float)cv;
    }
}

// ---------------------------------------------------------------- merged one-time prep (1 launch)
// [0,256): prep_enc (b = id>>2, 512-col slice id&3) — enc->encS bf16 + mean, unroll 14
// [256,1344): transpose+cast 5 weights (1088 tiles)
// [1344,14720): wout cast | emb gather | w2i pack (13376)
__global__ __launch_bounds__(256) void k_prep_all(
    const float* __restrict__ enc, const int* __restrict__ sortidx,
    ushort16* __restrict__ encS, ushort16* __restrict__ meanB,
    const float* __restrict__ Wea, const float* __restrict__ Wda,
    const float* __restrict__ Wbe, const float* __restrict__ Wih,
    const float* __restrict__ Wic,
    ushort16* __restrict__ WeaT, ushort16* __restrict__ Whg,
    ushort16* __restrict__ WInit,
    const float* __restrict__ Wout, const float* __restrict__ embedding,
    const int* __restrict__ caps, const float* __restrict__ WIH,
    const float* __restrict__ WHH,
    ushort16* __restrict__ WoB, ushort16* __restrict__ embB,
    ushort16* __restrict__ W2i)
{
    int bid = blockIdx.x;
    if (bid < 256) {
        int b = bid >> 2;
        int e = (bid & 3) * 512 + threadIdx.x * 2;
        long sbase = (long)sortidx[b] * P_ * ENC_ + e;
        long dbase = (long)b * P_ * ENC_ + e;
        float s0 = 0.f, s1 = 0.f;
#pragma unroll 14
        for (int p = 0; p < P_; ++p) {
            float2 v = *(const float2*)(enc + sbase + (long)p * ENC_);
            s0 += v.x; s1 += v.y;
            *(uint32*)(encS + dbase + (long)p * ENC_) = pack_b2(v.x, v.y);
        }
        const float inv = 1.f / (float)P_;
        *(uint32*)(meanB + b * ENC_ + e) = pack_b2(s0 * inv, s1 * inv);
        return;
    }
    if (bid < 1344) {
        __shared__ float tile[64][65];
        int id = bid - 256;
        const float* src; ushort16* dst; int R, C, bx, by;
        if (id < 256)      { src = Wea; dst = WeaT;                R = 2048; C = 512;  int i2 = id;        bx = i2 & 7;  by = i2 >> 3; }
        else if (id < 320) { src = Wda; dst = Whg;                 R = 512;  C = 512;  int i2 = id - 256;  bx = i2 & 7;  by = i2 >> 3; }
        else if (id < 576) { src = Wbe; dst = Whg + 512 * 512;     R = 512;  C = 2048; int i2 = id - 320;  bx = i2 & 31; by = i2 >> 5; }
        else if (id < 832) { src = Wih; dst = WInit;               R = 2048; C = 512;  int i2 = id - 576;  bx = i2 & 7;  by = i2 >> 3; }
        else               { src = Wic; dst = WInit + 512 * 2048;  R = 2048; C = 512;  int i2 = id - 832;  bx = i2 & 7;  by = i2 >> 3; }
        int c0 = bx * 64, r0 = by * 64;
        int lx = threadIdx.x & 63, ly = threadIdx.x >> 6;
#pragma unroll
        for (int i = 0; i < 16; ++i) {
            int r = ly * 16 + i;
            tile[lx][r] = src[(long)(r0 + r) * C + c0 + lx];
        }
        __syncthreads();
#pragma unroll
        for (int i = 0; i < 16; ++i) {
            int cr = ly * 16 + i;
            dst[(long)(c0 + cr) * R + r0 + lx] = f2b(tile[cr][lx]);
        }
        return;
    }
    int id = bid - 1344;
    if (id < 10112) {
        int r = id, k = threadIdx.x * 2;
        uint32 v = 0;
        if (r < V_) {
            float2 f = *(const float2*)(Wout + (long)r * 512 + k);
            v = pack_b2(f.x, f.y);
        }
        *(uint32*)(WoB + (long)r * 512 + k) = v;
    } else if (id < 11328) {
        int m = id - 10112;                    // m = t*64+b
        int tok = caps[(m & 63) * L_ + (m >> 6)];
        int k = threadIdx.x * 2;
        float2 v = *(const float2*)(embedding + (long)tok * E_ + k);
        *(uint32*)(embB + (long)m * E_ + k) = pack_b2(v.x, v.y);
    } else {
        int r = id - 11328;                    // 0..2047, r = 4d+q
        int d = r >> 2, q = r & 3;
        int n = q * 512 + d;
        for (int cch = threadIdx.x; cch < 384; cch += 256) {
            int kof = cch * 8;
            const float* s = (kof < 2560) ? (WIH + (long)n * 2560 + kof)
                                          : (WHH + (long)n * 512 + (kof - 2560));
            float4 f0 = *(const float4*)s;
            float4 f1 = *(const float4*)(s + 4);
            uint4 v; v.x = pack_b2(f0.x, f0.y); v.y = pack_b2(f0.z, f0.w);
            v.z = pack_b2(f1.x, f1.y); v.w = pack_b2(f1.z, f1.w);
            *(uint4*)(W2i + (long)r * 3072 + kof) = v;
        }
    }
}

// ---------------------------------------------------------------- bf16 MFMA GEMM
// EPI 1: bf16 C = v+bias
// EPI 2: gn<512 -> das=v+bias; else gate=sigmoid(v+bias2)
// EPI 6: gn<512 -> hb=f2b(v+bias); else c=v+bias2
// EPI 7: b=gm&63,tt=gm>>6; tt<T_ guard; preds=(tt<dlen)?v+bias:0
// SWZ 1: enc_proj 1D grid 784=98x8 -> (m<196, n<4), 4 same-A blocks co-XCD
// SWZ 2: pred     1D grid 800 -> (x<79, y<10), same-B blocks co-XCD
// KS fixed at 64 (KS=128 broke the XOR swizzle: R16, 4.8M bank conflicts)
template<int BM, int BN, int WM, int WN, int EPI, int SWZ>
__global__ __launch_bounds__(256) void mgemm(
    const ushort16* __restrict__ Amat, int lda1,
    const ushort16* __restrict__ Bmat, int ldb,
    void* __restrict__ Cout, void* __restrict__ Cout2, int ldc, int N, int K,
    const float* __restrict__ bias, const float* __restrict__ bias2,
    const int* __restrict__ dlen)
{
    int bx, by;
    if (SWZ == 1) {
        int id = blockIdx.x;                 // 784 = 98 per XCD x 8 XCDs (exact)
        int xcd = id & 7, idx = id >> 3;     // idx 0..97
        int j = xcd * 98 + idx;              // contiguous j-chunk per XCD
        by = j >> 2;                         // m-tile 0..195 (same-A quad co-XCD)
        bx = j & 3;                          // n-tile 0..3
    } else if (SWZ == 2) {
        int id = blockIdx.x;                 // 800 launched, 790 logical
        bx = (id / 80) * 8 + (id & 7);       // same-bx blocks differ by 8 -> same XCD
        by = (id >> 3) % 10;
        if (bx >= 79) return;
    } else { bx = blockIdx.x; by = blockIdx.y; }

    __shared__ __align__(16) ushort16 As[BM * 64];
    __shared__ __align__(16) ushort16 Bs[BN * 64];
    const int tid = threadIdx.x;
    const int m0 = by * BM, n0 = bx * BN;
    const int lane = tid & 63, wid = tid >> 6;
    constexpr int NWC = BN / WN;
    const int wr = wid / NWC, wc = wid % NWC;
    constexpr int FM = WM / 16, FN = WN / 16;
    f32x4 acc[FM][FN] = {};

    for (int k0 = 0; k0 < K; k0 += 64) {
        for (int i = tid; i < BM * 8; i += 256) {
            int r = i >> 3, ck = i & 7;
            uint4 val = *(const uint4*)(Amat + (long)(m0 + r) * lda1 + k0 + ck * 8);
            int bo = (r * 128 + ck * 16) ^ ((r & 7) << 4);
            *(uint4*)((char*)As + bo) = val;
        }
        for (int i = tid; i < BN * 8; i += 256) {
            int r = i >> 3, ck = i & 7;
            uint4 val = *(const uint4*)(Bmat + (long)(n0 + r) * ldb + k0 + ck * 8);
            int bo = (r * 128 + ck * 16) ^ ((r & 7) << 4);
            *(uint4*)((char*)Bs + bo) = val;
        }
        __syncthreads();
#pragma unroll
        for (int kk = 0; kk < 64; kk += 32) {
            short8v af[FM], bfr[FN];
#pragma unroll
            for (int f = 0; f < FM; ++f) {
                int r = wr * WM + f * 16 + (lane & 15);
                int bo = (r * 128 + (kk + ((lane >> 4) << 3)) * 2) ^ ((r & 7) << 4);
                af[f] = *(const short8v*)((const char*)As + bo);
            }
#pragma unroll
            for (int f = 0; f < FN; ++f) {
                int r = wc * WN + f * 16 + (lane & 15);
                int bo = (r * 128 + (kk + ((lane >> 4) << 3)) * 2) ^ ((r & 7) << 4);
                bfr[f] = *(const short8v*)((const char*)Bs + bo);
            }
#pragma unroll
            for (int fm = 0; fm < FM; ++fm)
#pragma unroll
                for (int fn = 0; fn < FN; ++fn)
                    acc[fm][fn] = __builtin_amdgcn_mfma_f32_16x16x32_bf16(
                        af[fm], bfr[fn], acc[fm][fn], 0, 0, 0);
        }
        __syncthreads();
    }

    int rr = lane >> 4, cc = lane & 15;
#pragma unroll
    for (int fm = 0; fm < FM; ++fm) {
#pragma unroll
        for (int fn = 0; fn < FN; ++fn) {
#pragma unroll
            for (int r = 0; r < 4; ++r) {
                int gm = m0 + wr * WM + fm * 16 + rr * 4 + r;
                int gn = n0 + wc * WN + fn * 16 + cc;
                float v = acc[fm][fn][r];
                if (EPI == 1) {
                    ((ushort16*)Cout)[(long)gm * ldc + gn] = f2b(v + bias[gn]);
                } else if (EPI == 2) {
                    if (gn < 512) ((float*)Cout)[gm * 512 + gn] = v + bias[gn];
                    else ((float*)Cout2)[gm * ENC_ + (gn - 512)] = fsigm(v + bias2[gn - 512]);
                } else if (EPI == 6) {
                    if (gn < 512) ((ushort16*)Cout)[gm * 512 + gn] = f2b(v + bias[gn]);
                    else ((float*)Cout2)[gm * 512 + (gn - 512)] = v + bias2[gn - 512];
                } else if (EPI == 7) {
                    int bq = gm & 63, tt = gm >> 6;
                    if (gn < N && tt < T_)   // tt<T_: rows >=1216 are padding (R8 bug lesson)
                        ((float*)Cout)[((long)bq * T_ + tt) * V_ + gn] =
                            (tt < dlen[bq]) ? v + bias[gn] : 0.f;
                }
            }
        }
    }
}

// ---------------------------------------------------------------- attention: scores+softmax+alpha+ctx
// grid 64 (one block per b), 1024 threads (16 waves): scores once, ctx 2 cols/thread
__global__ __launch_bounds__(1024) void k_att(
    const float* __restrict__ das, const float* __restrict__ gate,
    const float* __restrict__ Wfa, const float* __restrict__ bfa,
    const ushort16* __restrict__ ept, const ushort16* __restrict__ encS,
    const int* __restrict__ dlen,
    ushort16* __restrict__ ctxg, float* __restrict__ out, int t)
{
    int b = blockIdx.x;
    int tid = threadIdx.x;
    if (t >= dlen[b]) {
        if (tid < P_) out[OFF_ALPH + ((long)b * T_ + t) * P_ + tid] = 0.f;
        return;
    }
    __shared__ float al[P_ + 4];
    __shared__ float red[1024];
    int lane = tid & 63, wv = tid >> 6;   // 16 waves
    // scores: waves split p (16-stride), lanes split a
    float wf8[8], da8[8];
    {
        const float* wp = Wfa + lane * 8;
        const float* dp = das + b * 512 + lane * 8;
#pragma unroll
        for (int j = 0; j < 8; ++j) { wf8[j] = wp[j]; da8[j] = dp[j]; }
    }
    float b0 = bfa[0];
    for (int p = wv; p < P_; p += 16) {
        uint4 u = *(const uint4*)(ept + ((long)(b * P_ + p)) * 512 + lane * 8);
        float s = 0.f;
        s += wf8[0] * ftanh(b2f_lo(u.x) + da8[0]);
        s += wf8[1] * ftanh(b2f_hi(u.x) + da8[1]);
        s += wf8[2] * ftanh(b2f_lo(u.y) + da8[2]);
        s += wf8[3] * ftanh(b2f_hi(u.y) + da8[3]);
        s += wf8[4] * ftanh(b2f_lo(u.z) + da8[4]);
        s += wf8[5] * ftanh(b2f_hi(u.z) + da8[5]);
        s += wf8[6] * ftanh(b2f_lo(u.w) + da8[6]);
        s += wf8[7] * ftanh(b2f_hi(u.w) + da8[7]);
#pragma unroll
        for (int off = 32; off > 0; off >>= 1) s += __shfl_xor(s, off);
        if (lane == 0) al[p] = s + b0;
    }
    __syncthreads();
    // softmax over 196 (1024-thread tree)
    float sc = (tid < P_) ? al[tid] : -1e30f;
    red[tid] = sc;
    __syncthreads();
    for (int s = 512; s > 0; s >>= 1) {
        if (tid < s) red[tid] = fmaxf(red[tid], red[tid + s]);
        __syncthreads();
    }
    float mx = red[0];
    __syncthreads();
    float e = (tid < P_) ? __expf(sc - mx) : 0.f;
    red[tid] = e;
    __syncthreads();
    for (int s = 512; s > 0; s >>= 1) {
        if (tid < s) red[tid] += red[tid + s];
        __syncthreads();
    }
    float inv = 1.f / red[0];
    __syncthreads();
    if (tid < P_) al[tid] = e * inv;
    __syncthreads();
    if (tid < P_)
        out[OFF_ALPH + ((long)b * T_ + t) * P_ + tid] = al[tid];
    // ctx: 2 bf16 cols per thread (2048 cols total), unroll 14 for latency
    int e0 = tid * 2;
    long base = ((long)b * P_) * ENC_ + e0;
    float a0 = 0.f, a1 = 0.f;
#pragma unroll 14
    for (int p = 0; p < P_; ++p) {
        uint32 v = *(const uint32*)(encS + base + (long)p * ENC_);
        float alp = al[p];
        a0 += alp * b2f_lo(v); a1 += alp * b2f_hi(v);
    }
    float2 g2 = *(const float2*)(gate + b * ENC_ + e0);
    *(uint32*)(ctxg + b * ENC_ + e0) = pack_b2(g2.x * a0, g2.y * a1);
}

// ---------------------------------------------------------------- gates GEMM split-K (512 blocks, BN=32)
// bid = nt*8 + ks: nt 0..63 (32-col tiles), ks 0..7 (384 K each). 2 blocks/CU.
__global__ __launch_bounds__(256) void k_gates(
    const ushort16* __restrict__ embB, const ushort16* __restrict__ ctxg,
    const ushort16* __restrict__ hin,  const ushort16* __restrict__ W2i,
    float* __restrict__ gpart, int t)
{
    __shared__ __align__(16) ushort16 As[64 * 64];
    __shared__ __align__(16) ushort16 Bs[32 * 64];
    const int tid = threadIdx.x;
    const int nt = blockIdx.x >> 3, ks = blockIdx.x & 7;
    const int n0 = nt * 32, kbeg = ks * 384;
    const int lane = tid & 63, wid = tid >> 6;
    const int wr = wid >> 1, wc = wid & 1;       // 2x2 waves: M 2x32, N 2x16
    f32x4 acc[2] = {};                            // FM=2 (WM=32), FN=1 (WN=16)

    for (int k0 = kbeg; k0 < kbeg + 384; k0 += 64) {
        for (int i = tid; i < 512; i += 256) {
            int r = i >> 3, ck = i & 7;
            int kk = k0 + ck * 8;
            const ushort16* src;
            if (kk < 512)       src = embB + ((long)(t * 64 + r)) * 512 + kk;
            else if (kk < 2560) src = ctxg + (long)r * ENC_ + (kk - 512);
            else                src = hin + (long)r * 512 + (kk - 2560);
            uint4 val = *(const uint4*)src;
            int bo = (r * 128 + ck * 16) ^ ((r & 7) << 4);
            *(uint4*)((char*)As + bo) = val;
        }
        {
            int r = tid >> 3, ck = tid & 7;      // 256 threads cover 32 rows x 8 chunks
            uint4 val = *(const uint4*)(W2i + (long)(n0 + r) * 3072 + k0 + ck * 8);
            int bo = (r * 128 + ck * 16) ^ ((r & 7) << 4);
            *(uint4*)((char*)Bs + bo) = val;
        }
        __syncthreads();
#pragma unroll
        for (int kk = 0; kk < 64; kk += 32) {
            short8v af[2], bfr;
#pragma unroll
            for (int f = 0; f < 2; ++f) {
                int r = wr * 32 + f * 16 + (lane & 15);
                int bo = (r * 128 + (kk + ((lane >> 4) << 3)) * 2) ^ ((r & 7) << 4);
                af[f] = *(const short8v*)((const char*)As + bo);
            }
            {
                int r = wc * 16 + (lane & 15);
                int bo = (r * 128 + (kk + ((lane >> 4) << 3)) * 2) ^ ((r & 7) << 4);
                bfr = *(const short8v*)((const char*)Bs + bo);
            }
#pragma unroll
            for (int f = 0; f < 2; ++f)
                acc[f] = __builtin_amdgcn_mfma_f32_16x16x32_bf16(af[f], bfr, acc[f], 0, 0, 0);
        }
        __syncthreads();
    }
    int rr = lane >> 4, cc = lane & 15;
#pragma unroll
    for (int f = 0; f < 2; ++f)
#pragma unroll
        for (int r = 0; r < 4; ++r) {
            int gm = wr * 32 + f * 16 + rr * 4 + r;
            int gn = n0 + wc * 16 + cc;
            gpart[((long)(ks * 64 + gm)) * ENC_ + gn] = acc[f][r];
        }
}

// ---------------------------------------------------------------- LSTM pointwise (reduce 8 partials) — R7 proven
__global__ __launch_bounds__(256) void k_lstm(
    const float* __restrict__ gpart,
    const float* __restrict__ bIH, const float* __restrict__ bHH,
    const int* __restrict__ dlen, float* __restrict__ c,
    const ushort16* __restrict__ hin, ushort16* __restrict__ hout,
    ushort16* __restrict__ histB, int t)
{
    int idx = blockIdx.x * 256 + threadIdx.x;   // 128 blocks -> 64 b x 512 d
    int b = idx >> 9, d = idx & 511;
    long off = (long)b * 512 + d;
    if (t < dlen[b]) {
        float s0 = 0.f, s1 = 0.f, s2 = 0.f, s3 = 0.f;
#pragma unroll
        for (int ks = 0; ks < 8; ++ks) {
            float4 gp = *(const float4*)(gpart + ((long)(ks * 64 + b)) * ENC_ + 4 * d);
            s0 += gp.x; s1 += gp.y; s2 += gp.z; s3 += gp.w;
        }
        float g0 = s0 + bIH[d] + bHH[d];
        float g1 = s1 + bIH[512 + d] + bHH[512 + d];
        float g2v = s2 + bIH[1024 + d] + bHH[1024 + d];
        float g3 = s3 + bIH[1536 + d] + bHH[1536 + d];
        float i_ = fsigm(g0), f_ = fsigm(g1), gg = ftanh(g2v), o_ = fsigm(g3);
        float cn = f_ * c[off] + i_ * gg;
        float hn = o_ * ftanh(cn);
        c[off] = cn;
        ushort16 hv = f2b(hn);
        hout[off] = hv;
        histB[((long)(t * 64 + b)) * 512 + d] = hv;
    } else {
        hout[off] = hin[off];
    }
}

// ---------------------------------------------------------------- launch
extern "C" void kernel_launch(void* const* d_in, const int* in_sizes, int n_in,
                              void* d_out, int out_size, void* d_ws, size_t ws_size,
                              hipStream_t stream)
{
    (void)in_sizes; (void)n_in; (void)out_size; (void)ws_size;
    const float* enc      = (const float*)d_in[0];
    const int*   captions = (const int*)d_in[1];
    const int*   caplen   = (const int*)d_in[2];
    const float* Wemb     = (const float*)d_in[3];
    const float* Wea = (const float*)d_in[4];  const float* bea = (const float*)d_in[5];
    const float* Wda = (const float*)d_in[6];  const float* bda = (const float*)d_in[7];
    const float* Wfa = (const float*)d_in[8];  const float* bfa = (const float*)d_in[9];
    const float* Wih = (const float*)d_in[10]; const float* bih = (const float*)d_in[11];
    const float* Wic = (const float*)d_in[12]; const float* bic = (const float*)d_in[13];
    const float* Wbe = (const float*)d_in[14]; const float* bbe = (const float*)d_in[15];
    const float* WIH = (const float*)d_in[16]; const float* bIH = (const float*)d_in[17];
    const float* WHH = (const float*)d_in[18]; const float* bHH = (const float*)d_in[19];
    const float* Wout = (const float*)d_in[20]; const float* bout = (const float*)d_in[21];

    float* out = (float*)d_out;
    char*  ws  = (char*)d_ws;
    int*   wsi = (int*)ws;
    const int* dlen = wsi + WS_DLEN / 4;
    const int* sortidx = wsi + WS_SORT / 4;
    float* das     = (float*)(ws + WS_DAS);
    float* gate    = (float*)(ws + WS_GATE);
    ushort16* hb0  = (ushort16*)(ws + WS_HB0);
    ushort16* hb1  = (ushort16*)(ws + WS_HB1);
    float* c       = (float*)(ws + WS_C);
    ushort16* ctxg = (ushort16*)(ws + WS_CTXG);
    ushort16* meanB= (ushort16*)(ws + WS_MEANB);
    ushort16* histB= (ushort16*)(ws + WS_HIST);
    ushort16* embB = (ushort16*)(ws + WS_EMB);
    float* gpart   = (float*)(ws + WS_GPART);
    ushort16* ept  = (ushort16*)(ws + WS_EPT);
    ushort16* WeaT = (ushort16*)(ws + WS_WEAT);
    ushort16* Whg  = (ushort16*)(ws + WS_WHG);
    ushort16* W2i  = (ushort16*)(ws + WS_W2I);
    ushort16* WoB  = (ushort16*)(ws + WS_WOB);
    ushort16* WInit= (ushort16*)(ws + WS_WINIT);
    ushort16* encS = (ushort16*)(ws + WS_ENCS);

    k_sort<<<1, 64, 0, stream>>>(caplen, captions, out, wsi);
    k_prep_all<<<14720, 256, 0, stream>>>(enc, sortidx, encS, meanB,
                                          Wea, Wda, Wbe, Wih, Wic, WeaT, Whg, WInit,
                                          Wout, Wemb, wsi + WS_CAPS / 4, WIH, WHH,
                                          WoB, embB, W2i);

    // h0 | c0 = meanB @ WInit^T
    mgemm<64, 64, 32, 32, 6, 0><<<dim3(16, 1), 256, 0, stream>>>(
        meanB, ENC_, WInit, ENC_, hb0, c, 0, 1024, ENC_, bih, bic, nullptr);
    // enc_proj -> ept bf16: BM=64 x BN=128, KS=64 (R13-proven, 0 bank conflicts)
    mgemm<64, 128, 32, 64, 1, 1><<<784, 256, 0, stream>>>(
        encS, ENC_, WeaT, ENC_, ept, nullptr, A_, A_, ENC_, bea, nullptr, nullptr);

    for (int t = 0; t < T_; ++t) {
        ushort16* hcur = (t & 1) ? hb1 : hb0;
        ushort16* hnxt = (t & 1) ? hb0 : hb1;
        // das | beta-gate (MFMA, 80 blocks of BN=32 for 2x CU coverage)
        mgemm<64, 32, 16, 32, 2, 0><<<dim3(80, 1), 256, 0, stream>>>(
            hcur, D_, Whg, D_, das, gate, 0, 2560, D_, bda, bbe, nullptr);
        k_att<<<64, 1024, 0, stream>>>(das, gate, Wfa, bfa, ept, encS,
                                       dlen, ctxg, out, t);
        k_gates<<<512, 256, 0, stream>>>(embB, ctxg, hcur, W2i, gpart, t);
        k_lstm<<<128, 256, 0, stream>>>(gpart, bIH, bHH, dlen, c, hcur, hnxt, histB, t);
    }
    // all preds in one GEMM, XCD-swizzled (B-tile shared blocks co-XCD)
    mgemm<128, 128, 64, 64, 7, 2><<<800, 256, 0, stream>>>(
        histB, D_, WoB, D_, out + OFF_PREDS, nullptr, 0, V_, D_, bout, nullptr,
        dlen);
}